// Round 1
// baseline (2648.161 us; speedup 1.0000x reference)
//
#include <hip/hip_runtime.h>
#include <math.h>

#define LEAK 0.01f

// ---------------- Conv2d k=4 s=2 p=1, NCHW/OIHW, 8 output channels per thread ----------------
__global__ void conv_k4s2p1(const float* __restrict__ x, const float* __restrict__ w,
                            const float* __restrict__ bias, float* __restrict__ y,
                            int B, int Ci, int Hin, int Co, int Ho) {
    int idx = blockIdx.x * blockDim.x + threadIdx.x;
    int og_n = Co >> 3;
    int total = B * og_n * Ho * Ho;
    if (idx >= total) return;
    int ow = idx % Ho;
    int t = idx / Ho;
    int oh = t % Ho; t /= Ho;
    int og = t % og_n;
    int b  = t / og_n;
    int oc0 = og << 3;

    float acc[8];
#pragma unroll
    for (int u = 0; u < 8; ++u) acc[u] = bias[oc0 + u];

    const float* xb = x + (size_t)b * Ci * Hin * Hin;
    for (int ic = 0; ic < Ci; ++ic) {
        const float* xc = xb + (size_t)ic * Hin * Hin;
        const float* wc = w + ((size_t)oc0 * Ci + ic) * 16;  // w[oc0][ic][0][0]
        size_t wstride = (size_t)Ci * 16;
#pragma unroll
        for (int kh = 0; kh < 4; ++kh) {
            int ih = oh * 2 - 1 + kh;
            if (ih < 0 || ih >= Hin) continue;
#pragma unroll
            for (int kw = 0; kw < 4; ++kw) {
                int iw = ow * 2 - 1 + kw;
                if (iw < 0 || iw >= Hin) continue;
                float v = xc[ih * Hin + iw];
#pragma unroll
                for (int u = 0; u < 8; ++u)
                    acc[u] += v * wc[u * wstride + kh * 4 + kw];
            }
        }
    }
    size_t obase = (((size_t)b * Co + oc0) * Ho + oh) * Ho + ow;
    size_t oplane = (size_t)Ho * Ho;
#pragma unroll
    for (int u = 0; u < 8; ++u) y[obase + u * oplane] = acc[u];
}

// ---------------- BatchNorm stats (training mode, biased var) -> scale/shift ----------------
__global__ void bn_stats(const float* __restrict__ y, const float* __restrict__ g,
                         const float* __restrict__ bt, float* __restrict__ sc,
                         float* __restrict__ sh, int B, int C, int HW) {
    int c = blockIdx.x;
    int tid = threadIdx.x;
    double s = 0.0, s2 = 0.0;
    for (int b = 0; b < B; ++b) {
        const float* p = y + ((size_t)b * C + c) * HW;
        for (int i = tid; i < HW; i += 256) {
            float v = p[i];
            s += v; s2 += (double)v * v;
        }
    }
    __shared__ double ls[256], ls2[256];
    ls[tid] = s; ls2[tid] = s2;
    __syncthreads();
    for (int off = 128; off > 0; off >>= 1) {
        if (tid < off) { ls[tid] += ls[tid + off]; ls2[tid] += ls2[tid + off]; }
        __syncthreads();
    }
    if (tid == 0) {
        double n = (double)B * HW;
        double m = ls[0] / n;
        double var = ls2[0] / n - m * m;
        float rstd = (float)(1.0 / sqrt(var + 1e-5));
        float scale = g[c] * rstd;
        sc[c] = scale;
        sh[c] = bt[c] - (float)m * scale;
    }
}

// ---------------- Apply BN (scale/shift) + LeakyReLU, in place ----------------
__global__ void bn_apply(float* __restrict__ y, const float* __restrict__ sc,
                         const float* __restrict__ sh, int C, int HW, int total) {
    int i = blockIdx.x * blockDim.x + threadIdx.x;
    if (i >= total) return;
    int c = (i / HW) % C;
    float v = y[i] * sc[c] + sh[c];
    y[i] = v >= 0.f ? v : LEAK * v;
}

// ---------------- Vector quantizer: 1 block per latent vector ----------------
// z: (16,256,8,8) NCHW -> rows r = b*64 + s (s = h*8+w), zf[r][c] = z[(b*256+c)*64 + s]
#define OUT_CL   786432
#define OUT_CB   786433
#define OUT_IDX  786434
#define OUT_MIND 787458
__global__ void vq_kernel(const float* __restrict__ z, const float* __restrict__ cb,
                          float* __restrict__ q, float* __restrict__ dout) {
    int r = blockIdx.x;
    int b = r >> 6;
    int s = r & 63;
    int tid = threadIdx.x;

    __shared__ float zrow[256];
    __shared__ float rd[256];
    __shared__ int   ri[256];

    zrow[tid] = z[((size_t)(b * 256 + tid)) * 64 + s];
    __syncthreads();

    // ||z||^2
    rd[tid] = zrow[tid] * zrow[tid];
    __syncthreads();
    for (int off = 128; off > 0; off >>= 1) {
        if (tid < off) rd[tid] += rd[tid + off];
        __syncthreads();
    }
    float zn2 = rd[0];
    __syncthreads();

    // distances for codes tid and tid+256 (tid first -> first-index tie priority)
    float bestd = 3.4e38f;
    int besti = 0;
#pragma unroll
    for (int kk = 0; kk < 2; ++kk) {
        int code = tid + kk * 256;
        const float* cp = cb + (size_t)code * 256;
        float dot = 0.f, cn = 0.f;
        for (int c = 0; c < 256; ++c) {
            float cv = cp[c];
            dot += zrow[c] * cv;
            cn  += cv * cv;
        }
        float d = zn2 - 2.f * dot + cn;
        if (d < bestd) { bestd = d; besti = code; }
    }
    rd[tid] = bestd; ri[tid] = besti;
    __syncthreads();
    for (int off = 128; off > 0; off >>= 1) {
        if (tid < off) {
            float od = rd[tid + off]; int oi = ri[tid + off];
            if (od < rd[tid] || (od == rd[tid] && oi < ri[tid])) { rd[tid] = od; ri[tid] = oi; }
        }
        __syncthreads();
    }
    int best = ri[0];

    // q_st forward == codebook[best]; write back in NCHW
    q[((size_t)(b * 256 + tid)) * 64 + s] = cb[(size_t)best * 256 + tid];
    if (tid == 0) {
        dout[OUT_IDX + r]  = (float)best;
        dout[OUT_MIND + r] = rd[0];
    }
}

// commitment_loss == codebook_loss == sum(min_d)/(1024*256)
__global__ void vq_loss(float* __restrict__ dout) {
    int tid = threadIdx.x;
    __shared__ float red[256];
    float s = 0.f;
    for (int i = tid; i < 1024; i += 256) s += dout[OUT_MIND + i];
    red[tid] = s;
    __syncthreads();
    for (int off = 128; off > 0; off >>= 1) {
        if (tid < off) red[tid] += red[tid + off];
        __syncthreads();
    }
    if (tid == 0) {
        float loss = red[0] / 262144.f;
        dout[OUT_CL] = loss;
        dout[OUT_CB] = loss;
    }
}

// ---------------- ConvTranspose2d, stride == kernel (non-overlapping expansion) ----------------
// w: (Ci, Co, k, k); out[b][o][h*k+i][w*k+j] = sum_c x[b][c][h][w]*w[c][o][i][j] + bias[o]
__global__ void convt(const float* __restrict__ x, const float* __restrict__ wt,
                      const float* __restrict__ bias, float* __restrict__ y,
                      int B, int Ci, int Hin, int Co, int k) {
    int Ho = Hin * k;
    int og_n = Co >> 3;
    int idx = blockIdx.x * blockDim.x + threadIdx.x;
    int total = B * og_n * Ho * Ho;
    if (idx >= total) return;
    int ow = idx % Ho;
    int t = idx / Ho;
    int oh = t % Ho; t /= Ho;
    int og = t % og_n;
    int b  = t / og_n;
    int o0 = og << 3;

    int h = oh / k, i = oh % k;
    int w = ow / k, j = ow % k;

    float acc[8];
#pragma unroll
    for (int u = 0; u < 8; ++u) acc[u] = bias[o0 + u];

    const float* xp = x + ((size_t)b * Ci) * Hin * Hin + h * Hin + w;
    size_t xstride = (size_t)Hin * Hin;
    int kk = k * k;
    const float* wp = wt + ((size_t)o0 * k + i) * k + j;  // + c*Co*kk for channel c
    size_t wcs = (size_t)Co * kk;
    for (int c = 0; c < Ci; ++c) {
        float v = xp[c * xstride];
        const float* wc = wp + c * wcs;
#pragma unroll
        for (int u = 0; u < 8; ++u)
            acc[u] += v * wc[u * kk];
    }
    size_t obase = (((size_t)b * Co + o0) * Ho + oh) * Ho + ow;
    size_t oplane = (size_t)Ho * Ho;
#pragma unroll
    for (int u = 0; u < 8; ++u) y[obase + u * oplane] = acc[u];
}

// ---------------- Final 1x1 conv (32->3) + tanh ----------------
__global__ void final_conv_tanh(const float* __restrict__ hbuf, const float* __restrict__ w3,
                                const float* __restrict__ b3, float* __restrict__ out) {
    int idx = blockIdx.x * blockDim.x + threadIdx.x;  // B*128*128 = 262144
    if (idx >= 16 * 16384) return;
    int hw = idx % 16384;
    int b  = idx / 16384;
    const float* hp = hbuf + ((size_t)b * 32) * 16384 + hw;
    float a0 = b3[0], a1 = b3[1], a2 = b3[2];
#pragma unroll
    for (int c = 0; c < 32; ++c) {
        float v = hp[(size_t)c * 16384];
        a0 += v * w3[c];
        a1 += v * w3[32 + c];
        a2 += v * w3[64 + c];
    }
    size_t ob = ((size_t)b * 3) * 16384 + hw;
    out[ob]             = tanhf(a0);
    out[ob + 16384]     = tanhf(a1);
    out[ob + 2 * 16384] = tanhf(a2);
}

extern "C" void kernel_launch(void* const* d_in, const int* in_sizes, int n_in,
                              void* d_out, int out_size, void* d_ws, size_t ws_size,
                              hipStream_t stream) {
    const float* x      = (const float*)d_in[0];
    const float* enc_w0 = (const float*)d_in[1];
    const float* enc_b0 = (const float*)d_in[2];
    const float* enc_w1 = (const float*)d_in[3];
    const float* enc_b1 = (const float*)d_in[4];
    const float* enc_w2 = (const float*)d_in[5];
    const float* enc_b2 = (const float*)d_in[6];
    const float* enc_w3 = (const float*)d_in[7];
    const float* enc_b3 = (const float*)d_in[8];
    const float* ebn_g0 = (const float*)d_in[9];
    const float* ebn_b0 = (const float*)d_in[10];
    const float* ebn_g1 = (const float*)d_in[11];
    const float* ebn_b1 = (const float*)d_in[12];
    const float* ebn_g2 = (const float*)d_in[13];
    const float* ebn_b2 = (const float*)d_in[14];
    const float* cb     = (const float*)d_in[15];
    const float* dec_w0 = (const float*)d_in[16];
    const float* dec_b0 = (const float*)d_in[17];
    const float* dbn_g0 = (const float*)d_in[18];
    const float* dbn_b0 = (const float*)d_in[19];
    const float* dec_w1 = (const float*)d_in[20];
    const float* dec_b1 = (const float*)d_in[21];
    const float* dbn_g1 = (const float*)d_in[22];
    const float* dbn_b1 = (const float*)d_in[23];
    const float* dec_w2 = (const float*)d_in[24];
    const float* dec_b2 = (const float*)d_in[25];
    const float* dbn_g2 = (const float*)d_in[26];
    const float* dbn_b2 = (const float*)d_in[27];
    const float* dec_w3 = (const float*)d_in[28];
    const float* dec_b3 = (const float*)d_in[29];

    float* out = (float*)d_out;
    float* ws  = (float*)d_ws;

    // workspace layout (floats), with liveness-based reuse (~56 MB total)
    float* Y0 = ws;              // (16,64,64,64)   4194304
    float* Y1 = ws + 4194304;    // (16,128,32,32)  2097152
    float* Y2 = ws + 6291456;    // (16,256,16,16)  1048576
    float* Z  = ws + 7340032;    // (16,256,8,8)     262144
    float* Q  = ws + 7602176;    // (16,256,8,8)     262144
    float* D0 = ws;              // (16,128,32,32)  2097152  (Y0 dead)
    float* D1 = ws + 2097152;    // (16,64,64,64)   4194304  (Y0 hi / Y1 dead)
    float* D2 = ws + 6291456;    // (16,32,128,128) 8388608  (Y2/Z/Q dead)
    float* SC = ws + 14680064;   // 256 scale
    float* SH = ws + 14680320;   // 256 shift

    dim3 blk(256);

    // ---- encoder ----
    conv_k4s2p1<<<2048, blk, 0, stream>>>(x, enc_w0, enc_b0, Y0, 16, 3, 128, 64, 64);
    bn_stats<<<64, blk, 0, stream>>>(Y0, ebn_g0, ebn_b0, SC, SH, 16, 64, 4096);
    bn_apply<<<16384, blk, 0, stream>>>(Y0, SC, SH, 64, 4096, 4194304);

    conv_k4s2p1<<<1024, blk, 0, stream>>>(Y0, enc_w1, enc_b1, Y1, 16, 64, 64, 128, 32);
    bn_stats<<<128, blk, 0, stream>>>(Y1, ebn_g1, ebn_b1, SC, SH, 16, 128, 1024);
    bn_apply<<<8192, blk, 0, stream>>>(Y1, SC, SH, 128, 1024, 2097152);

    conv_k4s2p1<<<512, blk, 0, stream>>>(Y1, enc_w2, enc_b2, Y2, 16, 128, 32, 256, 16);
    bn_stats<<<256, blk, 0, stream>>>(Y2, ebn_g2, ebn_b2, SC, SH, 16, 256, 256);
    bn_apply<<<4096, blk, 0, stream>>>(Y2, SC, SH, 256, 256, 1048576);

    conv_k4s2p1<<<128, blk, 0, stream>>>(Y2, enc_w3, enc_b3, Z, 16, 256, 16, 256, 8);

    // ---- vector quantizer ----
    vq_kernel<<<1024, blk, 0, stream>>>(Z, cb, Q, out);
    vq_loss<<<1, blk, 0, stream>>>(out);

    // ---- decoder ----
    convt<<<1024, blk, 0, stream>>>(Q, dec_w0, dec_b0, D0, 16, 256, 8, 128, 4);
    bn_stats<<<128, blk, 0, stream>>>(D0, dbn_g0, dbn_b0, SC, SH, 16, 128, 1024);
    bn_apply<<<8192, blk, 0, stream>>>(D0, SC, SH, 128, 1024, 2097152);

    convt<<<2048, blk, 0, stream>>>(D0, dec_w1, dec_b1, D1, 16, 128, 32, 64, 2);
    bn_stats<<<64, blk, 0, stream>>>(D1, dbn_g1, dbn_b1, SC, SH, 16, 64, 4096);
    bn_apply<<<16384, blk, 0, stream>>>(D1, SC, SH, 64, 4096, 4194304);

    convt<<<4096, blk, 0, stream>>>(D1, dec_w2, dec_b2, D2, 16, 64, 64, 32, 2);
    bn_stats<<<32, blk, 0, stream>>>(D2, dbn_g2, dbn_b2, SC, SH, 16, 32, 16384);
    bn_apply<<<32768, blk, 0, stream>>>(D2, SC, SH, 32, 16384, 8388608);

    final_conv_tanh<<<1024, blk, 0, stream>>>(D2, dec_w3, dec_b3, out);
}

// Round 2
// 1945.778 us; speedup vs baseline: 1.3610x; 1.3610x over previous
//
#include <hip/hip_runtime.h>
#include <math.h>

#define LEAK 0.01f

// ================= Conv2d k=4 s=2 p=1, NCHW/OIHW =================
// 8 output channels per thread, optional split over input channels (KS slices).
// KS==1: writes y with bias.  KS>1: writes partials P[ks*outSize + i] (no bias).
__global__ void conv_k4s2p1_ks(const float* __restrict__ x, const float* __restrict__ w,
                               const float* __restrict__ bias, float* __restrict__ P,
                               int B, int Ci, int Hin, int Co, int Ho,
                               int KS, int icsl, int outSize) {
    int idx = blockIdx.x * 256 + threadIdx.x;
    int ogn = Co >> 3;
    int total = B * ogn * Ho * Ho * KS;
    if (idx >= total) return;
    int ow = idx % Ho; int t = idx / Ho;
    int oh = t % Ho;   t /= Ho;
    int og = t % ogn;  t /= ogn;
    int b  = t % B;
    int ks = t / B;
    int oc0 = og << 3;
    int ic0 = ks * icsl;

    float acc[8];
#pragma unroll
    for (int u = 0; u < 8; ++u) acc[u] = 0.f;
    if (KS == 1) {
#pragma unroll
        for (int u = 0; u < 8; ++u) acc[u] = bias[oc0 + u];
    }

    const float* xb = x + ((size_t)b * Ci + ic0) * Hin * Hin;
    const float* wb = w + ((size_t)oc0 * Ci + ic0) * 16;
    size_t wstride = (size_t)Ci * 16;
    int iw0 = ow * 2 - 1;

    for (int ic = 0; ic < icsl; ++ic) {
        const float* xc = xb + (size_t)ic * Hin * Hin;
        const float* wc = wb + (size_t)ic * 16;
#pragma unroll
        for (int kh = 0; kh < 4; ++kh) {
            int ih = oh * 2 - 1 + kh;
            if (ih < 0 || ih >= Hin) continue;
            float4 wv[8];
#pragma unroll
            for (int u = 0; u < 8; ++u)
                wv[u] = *(const float4*)(wc + u * wstride + kh * 4);
            const float* xrow = xc + (size_t)ih * Hin + iw0;
#pragma unroll
            for (int kw = 0; kw < 4; ++kw) {
                int iw = iw0 + kw;
                if (iw < 0 || iw >= Hin) continue;
                float v = xrow[kw];
#pragma unroll
                for (int u = 0; u < 8; ++u)
                    acc[u] += v * ((const float*)&wv[u])[kw];
            }
        }
    }
    size_t obase = (((size_t)b * Co + oc0) * Ho + oh) * Ho + ow;
    size_t oplane = (size_t)Ho * Ho;
    float* dst = P + (size_t)ks * outSize;
#pragma unroll
    for (int u = 0; u < 8; ++u) dst[obase + u * oplane] = acc[u];
}

// sum KS partial slices + bias -> y
__global__ void reduce_bias(const float* __restrict__ P, const float* __restrict__ bias,
                            float* __restrict__ y, int outSize, int KS, int Co, int HW) {
    int i = blockIdx.x * 256 + threadIdx.x;
    if (i >= outSize) return;
    float s = bias[(i / HW) % Co];
    for (int ks = 0; ks < KS; ++ks) s += P[(size_t)ks * outSize + i];
    y[i] = s;
}

// ================= BatchNorm (training): partial sums per (c,b) =================
__global__ void bn_part(const float* __restrict__ y, float* __restrict__ bnp,
                        int B, int C, int HW) {
    int blk = blockIdx.x;          // c*B + b
    int c = blk / B, b = blk % B;
    int tid = threadIdx.x;
    const float* p = y + ((size_t)b * C + c) * HW;
    float s = 0.f, s2 = 0.f;
    for (int i = tid; i < HW; i += 256) {
        float v = p[i];
        s += v; s2 += v * v;
    }
    __shared__ float ls[256], ls2[256];
    ls[tid] = s; ls2[tid] = s2;
    __syncthreads();
    for (int off = 128; off > 0; off >>= 1) {
        if (tid < off) { ls[tid] += ls[tid + off]; ls2[tid] += ls2[tid + off]; }
        __syncthreads();
    }
    if (tid == 0) { bnp[blk * 2] = ls[0]; bnp[blk * 2 + 1] = ls2[0]; }
}

__global__ void bn_finish(const float* __restrict__ bnp, const float* __restrict__ g,
                          const float* __restrict__ bt, float* __restrict__ sc,
                          float* __restrict__ sh, int B, int C, float invN) {
    int c = blockIdx.x * 256 + threadIdx.x;
    if (c >= C) return;
    float s = 0.f, s2 = 0.f;
    for (int b = 0; b < B; ++b) {
        s  += bnp[(c * B + b) * 2];
        s2 += bnp[(c * B + b) * 2 + 1];
    }
    float m = s * invN;
    float var = s2 * invN - m * m;
    float rstd = 1.0f / sqrtf(var + 1e-5f);
    float scale = g[c] * rstd;
    sc[c] = scale;
    sh[c] = bt[c] - m * scale;
}

__global__ void bn_apply(float* __restrict__ y, const float* __restrict__ sc,
                         const float* __restrict__ sh, int C, int HW, int total) {
    int i = blockIdx.x * 256 + threadIdx.x;
    if (i >= total) return;
    int c = (i / HW) % C;
    float v = y[i] * sc[c] + sh[c];
    y[i] = v >= 0.f ? v : LEAK * v;
}

// ================= Vector quantizer =================
#define OUT_CL   786432
#define OUT_CB   786433
#define OUT_IDX  786434
#define OUT_MIND 787458

// cbT[c*512 + k] = cb[k*256 + c]
__global__ void vq_prep(const float* __restrict__ cb, float* __restrict__ cbT) {
    int idx = blockIdx.x * 256 + threadIdx.x;   // 131072
    int k = idx & 511, c = idx >> 9;
    cbT[idx] = cb[k * 256 + c];
}

__global__ void vq_norm(const float* __restrict__ cb, float* __restrict__ cn) {
    int k = blockIdx.x * 256 + threadIdx.x;     // 512
    if (k >= 512) return;
    float s = 0.f;
    for (int c = 0; c < 256; ++c) { float v = cb[k * 256 + c]; s += v * v; }
    cn[k] = s;
}

// 8 latent rows per block; 256 threads; thread t evaluates codes t and t+256.
__global__ void vq_main(const float* __restrict__ z, const float* __restrict__ cbT,
                        const float* __restrict__ cn, const float* __restrict__ cb,
                        float* __restrict__ q, float* __restrict__ dout) {
    int r0 = blockIdx.x * 8;       // 128 blocks
    int tid = threadIdx.x;

    __shared__ float zT[256][8];   // [c][row]
    __shared__ float red[256][9];  // padded
    __shared__ float zn2[8];
    __shared__ float rd[256];
    __shared__ int   ri[256];
    __shared__ int   bestsh[8];

#pragma unroll
    for (int rr = 0; rr < 8; ++rr) {
        int r = r0 + rr, b = r >> 6, s = r & 63;
        zT[tid][rr] = z[((size_t)(b * 256 + tid)) * 64 + s];
    }
    __syncthreads();
#pragma unroll
    for (int rr = 0; rr < 8; ++rr) { float v = zT[tid][rr]; red[tid][rr] = v * v; }
    __syncthreads();
    for (int off = 128; off > 0; off >>= 1) {
        if (tid < off) {
#pragma unroll
            for (int rr = 0; rr < 8; ++rr) red[tid][rr] += red[tid + off][rr];
        }
        __syncthreads();
    }
    if (tid < 8) zn2[tid] = red[0][tid];
    __syncthreads();

    float d0[8], d1[8];
#pragma unroll
    for (int rr = 0; rr < 8; ++rr) { d0[rr] = 0.f; d1[rr] = 0.f; }

    for (int c = 0; c < 256; ++c) {
        float cv0 = cbT[c * 512 + tid];
        float cv1 = cbT[c * 512 + 256 + tid];
        float4 za = *(const float4*)&zT[c][0];
        float4 zb = *(const float4*)&zT[c][4];
        const float* zv = (const float*)&za;
        const float* zw = (const float*)&zb;
#pragma unroll
        for (int rr = 0; rr < 4; ++rr) {
            d0[rr]     += zv[rr] * cv0;  d1[rr]     += zv[rr] * cv1;
            d0[rr + 4] += zw[rr] * cv0;  d1[rr + 4] += zw[rr] * cv1;
        }
    }

    float c0 = cn[tid], c1 = cn[tid + 256];
#pragma unroll
    for (int rr = 0; rr < 8; ++rr) {
        float dist0 = zn2[rr] - 2.f * d0[rr] + c0;
        float dist1 = zn2[rr] - 2.f * d1[rr] + c1;
        float bd = dist0; int bi = tid;
        if (dist1 < bd) { bd = dist1; bi = tid + 256; }
        rd[tid] = bd; ri[tid] = bi;
        __syncthreads();
        for (int off = 128; off > 0; off >>= 1) {
            if (tid < off) {
                float od = rd[tid + off]; int oi = ri[tid + off];
                if (od < rd[tid] || (od == rd[tid] && oi < ri[tid])) { rd[tid] = od; ri[tid] = oi; }
            }
            __syncthreads();
        }
        if (tid == 0) {
            int r = r0 + rr;
            bestsh[rr] = ri[0];
            dout[OUT_IDX + r]  = (float)ri[0];
            dout[OUT_MIND + r] = rd[0];
        }
        __syncthreads();
    }

#pragma unroll
    for (int rr = 0; rr < 8; ++rr) {
        int r = r0 + rr, b = r >> 6, s = r & 63;
        q[((size_t)(b * 256 + tid)) * 64 + s] = cb[(size_t)bestsh[rr] * 256 + tid];
    }
}

__global__ void vq_loss(float* __restrict__ dout) {
    int tid = threadIdx.x;
    __shared__ float red[256];
    float s = 0.f;
    for (int i = tid; i < 1024; i += 256) s += dout[OUT_MIND + i];
    red[tid] = s;
    __syncthreads();
    for (int off = 128; off > 0; off >>= 1) {
        if (tid < off) red[tid] += red[tid + off];
        __syncthreads();
    }
    if (tid == 0) {
        float loss = red[0] / 262144.f;
        dout[OUT_CL] = loss;
        dout[OUT_CB] = loss;
    }
}

// ================= ConvTranspose (stride==k) =================
// wtT[(i*k+j)*Ci*Co + c*Co + o]  (pre-transposed), 16 oc per thread, optional split-K.
__global__ void transpose_wt(const float* __restrict__ wt, float* __restrict__ wtT,
                             int Ci, int Co, int kk, int total) {
    int idx = blockIdx.x * 256 + threadIdx.x;
    if (idx >= total) return;
    int o = idx % Co; int t = idx / Co;
    int c = t % Ci;   int ij = t / Ci;
    wtT[idx] = wt[((size_t)c * Co + o) * kk + ij];
}

__global__ void convt16(const float* __restrict__ x, const float* __restrict__ wtT,
                        const float* __restrict__ bias, float* __restrict__ P,
                        int B, int Ci, int Hin, int Co, int k,
                        int KS, int icsl, int outSize) {
    int Ho = Hin * k;
    int ogn = Co >> 4;
    int idx = blockIdx.x * 256 + threadIdx.x;
    int total = B * ogn * Ho * Ho * KS;
    if (idx >= total) return;
    int ow = idx % Ho; int t = idx / Ho;
    int oh = t % Ho;   t /= Ho;
    int og = t % ogn;  t /= ogn;
    int b  = t % B;
    int ks = t / B;
    int o0 = og << 4;
    int ic0 = ks * icsl;

    int h = oh / k, i = oh % k;
    int w = ow / k, j = ow % k;

    float acc[16];
#pragma unroll
    for (int u = 0; u < 16; ++u) acc[u] = 0.f;
    if (KS == 1) {
#pragma unroll
        for (int u = 0; u < 16; ++u) acc[u] = bias[o0 + u];
    }

    size_t HinHin = (size_t)Hin * Hin;
    const float* xp = x + ((size_t)b * Ci + ic0) * HinHin + (size_t)h * Hin + w;
    const float* wp = wtT + ((size_t)(i * k + j) * Ci + ic0) * Co + o0;

    for (int c = 0; c < icsl; ++c) {
        float v = xp[c * HinHin];
        const float* wr = wp + (size_t)c * Co;
        float4 w0 = *(const float4*)(wr);
        float4 w1 = *(const float4*)(wr + 4);
        float4 w2 = *(const float4*)(wr + 8);
        float4 w3 = *(const float4*)(wr + 12);
#pragma unroll
        for (int u = 0; u < 4; ++u) {
            acc[u]      += v * ((const float*)&w0)[u];
            acc[u + 4]  += v * ((const float*)&w1)[u];
            acc[u + 8]  += v * ((const float*)&w2)[u];
            acc[u + 12] += v * ((const float*)&w3)[u];
        }
    }
    size_t obase = (((size_t)b * Co + o0) * Ho + oh) * Ho + ow;
    size_t oplane = (size_t)Ho * Ho;
    float* dst = P + (size_t)ks * outSize;
#pragma unroll
    for (int u = 0; u < 16; ++u) dst[obase + u * oplane] = acc[u];
}

// ================= Final 1x1 conv (32->3) + tanh =================
__global__ void final_conv_tanh(const float* __restrict__ hbuf, const float* __restrict__ w3,
                                const float* __restrict__ b3, float* __restrict__ out) {
    int idx = blockIdx.x * 256 + threadIdx.x;
    if (idx >= 16 * 16384) return;
    int hw = idx % 16384;
    int b  = idx / 16384;
    const float* hp = hbuf + ((size_t)b * 32) * 16384 + hw;
    float a0 = b3[0], a1 = b3[1], a2 = b3[2];
#pragma unroll
    for (int c = 0; c < 32; ++c) {
        float v = hp[(size_t)c * 16384];
        a0 += v * w3[c];
        a1 += v * w3[32 + c];
        a2 += v * w3[64 + c];
    }
    size_t ob = ((size_t)b * 3) * 16384 + hw;
    out[ob]             = tanhf(a0);
    out[ob + 16384]     = tanhf(a1);
    out[ob + 2 * 16384] = tanhf(a2);
}

extern "C" void kernel_launch(void* const* d_in, const int* in_sizes, int n_in,
                              void* d_out, int out_size, void* d_ws, size_t ws_size,
                              hipStream_t stream) {
    const float* x      = (const float*)d_in[0];
    const float* enc_w0 = (const float*)d_in[1];
    const float* enc_b0 = (const float*)d_in[2];
    const float* enc_w1 = (const float*)d_in[3];
    const float* enc_b1 = (const float*)d_in[4];
    const float* enc_w2 = (const float*)d_in[5];
    const float* enc_b2 = (const float*)d_in[6];
    const float* enc_w3 = (const float*)d_in[7];
    const float* enc_b3 = (const float*)d_in[8];
    const float* ebn_g0 = (const float*)d_in[9];
    const float* ebn_b0 = (const float*)d_in[10];
    const float* ebn_g1 = (const float*)d_in[11];
    const float* ebn_b1 = (const float*)d_in[12];
    const float* ebn_g2 = (const float*)d_in[13];
    const float* ebn_b2 = (const float*)d_in[14];
    const float* cb     = (const float*)d_in[15];
    const float* dec_w0 = (const float*)d_in[16];
    const float* dec_b0 = (const float*)d_in[17];
    const float* dbn_g0 = (const float*)d_in[18];
    const float* dbn_b0 = (const float*)d_in[19];
    const float* dec_w1 = (const float*)d_in[20];
    const float* dec_b1 = (const float*)d_in[21];
    const float* dbn_g1 = (const float*)d_in[22];
    const float* dbn_b1 = (const float*)d_in[23];
    const float* dec_w2 = (const float*)d_in[24];
    const float* dec_b2 = (const float*)d_in[25];
    const float* dbn_g2 = (const float*)d_in[26];
    const float* dbn_b2 = (const float*)d_in[27];
    const float* dec_w3 = (const float*)d_in[28];
    const float* dec_b3 = (const float*)d_in[29];

    float* out = (float*)d_out;
    float* ws  = (float*)d_ws;

    // ---- workspace layout (floats), liveness-based reuse; footprint == round-1 (58.7 MB) ----
    float* Y0   = ws;              // (16,64,64,64)   4194304
    float* Y1   = ws + 4194304;    // (16,128,32,32)  2097152
    float* Y2   = ws + 6291456;    // (16,256,16,16)  1048576
    float* Z    = ws + 7340032;    // (16,256,8,8)     262144
    float* Q    = ws + 7602176;    // (16,256,8,8)     262144
    float* D0   = ws;              // (16,128,32,32)  2097152  (Y0 dead)
    float* D1   = ws + 2097152;    // (16,64,64,64)   4194304
    float* D2   = ws + 6291456;    // (16,32,128,128) 8388608
    float* SC   = ws + 14680064;   // 256
    float* SH   = ws + 14680320;   // 256
    // transient buffers in dead regions:
    float* P1   = ws + 6291456;    // enc1 partials  2*2097152 (Y2..D2 area, dead then)
    float* P2   = ws;              // enc2 partials  4*1048576 (Y0 dead)
    float* P3   = ws;              // enc3 partials  8*262144  (Y0/Y1 dead)
    float* PD0  = ws + 2097152;    // dec0 partials  2*2097152 (Y0hi/Y1 dead)
    float* CBT  = ws;              // 131072 (during VQ; Y0 dead)
    float* CNRM = ws + 131072;     // 512
    float* WT1  = ws + 6291456;    // dec1 wtT 32768   (D2 area, consumed before dec2)
    float* WT0  = ws + 6324224;    // dec0 wtT 524288  (D2 area, consumed before dec2)
    float* WT2  = ws + 7610368;    // dec2 wtT 8192    (Q area, Q dead by then)
    float* BNP  = ws + 7602176;    // bn partials 8192 (Q area; transient around each bn)

    dim3 blk(256);

    // ---- encoder ----
    // enc0: Ci=3, 128->64, Co=64, KS=1 : 2048 blocks
    conv_k4s2p1_ks<<<2048, blk, 0, stream>>>(x, enc_w0, enc_b0, Y0, 16, 3, 128, 64, 64, 1, 3, 4194304);
    bn_part<<<64 * 16, blk, 0, stream>>>(Y0, BNP, 16, 64, 4096);
    bn_finish<<<1, blk, 0, stream>>>(BNP, ebn_g0, ebn_b0, SC, SH, 16, 64, 1.f / 65536.f);
    bn_apply<<<16384, blk, 0, stream>>>(Y0, SC, SH, 64, 4096, 4194304);

    // enc1: Ci=64, 64->32, Co=128, KS=2 : 2048 blocks
    conv_k4s2p1_ks<<<2048, blk, 0, stream>>>(Y0, enc_w1, enc_b1, P1, 16, 64, 64, 128, 32, 2, 32, 2097152);
    reduce_bias<<<8192, blk, 0, stream>>>(P1, enc_b1, Y1, 2097152, 2, 128, 1024);
    bn_part<<<128 * 16, blk, 0, stream>>>(Y1, BNP, 16, 128, 1024);
    bn_finish<<<1, blk, 0, stream>>>(BNP, ebn_g1, ebn_b1, SC, SH, 16, 128, 1.f / 16384.f);
    bn_apply<<<8192, blk, 0, stream>>>(Y1, SC, SH, 128, 1024, 2097152);

    // enc2: Ci=128, 32->16, Co=256, KS=4 : 2048 blocks
    conv_k4s2p1_ks<<<2048, blk, 0, stream>>>(Y1, enc_w2, enc_b2, P2, 16, 128, 32, 256, 16, 4, 32, 1048576);
    reduce_bias<<<4096, blk, 0, stream>>>(P2, enc_b2, Y2, 1048576, 4, 256, 256);
    bn_part<<<256 * 16, blk, 0, stream>>>(Y2, BNP, 16, 256, 256);
    bn_finish<<<1, blk, 0, stream>>>(BNP, ebn_g2, ebn_b2, SC, SH, 16, 256, 1.f / 4096.f);
    bn_apply<<<4096, blk, 0, stream>>>(Y2, SC, SH, 256, 256, 1048576);

    // enc3: Ci=256, 16->8, Co=256, KS=8 : 1024 blocks
    conv_k4s2p1_ks<<<1024, blk, 0, stream>>>(Y2, enc_w3, enc_b3, P3, 16, 256, 16, 256, 8, 8, 32, 262144);
    reduce_bias<<<1024, blk, 0, stream>>>(P3, enc_b3, Z, 262144, 8, 256, 64);

    // ---- vector quantizer ----
    vq_prep<<<512, blk, 0, stream>>>(cb, CBT);
    vq_norm<<<2, blk, 0, stream>>>(cb, CNRM);
    vq_main<<<128, blk, 0, stream>>>(Z, CBT, CNRM, cb, Q, out);
    vq_loss<<<1, blk, 0, stream>>>(out);

    // ---- decoder ----
    // dec0: Ci=256, 8->32 (k=4), Co=128, KS=2 : 1024 blocks
    transpose_wt<<<2048, blk, 0, stream>>>(dec_w0, WT0, 256, 128, 16, 524288);
    convt16<<<1024, blk, 0, stream>>>(Q, WT0, dec_b0, PD0, 16, 256, 8, 128, 4, 2, 128, 2097152);
    reduce_bias<<<8192, blk, 0, stream>>>(PD0, dec_b0, D0, 2097152, 2, 128, 1024);
    bn_part<<<128 * 16, blk, 0, stream>>>(D0, BNP, 16, 128, 1024);
    bn_finish<<<1, blk, 0, stream>>>(BNP, dbn_g0, dbn_b0, SC, SH, 16, 128, 1.f / 16384.f);
    bn_apply<<<8192, blk, 0, stream>>>(D0, SC, SH, 128, 1024, 2097152);

    // dec1: Ci=128, 32->64 (k=2), Co=64, KS=1 : 1024 blocks
    transpose_wt<<<128, blk, 0, stream>>>(dec_w1, WT1, 128, 64, 4, 32768);
    convt16<<<1024, blk, 0, stream>>>(D0, WT1, dec_b1, D1, 16, 128, 32, 64, 2, 1, 128, 4194304);
    bn_part<<<64 * 16, blk, 0, stream>>>(D1, BNP, 16, 64, 4096);
    bn_finish<<<1, blk, 0, stream>>>(BNP, dbn_g1, dbn_b1, SC, SH, 16, 64, 1.f / 65536.f);
    bn_apply<<<16384, blk, 0, stream>>>(D1, SC, SH, 64, 4096, 4194304);

    // dec2: Ci=64, 64->128 (k=2), Co=32, KS=1 : 2048 blocks
    transpose_wt<<<32, blk, 0, stream>>>(dec_w2, WT2, 64, 32, 4, 8192);
    convt16<<<2048, blk, 0, stream>>>(D1, WT2, dec_b2, D2, 16, 64, 64, 32, 2, 1, 64, 8388608);
    bn_part<<<32 * 16, blk, 0, stream>>>(D2, BNP, 16, 32, 16384);
    bn_finish<<<1, blk, 0, stream>>>(BNP, dbn_g2, dbn_b2, SC, SH, 16, 32, 1.f / 262144.f);
    bn_apply<<<32768, blk, 0, stream>>>(D2, SC, SH, 32, 16384, 8388608);

    final_conv_tanh<<<1024, blk, 0, stream>>>(D2, dec_w3, dec_b3, out);
}

// Round 3
// 1115.287 us; speedup vs baseline: 2.3744x; 1.7446x over previous
//
#include <hip/hip_runtime.h>
#include <math.h>

#define LEAK 0.01f

// ================= Conv2d k=4 s=2 p=1, NCHW/OIHW =================
// Block-uniform (og, ks) -> weight reads become s_load (scalar pipe).
// Each thread: 1 output pixel, OCT output channels. Branch-free padding via
// clamped offsets + mask multiply.
template<int OCT>
__global__ __launch_bounds__(256) void conv4x4(
    const float* __restrict__ x, const float* __restrict__ w,
    const float* __restrict__ bias, float* __restrict__ P,
    int B, int Ci, int Hin, int Co, int Ho,
    int KS, int icsl, int outSize)
{
    int ogn = Co / OCT;
    int ntile = (B * Ho * Ho) >> 8;
    int bid = blockIdx.x;
    int tile = bid % ntile; bid /= ntile;
    int og = bid % ogn;
    int ks = bid / ogn;          // uniform per block
    int oc0 = og * OCT, ic0 = ks * icsl;

    int px = (tile << 8) + threadIdx.x;
    int ow = px % Ho; int t = px / Ho;
    int oh = t % Ho;  int b = t / Ho;

    // precompute clamped offsets + masks once (loop-invariant)
    int off[16]; float fm[16];
    int ih0 = oh * 2 - 1, iw0 = ow * 2 - 1;
#pragma unroll
    for (int kh = 0; kh < 4; ++kh) {
#pragma unroll
        for (int kw = 0; kw < 4; ++kw) {
            int ih = ih0 + kh, iw = iw0 + kw;
            bool ok = (ih >= 0) && (ih < Hin) && (iw >= 0) && (iw < Hin);
            int ihc = ih < 0 ? 0 : (ih >= Hin ? Hin - 1 : ih);
            int iwc = iw < 0 ? 0 : (iw >= Hin ? Hin - 1 : iw);
            off[kh * 4 + kw] = ihc * Hin + iwc;
            fm[kh * 4 + kw] = ok ? 1.f : 0.f;
        }
    }

    float acc[OCT];
#pragma unroll
    for (int u = 0; u < OCT; ++u) acc[u] = (KS == 1) ? bias[oc0 + u] : 0.f;

    const float* xc = x + ((size_t)b * Ci + ic0) * Hin * Hin;
    const float* wi = w + ((size_t)oc0 * Ci + ic0) * 16;
    int HinHin = Hin * Hin;

    for (int ic = 0; ic < icsl; ++ic) {
        float xv[16];
#pragma unroll
        for (int q = 0; q < 16; ++q) xv[q] = xc[off[q]] * fm[q];
#pragma unroll
        for (int u = 0; u < OCT; ++u) {
            const float* wo = wi + (size_t)u * Ci * 16;   // uniform -> s_load_dwordx16
            float a = acc[u];
#pragma unroll
            for (int q = 0; q < 16; ++q) a += xv[q] * wo[q];
            acc[u] = a;
        }
        xc += HinHin;
        wi += 16;
    }
    float* dst = P + (size_t)ks * outSize;
    size_t obase = (((size_t)b * Co + oc0) * Ho + oh) * Ho + ow;
    size_t opl = (size_t)Ho * Ho;
#pragma unroll
    for (int u = 0; u < OCT; ++u) dst[obase + u * opl] = acc[u];
}

// sum KS partial float4 slices + bias -> y
__global__ void reduce_bias4(const float4* __restrict__ P, const float* __restrict__ bias,
                             float4* __restrict__ y, int outSize4, int KS, int Co, int HW4) {
    int i = blockIdx.x * 256 + threadIdx.x;
    if (i >= outSize4) return;
    float bv = bias[(i / HW4) % Co];
    float4 s = make_float4(bv, bv, bv, bv);
    for (int ks = 0; ks < KS; ++ks) {
        float4 p = P[(size_t)ks * outSize4 + i];
        s.x += p.x; s.y += p.y; s.z += p.z; s.w += p.w;
    }
    y[i] = s;
}

// ================= BatchNorm (training) =================
__global__ void bn_part(const float* __restrict__ y, float* __restrict__ bnp,
                        int B, int C, int HW) {
    int blk = blockIdx.x;          // c*B + b
    int c = blk / B, b = blk % B;
    int tid = threadIdx.x;
    const float* p = y + ((size_t)b * C + c) * HW;
    float s = 0.f, s2 = 0.f;
    for (int i = tid; i < HW; i += 256) {
        float v = p[i];
        s += v; s2 += v * v;
    }
    __shared__ float ls[256], ls2[256];
    ls[tid] = s; ls2[tid] = s2;
    __syncthreads();
    for (int off = 128; off > 0; off >>= 1) {
        if (tid < off) { ls[tid] += ls[tid + off]; ls2[tid] += ls2[tid + off]; }
        __syncthreads();
    }
    if (tid == 0) { bnp[blk * 2] = ls[0]; bnp[blk * 2 + 1] = ls2[0]; }
}

__global__ void bn_finish(const float* __restrict__ bnp, const float* __restrict__ g,
                          const float* __restrict__ bt, float* __restrict__ sc,
                          float* __restrict__ sh, int B, int C, float invN) {
    int c = blockIdx.x * 256 + threadIdx.x;
    if (c >= C) return;
    float s = 0.f, s2 = 0.f;
    for (int b = 0; b < B; ++b) {
        s  += bnp[(c * B + b) * 2];
        s2 += bnp[(c * B + b) * 2 + 1];
    }
    float m = s * invN;
    float var = s2 * invN - m * m;
    float rstd = 1.0f / sqrtf(var + 1e-5f);
    float scale = g[c] * rstd;
    sc[c] = scale;
    sh[c] = bt[c] - m * scale;
}

__global__ void bn_apply4(float4* __restrict__ y, const float* __restrict__ sc,
                          const float* __restrict__ sh, int C, int HW4, int total4) {
    int i = blockIdx.x * 256 + threadIdx.x;
    if (i >= total4) return;
    int c = (i / HW4) % C;
    float s = sc[c], h = sh[c];
    float4 v = y[i];
    v.x = v.x * s + h; v.x = v.x >= 0.f ? v.x : LEAK * v.x;
    v.y = v.y * s + h; v.y = v.y >= 0.f ? v.y : LEAK * v.y;
    v.z = v.z * s + h; v.z = v.z >= 0.f ? v.z : LEAK * v.z;
    v.w = v.w * s + h; v.w = v.w >= 0.f ? v.w : LEAK * v.w;
    y[i] = v;
}

// ================= Vector quantizer (unchanged from round 2 - verified) =================
#define OUT_CL   786432
#define OUT_CB   786433
#define OUT_IDX  786434
#define OUT_MIND 787458

__global__ void vq_prep(const float* __restrict__ cb, float* __restrict__ cbT) {
    int idx = blockIdx.x * 256 + threadIdx.x;   // 131072
    int k = idx & 511, c = idx >> 9;
    cbT[idx] = cb[k * 256 + c];
}

__global__ void vq_norm(const float* __restrict__ cb, float* __restrict__ cn) {
    int k = blockIdx.x * 256 + threadIdx.x;     // 512
    if (k >= 512) return;
    float s = 0.f;
    for (int c = 0; c < 256; ++c) { float v = cb[k * 256 + c]; s += v * v; }
    cn[k] = s;
}

__global__ void vq_main(const float* __restrict__ z, const float* __restrict__ cbT,
                        const float* __restrict__ cn, const float* __restrict__ cb,
                        float* __restrict__ q, float* __restrict__ dout) {
    int r0 = blockIdx.x * 8;       // 128 blocks
    int tid = threadIdx.x;

    __shared__ float zT[256][8];
    __shared__ float red[256][9];
    __shared__ float zn2[8];
    __shared__ float rd[256];
    __shared__ int   ri[256];
    __shared__ int   bestsh[8];

#pragma unroll
    for (int rr = 0; rr < 8; ++rr) {
        int r = r0 + rr, b = r >> 6, s = r & 63;
        zT[tid][rr] = z[((size_t)(b * 256 + tid)) * 64 + s];
    }
    __syncthreads();
#pragma unroll
    for (int rr = 0; rr < 8; ++rr) { float v = zT[tid][rr]; red[tid][rr] = v * v; }
    __syncthreads();
    for (int off = 128; off > 0; off >>= 1) {
        if (tid < off) {
#pragma unroll
            for (int rr = 0; rr < 8; ++rr) red[tid][rr] += red[tid + off][rr];
        }
        __syncthreads();
    }
    if (tid < 8) zn2[tid] = red[0][tid];
    __syncthreads();

    float d0[8], d1[8];
#pragma unroll
    for (int rr = 0; rr < 8; ++rr) { d0[rr] = 0.f; d1[rr] = 0.f; }

    for (int c = 0; c < 256; ++c) {
        float cv0 = cbT[c * 512 + tid];
        float cv1 = cbT[c * 512 + 256 + tid];
        float4 za = *(const float4*)&zT[c][0];
        float4 zb = *(const float4*)&zT[c][4];
        const float* zv = (const float*)&za;
        const float* zw = (const float*)&zb;
#pragma unroll
        for (int rr = 0; rr < 4; ++rr) {
            d0[rr]     += zv[rr] * cv0;  d1[rr]     += zv[rr] * cv1;
            d0[rr + 4] += zw[rr] * cv0;  d1[rr + 4] += zw[rr] * cv1;
        }
    }

    float c0 = cn[tid], c1 = cn[tid + 256];
#pragma unroll
    for (int rr = 0; rr < 8; ++rr) {
        float dist0 = zn2[rr] - 2.f * d0[rr] + c0;
        float dist1 = zn2[rr] - 2.f * d1[rr] + c1;
        float bd = dist0; int bi = tid;
        if (dist1 < bd) { bd = dist1; bi = tid + 256; }
        rd[tid] = bd; ri[tid] = bi;
        __syncthreads();
        for (int off = 128; off > 0; off >>= 1) {
            if (tid < off) {
                float od = rd[tid + off]; int oi = ri[tid + off];
                if (od < rd[tid] || (od == rd[tid] && oi < ri[tid])) { rd[tid] = od; ri[tid] = oi; }
            }
            __syncthreads();
        }
        if (tid == 0) {
            int r = r0 + rr;
            bestsh[rr] = ri[0];
            dout[OUT_IDX + r]  = (float)ri[0];
            dout[OUT_MIND + r] = rd[0];
        }
        __syncthreads();
    }

#pragma unroll
    for (int rr = 0; rr < 8; ++rr) {
        int r = r0 + rr, b = r >> 6, s = r & 63;
        q[((size_t)(b * 256 + tid)) * 64 + s] = cb[(size_t)bestsh[rr] * 256 + tid];
    }
}

__global__ void vq_loss(float* __restrict__ dout) {
    int tid = threadIdx.x;
    __shared__ float red[256];
    float s = 0.f;
    for (int i = tid; i < 1024; i += 256) s += dout[OUT_MIND + i];
    red[tid] = s;
    __syncthreads();
    for (int off = 128; off > 0; off >>= 1) {
        if (tid < off) red[tid] += red[tid + off];
        __syncthreads();
    }
    if (tid == 0) {
        float loss = red[0] / 262144.f;
        dout[OUT_CL] = loss;
        dout[OUT_CB] = loss;
    }
}

// ================= ConvTranspose (stride==k), block-uniform (og, ij) =================
// wtT[ij*Ci*Co + c*Co + o] pre-transposed -> s_load_dwordx16 weight rows.
__global__ void transpose_wt(const float* __restrict__ wt, float* __restrict__ wtT,
                             int Ci, int Co, int kk, int total) {
    int idx = blockIdx.x * 256 + threadIdx.x;
    if (idx >= total) return;
    int o = idx % Co; int t = idx / Co;
    int c = t % Ci;   int ij = t / Ci;
    wtT[idx] = wt[((size_t)c * Co + o) * kk + ij];
}

template<int OCT>
__global__ __launch_bounds__(256) void convt_ij(
    const float* __restrict__ x, const float* __restrict__ wtT,
    const float* __restrict__ bias, float* __restrict__ y,
    int B, int Ci, int Hin, int Co, int k)
{
    int hw = Hin * Hin;
    int ntile = (B * hw) >> 8;
    int kk = k * k;
    int bid = blockIdx.x;
    int tile = bid % ntile; bid /= ntile;
    int ij = bid % kk; bid /= kk;
    int og = bid;                   // uniform
    int oc0 = og * OCT;
    int i = ij / k, j = ij % k;

    int px = (tile << 8) + threadIdx.x;
    int wp = px % Hin; int t = px / Hin;
    int hp = t % Hin;  int b = t / Hin;

    float acc[OCT];
#pragma unroll
    for (int u = 0; u < OCT; ++u) acc[u] = bias[oc0 + u];

    const float* xp = x + ((size_t)b * Ci) * hw + hp * Hin + wp;
    const float* wo = wtT + ((size_t)ij * Ci) * Co + oc0;   // uniform
    for (int ic = 0; ic < Ci; ++ic) {
        float v = xp[(size_t)ic * hw];
#pragma unroll
        for (int u = 0; u < OCT; ++u)
            acc[u] += v * wo[u];
        wo += Co;
    }
    int Ho = Hin * k;
    size_t obase = (((size_t)b * Co + oc0) * Ho + (hp * k + i)) * Ho + (wp * k + j);
    size_t opl = (size_t)Ho * Ho;
#pragma unroll
    for (int u = 0; u < OCT; ++u) y[obase + u * opl] = acc[u];
}

// ================= Final 1x1 conv (32->3) + tanh =================
__global__ void final_conv_tanh(const float* __restrict__ hbuf, const float* __restrict__ w3,
                                const float* __restrict__ b3, float* __restrict__ out) {
    int idx = blockIdx.x * 256 + threadIdx.x;
    if (idx >= 16 * 16384) return;
    int hw = idx % 16384;
    int b  = idx / 16384;
    const float* hp = hbuf + ((size_t)b * 32) * 16384 + hw;
    float a0 = b3[0], a1 = b3[1], a2 = b3[2];
#pragma unroll
    for (int c = 0; c < 32; ++c) {
        float v = hp[(size_t)c * 16384];
        a0 += v * w3[c];
        a1 += v * w3[32 + c];
        a2 += v * w3[64 + c];
    }
    size_t ob = ((size_t)b * 3) * 16384 + hw;
    out[ob]             = tanhf(a0);
    out[ob + 16384]     = tanhf(a1);
    out[ob + 2 * 16384] = tanhf(a2);
}

extern "C" void kernel_launch(void* const* d_in, const int* in_sizes, int n_in,
                              void* d_out, int out_size, void* d_ws, size_t ws_size,
                              hipStream_t stream) {
    const float* x      = (const float*)d_in[0];
    const float* enc_w0 = (const float*)d_in[1];
    const float* enc_b0 = (const float*)d_in[2];
    const float* enc_w1 = (const float*)d_in[3];
    const float* enc_b1 = (const float*)d_in[4];
    const float* enc_w2 = (const float*)d_in[5];
    const float* enc_b2 = (const float*)d_in[6];
    const float* enc_w3 = (const float*)d_in[7];
    const float* enc_b3 = (const float*)d_in[8];
    const float* ebn_g0 = (const float*)d_in[9];
    const float* ebn_b0 = (const float*)d_in[10];
    const float* ebn_g1 = (const float*)d_in[11];
    const float* ebn_b1 = (const float*)d_in[12];
    const float* ebn_g2 = (const float*)d_in[13];
    const float* ebn_b2 = (const float*)d_in[14];
    const float* cb     = (const float*)d_in[15];
    const float* dec_w0 = (const float*)d_in[16];
    const float* dec_b0 = (const float*)d_in[17];
    const float* dbn_g0 = (const float*)d_in[18];
    const float* dbn_b0 = (const float*)d_in[19];
    const float* dec_w1 = (const float*)d_in[20];
    const float* dec_b1 = (const float*)d_in[21];
    const float* dbn_g1 = (const float*)d_in[22];
    const float* dbn_b1 = (const float*)d_in[23];
    const float* dec_w2 = (const float*)d_in[24];
    const float* dec_b2 = (const float*)d_in[25];
    const float* dbn_g2 = (const float*)d_in[26];
    const float* dbn_b2 = (const float*)d_in[27];
    const float* dec_w3 = (const float*)d_in[28];
    const float* dec_b3 = (const float*)d_in[29];

    float* out = (float*)d_out;
    float* ws  = (float*)d_ws;

    // ---- workspace (floats), liveness-verified; footprint 58.72 MB ----
    float* Y0   = ws;              // 0        .. 4194304   enc0 out
    float* Y1   = ws + 4194304;    // 4194304  .. 6291456   enc1 out
    float* Y2   = ws + 6291456;    // 6291456  .. 7340032   enc2 out
    float* Z    = ws + 7340032;    // 7340032  .. 7602176
    float* Q    = ws + 7602176;    // 7602176  .. 7864320
    float* P2   = ws;              // enc2 partials 2x1048576 (Y0 dead)
    float* P3   = ws;              // enc3 partials 16x262144 (Y0/Y1 dead)
    float* D0   = ws;              // 0        .. 2097152   dec0 out (post-VQ)
    float* D1   = ws + 2097152;    // 2097152  .. 6291456   dec1 out
    float* D2   = ws + 6291456;    // 6291456  .. 14680064  dec2 out
    float* CBT  = ws;              // 131072   (VQ phase; P3 dead)
    float* CNRM = ws + 131072;     // 512
    float* WT0  = ws + 6291456;    // 524288 (Y2/Z region, dead; consumed by dec0 < dec2)
    float* WT1  = ws + 6815744;    // 32768  (ends 6848512 < 7340032; consumed by dec1 < dec2)
    float* WT2  = ws;              // 8192   (D0 region; written after dec1 consumed D0)
    float* BNP  = ws + 7602176;    // 8192 transient (Q region; never live同时)
    float* SC   = ws + 14680064;   // 256
    float* SH   = ws + 14680320;   // 256

    dim3 blk(256);

    // ---- encoder ----
    // enc0: Ci=3 -> Co=64, 128->64.  tiles=256, og=4 -> 1024 blocks
    conv4x4<16><<<1024, blk, 0, stream>>>(x, enc_w0, enc_b0, Y0, 16, 3, 128, 64, 64, 1, 3, 0);
    bn_part<<<1024, blk, 0, stream>>>(Y0, BNP, 16, 64, 4096);
    bn_finish<<<1, blk, 0, stream>>>(BNP, ebn_g0, ebn_b0, SC, SH, 16, 64, 1.f / 65536.f);
    bn_apply4<<<4096, blk, 0, stream>>>((float4*)Y0, SC, SH, 64, 1024, 1048576);

    // enc1: Ci=64 -> Co=128, 64->32.  tiles=64, og=8 -> 512 blocks
    conv4x4<16><<<512, blk, 0, stream>>>(Y0, enc_w1, enc_b1, Y1, 16, 64, 64, 128, 32, 1, 64, 0);
    bn_part<<<2048, blk, 0, stream>>>(Y1, BNP, 16, 128, 1024);
    bn_finish<<<1, blk, 0, stream>>>(BNP, ebn_g1, ebn_b1, SC, SH, 16, 128, 1.f / 16384.f);
    bn_apply4<<<2048, blk, 0, stream>>>((float4*)Y1, SC, SH, 128, 256, 524288);

    // enc2: Ci=128 -> Co=256, 32->16.  tiles=16, og=16, KS=2 -> 512 blocks
    conv4x4<16><<<512, blk, 0, stream>>>(Y1, enc_w2, enc_b2, P2, 16, 128, 32, 256, 16, 2, 64, 1048576);
    reduce_bias4<<<1024, blk, 0, stream>>>((const float4*)P2, enc_b2, (float4*)Y2, 262144, 2, 256, 64);
    bn_part<<<4096, blk, 0, stream>>>(Y2, BNP, 16, 256, 256);
    bn_finish<<<1, blk, 0, stream>>>(BNP, ebn_g2, ebn_b2, SC, SH, 16, 256, 1.f / 4096.f);
    bn_apply4<<<1024, blk, 0, stream>>>((float4*)Y2, SC, SH, 256, 64, 262144);

    // enc3: Ci=256 -> Co=256, 16->8.  tiles=4, og=16, KS=16 -> 1024 blocks
    conv4x4<16><<<1024, blk, 0, stream>>>(Y2, enc_w3, enc_b3, P3, 16, 256, 16, 256, 8, 16, 16, 262144);
    reduce_bias4<<<256, blk, 0, stream>>>((const float4*)P3, enc_b3, (float4*)Z, 65536, 16, 256, 16);

    // ---- vector quantizer ----
    vq_prep<<<512, blk, 0, stream>>>(cb, CBT);
    vq_norm<<<2, blk, 0, stream>>>(cb, CNRM);
    vq_main<<<128, blk, 0, stream>>>(Z, CBT, CNRM, cb, Q, out);
    vq_loss<<<1, blk, 0, stream>>>(out);

    // ---- decoder ----
    // dec0: Ci=256, 8->32 (k=4), Co=128.  tiles=4, kk=16, og=8 -> 512 blocks
    transpose_wt<<<2048, blk, 0, stream>>>(dec_w0, WT0, 256, 128, 16, 524288);
    transpose_wt<<<128, blk, 0, stream>>>(dec_w1, WT1, 128, 64, 4, 32768);
    convt_ij<16><<<512, blk, 0, stream>>>(Q, WT0, dec_b0, D0, 16, 256, 8, 128, 4);
    bn_part<<<2048, blk, 0, stream>>>(D0, BNP, 16, 128, 1024);
    bn_finish<<<1, blk, 0, stream>>>(BNP, dbn_g0, dbn_b0, SC, SH, 16, 128, 1.f / 16384.f);
    bn_apply4<<<2048, blk, 0, stream>>>((float4*)D0, SC, SH, 128, 256, 524288);

    // dec1: Ci=128, 32->64 (k=2), Co=64.  tiles=64, kk=4, og=4 -> 1024 blocks
    convt_ij<16><<<1024, blk, 0, stream>>>(D0, WT1, dec_b1, D1, 16, 128, 32, 64, 2);
    transpose_wt<<<32, blk, 0, stream>>>(dec_w2, WT2, 64, 32, 4, 8192);   // D0 now dead
    bn_part<<<1024, blk, 0, stream>>>(D1, BNP, 16, 64, 4096);
    bn_finish<<<1, blk, 0, stream>>>(BNP, dbn_g1, dbn_b1, SC, SH, 16, 64, 1.f / 65536.f);
    bn_apply4<<<4096, blk, 0, stream>>>((float4*)D1, SC, SH, 64, 1024, 1048576);

    // dec2: Ci=64, 64->128 (k=2), Co=32.  tiles=256, kk=4, og=2 -> 2048 blocks
    convt_ij<16><<<2048, blk, 0, stream>>>(D1, WT2, dec_b2, D2, 16, 64, 64, 32, 2);
    bn_part<<<512, blk, 0, stream>>>(D2, BNP, 16, 32, 16384);
    bn_finish<<<1, blk, 0, stream>>>(BNP, dbn_g2, dbn_b2, SC, SH, 16, 32, 1.f / 262144.f);
    bn_apply4<<<8192, blk, 0, stream>>>((float4*)D2, SC, SH, 32, 4096, 2097152);

    final_conv_tanh<<<1024, blk, 0, stream>>>(D2, dec_w3, dec_b3, out);
}

// Round 4
// 909.196 us; speedup vs baseline: 2.9126x; 1.2267x over previous
//
#include <hip/hip_runtime.h>
#include <math.h>

#define LEAK 0.01f

// ================= Conv2d k=4 s=2 p=1, NCHW/OIHW =================
// Block-uniform (og, ks) -> weight reads on scalar pipe. Split-K over input
// channels: KS>1 writes partials (no bias), reduced later.
template<int OCT>
__global__ __launch_bounds__(256) void conv4x4(
    const float* __restrict__ x, const float* __restrict__ w,
    const float* __restrict__ bias, float* __restrict__ P,
    int B, int Ci, int Hin, int Co, int Ho,
    int KS, int icsl, int outSize)
{
    int ogn = Co / OCT;
    int ntile = (B * Ho * Ho) >> 8;
    int bid = blockIdx.x;
    int tile = bid % ntile; bid /= ntile;
    int og = bid % ogn;
    int ks = bid / ogn;          // uniform per block
    int oc0 = og * OCT, ic0 = ks * icsl;

    int px = (tile << 8) + threadIdx.x;
    int ow = px % Ho; int t = px / Ho;
    int oh = t % Ho;  int b = t / Ho;

    int off[16]; float fm[16];
    int ih0 = oh * 2 - 1, iw0 = ow * 2 - 1;
#pragma unroll
    for (int kh = 0; kh < 4; ++kh) {
#pragma unroll
        for (int kw = 0; kw < 4; ++kw) {
            int ih = ih0 + kh, iw = iw0 + kw;
            bool ok = (ih >= 0) && (ih < Hin) && (iw >= 0) && (iw < Hin);
            int ihc = ih < 0 ? 0 : (ih >= Hin ? Hin - 1 : ih);
            int iwc = iw < 0 ? 0 : (iw >= Hin ? Hin - 1 : iw);
            off[kh * 4 + kw] = ihc * Hin + iwc;
            fm[kh * 4 + kw] = ok ? 1.f : 0.f;
        }
    }

    float acc[OCT];
#pragma unroll
    for (int u = 0; u < OCT; ++u) acc[u] = (KS == 1) ? bias[oc0 + u] : 0.f;

    const float* xc = x + ((size_t)b * Ci + ic0) * Hin * Hin;
    const float* wi = w + ((size_t)oc0 * Ci + ic0) * 16;
    int HinHin = Hin * Hin;

    for (int ic = 0; ic < icsl; ++ic) {
        float xv[16];
#pragma unroll
        for (int q = 0; q < 16; ++q) xv[q] = xc[off[q]] * fm[q];
#pragma unroll
        for (int u = 0; u < OCT; ++u) {
            const float* wo = wi + (size_t)u * Ci * 16;   // uniform -> s_load
            float a = acc[u];
#pragma unroll
            for (int q = 0; q < 16; ++q) a += xv[q] * wo[q];
            acc[u] = a;
        }
        xc += HinHin;
        wi += 16;
    }
    float* dst = P + (size_t)ks * outSize;
    size_t obase = (((size_t)b * Co + oc0) * Ho + oh) * Ho + ow;
    size_t opl = (size_t)Ho * Ho;
#pragma unroll
    for (int u = 0; u < OCT; ++u) dst[obase + u * opl] = acc[u];
}

// ================= ConvTranspose (stride==k), block-uniform (og, ij, ks) =================
template<int OCT>
__global__ __launch_bounds__(256) void convt_ij(
    const float* __restrict__ x, const float* __restrict__ wtT,
    const float* __restrict__ bias, float* __restrict__ P,
    int B, int Ci, int Hin, int Co, int k,
    int KS, int icsl, int outSize)
{
    int hw = Hin * Hin;
    int ntile = (B * hw) >> 8;
    int kk = k * k;
    int ogn = Co / OCT;
    int bid = blockIdx.x;
    int tile = bid % ntile; bid /= ntile;
    int ij = bid % kk; bid /= kk;
    int og = bid % ogn;
    int ks = bid / ogn;
    int oc0 = og * OCT, ic0 = ks * icsl;
    int i = ij / k, j = ij % k;

    int px = (tile << 8) + threadIdx.x;
    int wp = px % Hin; int t = px / Hin;
    int hp = t % Hin;  int b = t / Hin;

    float acc[OCT];
#pragma unroll
    for (int u = 0; u < OCT; ++u) acc[u] = (KS == 1) ? bias[oc0 + u] : 0.f;

    const float* xp = x + ((size_t)b * Ci + ic0) * hw + hp * Hin + wp;
    const float* wo = wtT + ((size_t)ij * Ci + ic0) * Co + oc0;   // uniform
    for (int ic = 0; ic < icsl; ++ic) {
        float v = xp[(size_t)ic * hw];
#pragma unroll
        for (int u = 0; u < OCT; ++u)
            acc[u] += v * wo[u];
        wo += Co;
    }
    int Ho = Hin * k;
    float* dst = P + (size_t)ks * outSize;
    size_t obase = (((size_t)b * Co + oc0) * Ho + (hp * k + i)) * Ho + (wp * k + j);
    size_t opl = (size_t)Ho * Ho;
#pragma unroll
    for (int u = 0; u < OCT; ++u) dst[obase + u * opl] = acc[u];
}

// ================= reduce partials (+bias), optional fused BN stats =================
__global__ void reduce_bias4(const float4* __restrict__ P, const float* __restrict__ bias,
                             float4* __restrict__ y, int outSize4, int KS, int Co, int HW4) {
    int i = blockIdx.x * 256 + threadIdx.x;
    if (i >= outSize4) return;
    float bv = bias[(i / HW4) % Co];
    float4 s = make_float4(bv, bv, bv, bv);
    for (int ks = 0; ks < KS; ++ks) {
        float4 p = P[(size_t)ks * outSize4 + i];
        s.x += p.x; s.y += p.y; s.z += p.z; s.w += p.w;
    }
    y[i] = s;
}

// blocks of 256 float4 never cross a batch-plane; <=16 channels per block.
__global__ void reduce_bias_stats4(const float4* __restrict__ P, const float* __restrict__ bias,
                                   float4* __restrict__ y, float* __restrict__ bnt,
                                   int outSize4, int KS, int Co, int HW4, int nch) {
    int tid = threadIdx.x;
    int i = blockIdx.x * 256 + tid;
    int c = (i / HW4) % Co;
    float bv = bias[c];
    float4 s = make_float4(bv, bv, bv, bv);
    for (int ks = 0; ks < KS; ++ks) {
        float4 p = P[(size_t)ks * outSize4 + i];
        s.x += p.x; s.y += p.y; s.z += p.z; s.w += p.w;
    }
    y[i] = s;
    float ls  = s.x + s.y + s.z + s.w;
    float ls2 = s.x * s.x + s.y * s.y + s.z * s.z + s.w * s.w;
    __shared__ float as[16], aq[16];
    if (tid < 16) { as[tid] = 0.f; aq[tid] = 0.f; }
    __syncthreads();
    int c0 = ((blockIdx.x * 256) / HW4) % Co;
    atomicAdd(&as[c - c0], ls);
    atomicAdd(&aq[c - c0], ls2);
    __syncthreads();
    if (tid < nch) {
        atomicAdd(&bnt[(c0 + tid) * 2],     as[tid]);
        atomicAdd(&bnt[(c0 + tid) * 2 + 1], aq[tid]);
    }
}

// per-(c,b) stats -> atomic accumulate into per-channel totals
__global__ void bn_part_atomic(const float* __restrict__ y, float* __restrict__ bnt,
                               int B, int C, int HW) {
    int blk = blockIdx.x;          // c*B + b
    int c = blk / B, b = blk % B;
    int tid = threadIdx.x;
    const float* p = y + ((size_t)b * C + c) * HW;
    float s = 0.f, s2 = 0.f;
    for (int i = tid; i < HW; i += 256) {
        float v = p[i];
        s += v; s2 += v * v;
    }
    __shared__ float ls[256], ls2[256];
    ls[tid] = s; ls2[tid] = s2;
    __syncthreads();
    for (int off = 128; off > 0; off >>= 1) {
        if (tid < off) { ls[tid] += ls[tid + off]; ls2[tid] += ls2[tid + off]; }
        __syncthreads();
    }
    if (tid == 0) {
        atomicAdd(&bnt[c * 2],     ls[0]);
        atomicAdd(&bnt[c * 2 + 1], ls2[0]);
    }
}

// apply BN (from totals) + LeakyReLU, in place
__global__ void bn_apply4(float4* __restrict__ y, const float* __restrict__ bnt,
                          const float* __restrict__ g, const float* __restrict__ bt,
                          int C, int HW4, float invN) {
    int i = blockIdx.x * 256 + threadIdx.x;
    int c = (i / HW4) % C;
    float m = bnt[c * 2] * invN;
    float var = bnt[c * 2 + 1] * invN - m * m;
    float scale = g[c] * rsqrtf(var + 1e-5f);
    float shift = bt[c] - m * scale;
    float4 v = y[i];
    v.x = v.x * scale + shift; v.x = v.x >= 0.f ? v.x : LEAK * v.x;
    v.y = v.y * scale + shift; v.y = v.y >= 0.f ? v.y : LEAK * v.y;
    v.z = v.z * scale + shift; v.z = v.z >= 0.f ? v.z : LEAK * v.z;
    v.w = v.w * scale + shift; v.w = v.w >= 0.f ? v.w : LEAK * v.w;
    y[i] = v;
}

__global__ void zero_buf(float* __restrict__ p) {
    p[blockIdx.x * 256 + threadIdx.x] = 0.f;
}

// ================= Vector quantizer =================
#define OUT_CL   786432
#define OUT_CB   786433
#define OUT_IDX  786434
#define OUT_MIND 787458

__global__ void vq_prep(const float* __restrict__ cb, float* __restrict__ cbT) {
    int idx = blockIdx.x * 256 + threadIdx.x;   // 131072
    int k = idx & 511, c = idx >> 9;
    cbT[idx] = cb[k * 256 + c];
}

__global__ void vq_main(const float* __restrict__ z, const float* __restrict__ cbT,
                        const float* __restrict__ cb,
                        float* __restrict__ q, float* __restrict__ dout) {
    int r0 = blockIdx.x * 8;       // 128 blocks
    int tid = threadIdx.x;

    __shared__ float zT[256][8];
    __shared__ float red[256][9];
    __shared__ float zn2[8];
    __shared__ float rd[256];
    __shared__ int   ri[256];
    __shared__ int   bestsh[8];

#pragma unroll
    for (int rr = 0; rr < 8; ++rr) {
        int r = r0 + rr, b = r >> 6, s = r & 63;
        zT[tid][rr] = z[((size_t)(b * 256 + tid)) * 64 + s];
    }
    __syncthreads();
#pragma unroll
    for (int rr = 0; rr < 8; ++rr) { float v = zT[tid][rr]; red[tid][rr] = v * v; }
    __syncthreads();
    for (int off = 128; off > 0; off >>= 1) {
        if (tid < off) {
#pragma unroll
            for (int rr = 0; rr < 8; ++rr) red[tid][rr] += red[tid + off][rr];
        }
        __syncthreads();
    }
    if (tid < 8) zn2[tid] = red[0][tid];
    __syncthreads();

    float d0[8], d1[8];
#pragma unroll
    for (int rr = 0; rr < 8; ++rr) { d0[rr] = 0.f; d1[rr] = 0.f; }
    float cn0 = 0.f, cn1 = 0.f;

    for (int c = 0; c < 256; ++c) {
        float cv0 = cbT[c * 512 + tid];
        float cv1 = cbT[c * 512 + 256 + tid];
        cn0 += cv0 * cv0;
        cn1 += cv1 * cv1;
        float4 za = *(const float4*)&zT[c][0];
        float4 zb = *(const float4*)&zT[c][4];
        const float* zv = (const float*)&za;
        const float* zw = (const float*)&zb;
#pragma unroll
        for (int rr = 0; rr < 4; ++rr) {
            d0[rr]     += zv[rr] * cv0;  d1[rr]     += zv[rr] * cv1;
            d0[rr + 4] += zw[rr] * cv0;  d1[rr + 4] += zw[rr] * cv1;
        }
    }

#pragma unroll
    for (int rr = 0; rr < 8; ++rr) {
        float dist0 = zn2[rr] - 2.f * d0[rr] + cn0;
        float dist1 = zn2[rr] - 2.f * d1[rr] + cn1;
        float bd = dist0; int bi = tid;
        if (dist1 < bd) { bd = dist1; bi = tid + 256; }
        rd[tid] = bd; ri[tid] = bi;
        __syncthreads();
        for (int off = 128; off > 0; off >>= 1) {
            if (tid < off) {
                float od = rd[tid + off]; int oi = ri[tid + off];
                if (od < rd[tid] || (od == rd[tid] && oi < ri[tid])) { rd[tid] = od; ri[tid] = oi; }
            }
            __syncthreads();
        }
        if (tid == 0) {
            int r = r0 + rr;
            bestsh[rr] = ri[0];
            dout[OUT_IDX + r]  = (float)ri[0];
            dout[OUT_MIND + r] = rd[0];
        }
        __syncthreads();
    }

#pragma unroll
    for (int rr = 0; rr < 8; ++rr) {
        int r = r0 + rr, b = r >> 6, s = r & 63;
        q[((size_t)(b * 256 + tid)) * 64 + s] = cb[(size_t)bestsh[rr] * 256 + tid];
    }
}

__global__ void vq_loss(float* __restrict__ dout) {
    int tid = threadIdx.x;
    __shared__ float red[256];
    float s = 0.f;
    for (int i = tid; i < 1024; i += 256) s += dout[OUT_MIND + i];
    red[tid] = s;
    __syncthreads();
    for (int off = 128; off > 0; off >>= 1) {
        if (tid < off) red[tid] += red[tid + off];
        __syncthreads();
    }
    if (tid == 0) {
        float loss = red[0] / 262144.f;
        dout[OUT_CL] = loss;
        dout[OUT_CB] = loss;
    }
}

// ================= fused decoder-weight transposes =================
// wtT[ij*Ci*Co + c*Co + o] = wt[(c*Co+o)*kk + ij]
__global__ void transpose_all(const float* __restrict__ w0, const float* __restrict__ w1,
                              const float* __restrict__ w2, float* __restrict__ wt0,
                              float* __restrict__ wt1, float* __restrict__ wt2) {
    int idx = blockIdx.x * 256 + threadIdx.x;
    if (idx < 524288) {                       // Ci=256 Co=128 kk=16
        int o = idx % 128; int t = idx / 128;
        int c = t % 256;   int ij = t / 256;
        wt0[idx] = w0[((size_t)c * 128 + o) * 16 + ij];
    } else if (idx < 524288 + 32768) {        // Ci=128 Co=64 kk=4
        int i2 = idx - 524288;
        int o = i2 % 64;  int t = i2 / 64;
        int c = t % 128;  int ij = t / 128;
        wt1[i2] = w1[((size_t)c * 64 + o) * 4 + ij];
    } else if (idx < 524288 + 32768 + 8192) { // Ci=64 Co=32 kk=4
        int i3 = idx - 524288 - 32768;
        int o = i3 % 32;  int t = i3 / 32;
        int c = t % 64;   int ij = t / 64;
        wt2[i3] = w2[((size_t)c * 32 + o) * 4 + ij];
    }
}

// ================= Final 1x1 conv (32->3) + tanh =================
__global__ void final_conv_tanh(const float* __restrict__ hbuf, const float* __restrict__ w3,
                                const float* __restrict__ b3, float* __restrict__ out) {
    int idx = blockIdx.x * 256 + threadIdx.x;
    if (idx >= 16 * 16384) return;
    int hw = idx % 16384;
    int b  = idx / 16384;
    const float* hp = hbuf + ((size_t)b * 32) * 16384 + hw;
    float a0 = b3[0], a1 = b3[1], a2 = b3[2];
#pragma unroll
    for (int c = 0; c < 32; ++c) {
        float v = hp[(size_t)c * 16384];
        a0 += v * w3[c];
        a1 += v * w3[32 + c];
        a2 += v * w3[64 + c];
    }
    size_t ob = ((size_t)b * 3) * 16384 + hw;
    out[ob]             = tanhf(a0);
    out[ob + 16384]     = tanhf(a1);
    out[ob + 2 * 16384] = tanhf(a2);
}

extern "C" void kernel_launch(void* const* d_in, const int* in_sizes, int n_in,
                              void* d_out, int out_size, void* d_ws, size_t ws_size,
                              hipStream_t stream) {
    const float* x      = (const float*)d_in[0];
    const float* enc_w0 = (const float*)d_in[1];
    const float* enc_b0 = (const float*)d_in[2];
    const float* enc_w1 = (const float*)d_in[3];
    const float* enc_b1 = (const float*)d_in[4];
    const float* enc_w2 = (const float*)d_in[5];
    const float* enc_b2 = (const float*)d_in[6];
    const float* enc_w3 = (const float*)d_in[7];
    const float* enc_b3 = (const float*)d_in[8];
    const float* ebn_g0 = (const float*)d_in[9];
    const float* ebn_b0 = (const float*)d_in[10];
    const float* ebn_g1 = (const float*)d_in[11];
    const float* ebn_b1 = (const float*)d_in[12];
    const float* ebn_g2 = (const float*)d_in[13];
    const float* ebn_b2 = (const float*)d_in[14];
    const float* cb     = (const float*)d_in[15];
    const float* dec_w0 = (const float*)d_in[16];
    const float* dec_b0 = (const float*)d_in[17];
    const float* dbn_g0 = (const float*)d_in[18];
    const float* dbn_b0 = (const float*)d_in[19];
    const float* dec_w1 = (const float*)d_in[20];
    const float* dec_b1 = (const float*)d_in[21];
    const float* dbn_g1 = (const float*)d_in[22];
    const float* dbn_b1 = (const float*)d_in[23];
    const float* dec_w2 = (const float*)d_in[24];
    const float* dec_b2 = (const float*)d_in[25];
    const float* dbn_g2 = (const float*)d_in[26];
    const float* dbn_b2 = (const float*)d_in[27];
    const float* dec_w3 = (const float*)d_in[28];
    const float* dec_b3 = (const float*)d_in[29];

    float* out = (float*)d_out;
    float* ws  = (float*)d_ws;

    // ---- workspace layout (floats); total 16969728 fl = 64.7 MiB ----
    float* Y0   = ws;               // [0, 4194304)
    float* Y1   = ws + 4194304;     // [4194304, 6291456)
    float* Y2   = ws + 6291456;     // [6291456, 7340032)
    float* Z    = ws + 7340032;     // [7340032, 7602176)
    float* Q    = ws + 7602176;     // [7602176, 7864320)
    float* WT0  = ws + 7864320;     // 524288, dead after dec0 conv
    float* WT1  = ws + 8388608;     // 32768,  dead after dec1 conv
    float* CBT  = ws + 8429568;     // 131072, dead after vq_main
    float* PART = ws + 8566784;     // 8388608 shared split-K partials [.., 16955392)
    float* BNT  = ws + 16955392;    // 6144: six 1024-fl per-layer stat slots
    float* WT2  = ws + 16961536;    // 8192 (outside D2 region!)
    float* D0   = ws;               // [0, 2097152)        (Y0 dead after enc1 conv)
    float* D1   = ws + 2097152;     // [2097152, 6291456)  (Y1 dead after enc2 conv)
    float* D2   = ws + 6291456;     // [6291456, 14680064) (Y2/Z/Q/WT0/WT1/CBT/PART dead)

    dim3 blk(256);

    // ---- prologue: zero stat accumulators, transpose dec weights, transpose codebook ----
    zero_buf<<<24, blk, 0, stream>>>(BNT);
    transpose_all<<<2208, blk, 0, stream>>>(dec_w0, dec_w1, dec_w2, WT0, WT1, WT2);
    vq_prep<<<512, blk, 0, stream>>>(cb, CBT);

    // ---- encoder ----
    // enc0: Ci=3, 128->64, Co=64, OCT=8 : 256 tiles x 8 og = 2048 blocks
    conv4x4<8><<<2048, blk, 0, stream>>>(x, enc_w0, enc_b0, Y0, 16, 3, 128, 64, 64, 1, 3, 0);
    bn_part_atomic<<<1024, blk, 0, stream>>>(Y0, BNT, 16, 64, 4096);
    bn_apply4<<<4096, blk, 0, stream>>>((float4*)Y0, BNT, ebn_g0, ebn_b0, 64, 1024, 1.f / 65536.f);

    // enc1: Ci=64, 64->32, Co=128, KS=4 : 64 x 8 x 4 = 2048 blocks
    conv4x4<16><<<2048, blk, 0, stream>>>(Y0, enc_w1, enc_b1, PART, 16, 64, 64, 128, 32, 4, 16, 2097152);
    reduce_bias_stats4<<<2048, blk, 0, stream>>>((const float4*)PART, enc_b1, (float4*)Y1,
                                                 BNT + 1024, 524288, 4, 128, 256, 1);
    bn_apply4<<<2048, blk, 0, stream>>>((float4*)Y1, BNT + 1024, ebn_g1, ebn_b1, 128, 256, 1.f / 16384.f);

    // enc2: Ci=128, 32->16, Co=256, KS=8 : 16 x 16 x 8 = 2048 blocks
    conv4x4<16><<<2048, blk, 0, stream>>>(Y1, enc_w2, enc_b2, PART, 16, 128, 32, 256, 16, 8, 16, 1048576);
    reduce_bias_stats4<<<1024, blk, 0, stream>>>((const float4*)PART, enc_b2, (float4*)Y2,
                                                 BNT + 2048, 262144, 8, 256, 64, 4);
    bn_apply4<<<1024, blk, 0, stream>>>((float4*)Y2, BNT + 2048, ebn_g2, ebn_b2, 256, 64, 1.f / 4096.f);

    // enc3: Ci=256, 16->8, Co=256, KS=32 : 4 x 16 x 32 = 2048 blocks (no BN)
    conv4x4<16><<<2048, blk, 0, stream>>>(Y2, enc_w3, enc_b3, PART, 16, 256, 16, 256, 8, 32, 8, 262144);
    reduce_bias4<<<256, blk, 0, stream>>>((const float4*)PART, enc_b3, (float4*)Z, 65536, 32, 256, 16);

    // ---- vector quantizer ----
    vq_main<<<128, blk, 0, stream>>>(Z, CBT, cb, Q, out);
    vq_loss<<<1, blk, 0, stream>>>(out);

    // ---- decoder ----
    // dec0: Ci=256, 8->32 (k=4), Co=128, KS=4 : 4 x 16 x 8 x 4 = 2048 blocks
    convt_ij<16><<<2048, blk, 0, stream>>>(Q, WT0, dec_b0, PART, 16, 256, 8, 128, 4, 4, 64, 2097152);
    reduce_bias_stats4<<<2048, blk, 0, stream>>>((const float4*)PART, dec_b0, (float4*)D0,
                                                 BNT + 3072, 524288, 4, 128, 256, 1);
    bn_apply4<<<2048, blk, 0, stream>>>((float4*)D0, BNT + 3072, dbn_g0, dbn_b0, 128, 256, 1.f / 16384.f);

    // dec1: Ci=128, 32->64 (k=2), Co=64, KS=2 : 64 x 4 x 4 x 2 = 2048 blocks
    convt_ij<16><<<2048, blk, 0, stream>>>(D0, WT1, dec_b1, PART, 16, 128, 32, 64, 2, 2, 64, 4194304);
    reduce_bias_stats4<<<4096, blk, 0, stream>>>((const float4*)PART, dec_b1, (float4*)D1,
                                                 BNT + 4096, 1048576, 2, 64, 1024, 1);
    bn_apply4<<<4096, blk, 0, stream>>>((float4*)D1, BNT + 4096, dbn_g1, dbn_b1, 64, 1024, 1.f / 65536.f);

    // dec2: Ci=64, 64->128 (k=2), Co=32 : 256 x 4 x 2 = 2048 blocks
    convt_ij<16><<<2048, blk, 0, stream>>>(D1, WT2, dec_b2, D2, 16, 64, 64, 32, 2, 1, 64, 0);
    bn_part_atomic<<<512, blk, 0, stream>>>(D2, BNT + 5120, 16, 32, 16384);
    bn_apply4<<<8192, blk, 0, stream>>>((float4*)D2, BNT + 5120, dbn_g2, dbn_b2, 32, 4096, 1.f / 262144.f);

    final_conv_tanh<<<1024, blk, 0, stream>>>(D2, dec_w3, dec_b3, out);
}

// Round 5
// 631.200 us; speedup vs baseline: 4.1954x; 1.4404x over previous
//
#include <hip/hip_runtime.h>
#include <math.h>

#define LEAK 0.01f

// ================= Unified fp32 tiled GEMM =================
// C[M x N] = A[M x K] * B[K x N], block tile 128x64, thread tile 8x4, Kt=32.
// MODE 0: conv k4 s2 p1.  B[k][n] = im2col(x):
//   k -> (ic = k>>4, kh = (k>>2)&3, kw = k&3)
//   n -> (b = n>>(2*lgHo), oh = (n>>lgHo)&(Ho-1), ow = n&(Ho-1))
//   A = w (OIHW): A[m][k] = w[m*K + k]
//   out[m][n] -> y[((b*Co+m)*Ho+oh)*Ho+ow]
// MODE 1: convT stride==k.  B[k][n] = x[(b*Ci+k)*HW + hw], n=(b,hw)
//   A[m][k] = wtA[m*Ci + k],  m = ij*Co + o  (prebuilt)
//   out[m][n] -> y[((b*Co+o)*Ho + h*kf+i)*Ho + w*kf+j],  Ho = Hin*kf
// Split-K: block ks handles k in [ks*Kslice, (ks+1)*Kslice); KS>1 -> partials.
template<int MODE>
__global__ __launch_bounds__(256) void gemm128(
    const float* __restrict__ Ag, const float* __restrict__ Bg,
    const float* __restrict__ bias, float* __restrict__ P,
    int Mtiles, int Ntiles, int K, int Kslice, int KS, int outSize,
    int Ci, int Hin, int Co, int Ho, int lgHo,
    int lgHW, int lgHin, int lgCo, int lgk)
{
    __shared__ float As[32][132];   // [k][m], 2-way bank aliasing only
    __shared__ float Bs[32][68];    // [k][n]

    int bid = blockIdx.x;
    int ntile = bid % Ntiles; bid /= Ntiles;
    int mtile = bid % Mtiles;
    int ks = bid / Mtiles;
    int tid = threadIdx.x;
    int tm = tid & 15, tn = tid >> 4;

    int k0 = ks * Kslice;
    int m0 = mtile * 128;
    int n0 = ntile * 64;

    float acc[8][4];
#pragma unroll
    for (int i = 0; i < 8; ++i)
#pragma unroll
        for (int j = 0; j < 4; ++j) acc[i][j] = 0.f;

    for (int kc = 0; kc < Kslice; kc += 32) {
        int kbase = k0 + kc;
        // ---- stage A: 128x32, coalesced dwordx4 rows ----
#pragma unroll
        for (int rep = 0; rep < 4; ++rep) {
            int idx = rep * 256 + tid;          // 0..1023
            int m = idx >> 3, kg = (idx & 7) << 2;
            float4 v = *(const float4*)&Ag[(size_t)(m0 + m) * K + kbase + kg];
            As[kg][m] = v.x; As[kg + 1][m] = v.y; As[kg + 2][m] = v.z; As[kg + 3][m] = v.w;
        }
        // ---- stage B: 32x64 ----
        if (MODE == 0) {
#pragma unroll
            for (int rep = 0; rep < 8; ++rep) {
                int idx = rep * 256 + tid;      // 0..2047
                int nl = idx & 63, kl = idx >> 6;
                int n = n0 + nl;
                int kk = kbase + kl;
                int ic = kk >> 4, kh = (kk >> 2) & 3, kw = kk & 3;
                int ow = n & (Ho - 1), oh = (n >> lgHo) & (Ho - 1), b = n >> (lgHo + lgHo);
                int ih = oh * 2 - 1 + kh, iw = ow * 2 - 1 + kw;
                bool ok = ((unsigned)ih < (unsigned)Hin) && ((unsigned)iw < (unsigned)Hin);
                int ihc = ih < 0 ? 0 : (ih >= Hin ? Hin - 1 : ih);
                int iwc = iw < 0 ? 0 : (iw >= Hin ? Hin - 1 : iw);
                float v = Bg[((size_t)(b * Ci + ic) * Hin + ihc) * Hin + iwc];
                Bs[kl][nl] = ok ? v : 0.f;
            }
        } else {
#pragma unroll
            for (int rep = 0; rep < 2; ++rep) {
                int idx = rep * 256 + tid;      // 0..511
                int n4 = (idx & 15) << 2, kl = idx >> 4;
                int n = n0 + n4;
                int c = kbase + kl;
                int b = n >> lgHW, hw = n & ((1 << lgHW) - 1);
                float4 v = *(const float4*)&Bg[((size_t)(b * Ci + c) << lgHW) + hw];
                *(float4*)&Bs[kl][n4] = v;
            }
        }
        __syncthreads();
        // ---- compute: 32 k-steps x 32 FMA ----
#pragma unroll
        for (int k = 0; k < 32; ++k) {
            float4 a0 = *(const float4*)&As[k][tm * 4];
            float4 a1 = *(const float4*)&As[k][64 + tm * 4];
            float4 b  = *(const float4*)&Bs[k][tn * 4];
            float av[8] = {a0.x, a0.y, a0.z, a0.w, a1.x, a1.y, a1.z, a1.w};
#pragma unroll
            for (int i = 0; i < 8; ++i) {
                acc[i][0] += av[i] * b.x; acc[i][1] += av[i] * b.y;
                acc[i][2] += av[i] * b.z; acc[i][3] += av[i] * b.w;
            }
        }
        __syncthreads();
    }

    // ---- epilogue ----
    float* dst = P + (size_t)ks * outSize;
    if (MODE == 0) {
        int n = n0 + tn * 4;
        int ow = n & (Ho - 1), oh = (n >> lgHo) & (Ho - 1), b = n >> (lgHo + lgHo);
#pragma unroll
        for (int i = 0; i < 8; ++i) {
            int mloc = (i < 4) ? (tm * 4 + i) : (64 + tm * 4 + i - 4);
            int oc = m0 + mloc;
            float4 v = make_float4(acc[i][0], acc[i][1], acc[i][2], acc[i][3]);
            if (KS == 1) { float bv = bias[oc]; v.x += bv; v.y += bv; v.z += bv; v.w += bv; }
            *(float4*)&dst[((size_t)(b * Co + oc) * Ho + oh) * Ho + ow] = v;
        }
    } else {
        int n = n0 + tn * 4;
        int b = n >> lgHW, hw = n & ((1 << lgHW) - 1);
        int h = hw >> lgHin, w = hw & (Hin - 1);
        int kf = 1 << lgk;
        int Ho2 = Hin << lgk;
#pragma unroll
        for (int i = 0; i < 8; ++i) {
            int mloc = (i < 4) ? (tm * 4 + i) : (64 + tm * 4 + i - 4);
            int m = m0 + mloc;
            int o = m & (Co - 1), ij = m >> lgCo;
            int ii = ij >> lgk, jj = ij & (kf - 1);
            float bv = (KS == 1) ? bias[o] : 0.f;
            size_t base = ((size_t)(b * Co + o) * Ho2 + (h << lgk) + ii) * Ho2 + (w << lgk) + jj;
            dst[base]          = acc[i][0] + bv;
            dst[base + kf]     = acc[i][1] + bv;
            dst[base + 2 * kf] = acc[i][2] + bv;
            dst[base + 3 * kf] = acc[i][3] + bv;
        }
    }
}

// ================= enc0 direct conv (Ci=3, tiny K) =================
template<int OCT>
__global__ __launch_bounds__(256) void conv4x4(
    const float* __restrict__ x, const float* __restrict__ w,
    const float* __restrict__ bias, float* __restrict__ P,
    int B, int Ci, int Hin, int Co, int Ho)
{
    int ogn = Co / OCT;
    int ntile = (B * Ho * Ho) >> 8;
    int bid = blockIdx.x;
    int tile = bid % ntile; bid /= ntile;
    int og = bid % ogn;
    int oc0 = og * OCT;

    int px = (tile << 8) + threadIdx.x;
    int ow = px % Ho; int t = px / Ho;
    int oh = t % Ho;  int b = t / Ho;

    int off[16]; float fm[16];
    int ih0 = oh * 2 - 1, iw0 = ow * 2 - 1;
#pragma unroll
    for (int kh = 0; kh < 4; ++kh) {
#pragma unroll
        for (int kw = 0; kw < 4; ++kw) {
            int ih = ih0 + kh, iw = iw0 + kw;
            bool ok = (ih >= 0) && (ih < Hin) && (iw >= 0) && (iw < Hin);
            int ihc = ih < 0 ? 0 : (ih >= Hin ? Hin - 1 : ih);
            int iwc = iw < 0 ? 0 : (iw >= Hin ? Hin - 1 : iw);
            off[kh * 4 + kw] = ihc * Hin + iwc;
            fm[kh * 4 + kw] = ok ? 1.f : 0.f;
        }
    }

    float acc[OCT];
#pragma unroll
    for (int u = 0; u < OCT; ++u) acc[u] = bias[oc0 + u];

    const float* xc = x + (size_t)b * Ci * Hin * Hin;
    const float* wi = w + (size_t)oc0 * Ci * 16;
    int HinHin = Hin * Hin;

    for (int ic = 0; ic < Ci; ++ic) {
        float xv[16];
#pragma unroll
        for (int q = 0; q < 16; ++q) xv[q] = xc[off[q]] * fm[q];
#pragma unroll
        for (int u = 0; u < OCT; ++u) {
            const float* wo = wi + (size_t)u * Ci * 16;
            float a = acc[u];
#pragma unroll
            for (int q = 0; q < 16; ++q) a += xv[q] * wo[q];
            acc[u] = a;
        }
        xc += HinHin;
        wi += 16;
    }
    size_t obase = (((size_t)b * Co + oc0) * Ho + oh) * Ho + ow;
    size_t opl = (size_t)Ho * Ho;
#pragma unroll
    for (int u = 0; u < OCT; ++u) P[obase + u * opl] = acc[u];
}

// ================= reduce partials (+bias), optional fused BN stats =================
__global__ void reduce_bias4(const float4* __restrict__ P, const float* __restrict__ bias,
                             float4* __restrict__ y, int outSize4, int KS, int Co, int HW4) {
    int i = blockIdx.x * 256 + threadIdx.x;
    if (i >= outSize4) return;
    float bv = bias[(i / HW4) % Co];
    float4 s = make_float4(bv, bv, bv, bv);
    for (int ks = 0; ks < KS; ++ks) {
        float4 p = P[(size_t)ks * outSize4 + i];
        s.x += p.x; s.y += p.y; s.z += p.z; s.w += p.w;
    }
    y[i] = s;
}

__global__ void reduce_bias_stats4(const float4* __restrict__ P, const float* __restrict__ bias,
                                   float4* __restrict__ y, float* __restrict__ bnt,
                                   int outSize4, int KS, int Co, int HW4, int nch) {
    int tid = threadIdx.x;
    int i = blockIdx.x * 256 + tid;
    int c = (i / HW4) % Co;
    float bv = bias[c];
    float4 s = make_float4(bv, bv, bv, bv);
    for (int ks = 0; ks < KS; ++ks) {
        float4 p = P[(size_t)ks * outSize4 + i];
        s.x += p.x; s.y += p.y; s.z += p.z; s.w += p.w;
    }
    y[i] = s;
    float ls  = s.x + s.y + s.z + s.w;
    float ls2 = s.x * s.x + s.y * s.y + s.z * s.z + s.w * s.w;
    __shared__ float as[16], aq[16];
    if (tid < 16) { as[tid] = 0.f; aq[tid] = 0.f; }
    __syncthreads();
    int c0 = ((blockIdx.x * 256) / HW4) % Co;
    atomicAdd(&as[c - c0], ls);
    atomicAdd(&aq[c - c0], ls2);
    __syncthreads();
    if (tid < nch) {
        atomicAdd(&bnt[(c0 + tid) * 2],     as[tid]);
        atomicAdd(&bnt[(c0 + tid) * 2 + 1], aq[tid]);
    }
}

__global__ void bn_part_atomic(const float* __restrict__ y, float* __restrict__ bnt,
                               int B, int C, int HW) {
    int blk = blockIdx.x;          // c*B + b
    int c = blk / B, b = blk % B;
    int tid = threadIdx.x;
    const float* p = y + ((size_t)b * C + c) * HW;
    float s = 0.f, s2 = 0.f;
    for (int i = tid; i < HW; i += 256) {
        float v = p[i];
        s += v; s2 += v * v;
    }
    __shared__ float ls[256], ls2[256];
    ls[tid] = s; ls2[tid] = s2;
    __syncthreads();
    for (int off = 128; off > 0; off >>= 1) {
        if (tid < off) { ls[tid] += ls[tid + off]; ls2[tid] += ls2[tid + off]; }
        __syncthreads();
    }
    if (tid == 0) {
        atomicAdd(&bnt[c * 2],     ls[0]);
        atomicAdd(&bnt[c * 2 + 1], ls2[0]);
    }
}

__global__ void bn_apply4(float4* __restrict__ y, const float* __restrict__ bnt,
                          const float* __restrict__ g, const float* __restrict__ bt,
                          int C, int HW4, float invN) {
    int i = blockIdx.x * 256 + threadIdx.x;
    int c = (i / HW4) % C;
    float m = bnt[c * 2] * invN;
    float var = bnt[c * 2 + 1] * invN - m * m;
    float scale = g[c] * rsqrtf(var + 1e-5f);
    float shift = bt[c] - m * scale;
    float4 v = y[i];
    v.x = v.x * scale + shift; v.x = v.x >= 0.f ? v.x : LEAK * v.x;
    v.y = v.y * scale + shift; v.y = v.y >= 0.f ? v.y : LEAK * v.y;
    v.z = v.z * scale + shift; v.z = v.z >= 0.f ? v.z : LEAK * v.z;
    v.w = v.w * scale + shift; v.w = v.w >= 0.f ? v.w : LEAK * v.w;
    y[i] = v;
}

__global__ void zero_buf(float* __restrict__ p) {
    p[blockIdx.x * 256 + threadIdx.x] = 0.f;
}

// ================= Vector quantizer =================
#define OUT_CL   786432
#define OUT_CB   786433
#define OUT_IDX  786434
#define OUT_MIND 787458

__global__ void vq_prep(const float* __restrict__ cb, float* __restrict__ cbT) {
    int idx = blockIdx.x * 256 + threadIdx.x;   // 131072
    int k = idx & 511, c = idx >> 9;
    cbT[idx] = cb[k * 256 + c];
}

__global__ void vq_main(const float* __restrict__ z, const float* __restrict__ cbT,
                        const float* __restrict__ cb,
                        float* __restrict__ q, float* __restrict__ dout) {
    int r0 = blockIdx.x * 8;       // 128 blocks
    int tid = threadIdx.x;

    __shared__ float zT[256][8];
    __shared__ float red[256][9];
    __shared__ float zn2[8];
    __shared__ float rd[256];
    __shared__ int   ri[256];
    __shared__ int   bestsh[8];

#pragma unroll
    for (int rr = 0; rr < 8; ++rr) {
        int r = r0 + rr, b = r >> 6, s = r & 63;
        zT[tid][rr] = z[((size_t)(b * 256 + tid)) * 64 + s];
    }
    __syncthreads();
#pragma unroll
    for (int rr = 0; rr < 8; ++rr) { float v = zT[tid][rr]; red[tid][rr] = v * v; }
    __syncthreads();
    for (int off = 128; off > 0; off >>= 1) {
        if (tid < off) {
#pragma unroll
            for (int rr = 0; rr < 8; ++rr) red[tid][rr] += red[tid + off][rr];
        }
        __syncthreads();
    }
    if (tid < 8) zn2[tid] = red[0][tid];
    __syncthreads();

    float d0[8], d1[8];
#pragma unroll
    for (int rr = 0; rr < 8; ++rr) { d0[rr] = 0.f; d1[rr] = 0.f; }
    float cn0 = 0.f, cn1 = 0.f;

    for (int c = 0; c < 256; ++c) {
        float cv0 = cbT[c * 512 + tid];
        float cv1 = cbT[c * 512 + 256 + tid];
        cn0 += cv0 * cv0;
        cn1 += cv1 * cv1;
        float4 za = *(const float4*)&zT[c][0];
        float4 zb = *(const float4*)&zT[c][4];
        const float* zv = (const float*)&za;
        const float* zw = (const float*)&zb;
#pragma unroll
        for (int rr = 0; rr < 4; ++rr) {
            d0[rr]     += zv[rr] * cv0;  d1[rr]     += zv[rr] * cv1;
            d0[rr + 4] += zw[rr] * cv0;  d1[rr + 4] += zw[rr] * cv1;
        }
    }

#pragma unroll
    for (int rr = 0; rr < 8; ++rr) {
        float dist0 = zn2[rr] - 2.f * d0[rr] + cn0;
        float dist1 = zn2[rr] - 2.f * d1[rr] + cn1;
        float bd = dist0; int bi = tid;
        if (dist1 < bd) { bd = dist1; bi = tid + 256; }
        rd[tid] = bd; ri[tid] = bi;
        __syncthreads();
        for (int off = 128; off > 0; off >>= 1) {
            if (tid < off) {
                float od = rd[tid + off]; int oi = ri[tid + off];
                if (od < rd[tid] || (od == rd[tid] && oi < ri[tid])) { rd[tid] = od; ri[tid] = oi; }
            }
            __syncthreads();
        }
        if (tid == 0) {
            int r = r0 + rr;
            bestsh[rr] = ri[0];
            dout[OUT_IDX + r]  = (float)ri[0];
            dout[OUT_MIND + r] = rd[0];
        }
        __syncthreads();
    }

#pragma unroll
    for (int rr = 0; rr < 8; ++rr) {
        int r = r0 + rr, b = r >> 6, s = r & 63;
        q[((size_t)(b * 256 + tid)) * 64 + s] = cb[(size_t)bestsh[rr] * 256 + tid];
    }
}

__global__ void vq_loss(float* __restrict__ dout) {
    int tid = threadIdx.x;
    __shared__ float red[256];
    float s = 0.f;
    for (int i = tid; i < 1024; i += 256) s += dout[OUT_MIND + i];
    red[tid] = s;
    __syncthreads();
    for (int off = 128; off > 0; off >>= 1) {
        if (tid < off) red[tid] += red[tid + off];
        __syncthreads();
    }
    if (tid == 0) {
        float loss = red[0] / 262144.f;
        dout[OUT_CL] = loss;
        dout[OUT_CB] = loss;
    }
}

// ================= decoder-weight transposes: wtA[(ij*Co+o)*Ci + c] = wt[(c*Co+o)*kk + ij] =================
__global__ void transpose_all(const float* __restrict__ w0, const float* __restrict__ w1,
                              const float* __restrict__ w2, float* __restrict__ wt0,
                              float* __restrict__ wt1, float* __restrict__ wt2) {
    int idx = blockIdx.x * 256 + threadIdx.x;
    if (idx < 524288) {                       // Ci=256 Co=128 kk=16
        int c = idx & 255; int m = idx >> 8;
        int o = m & 127;   int ij = m >> 7;
        wt0[idx] = w0[((size_t)c * 128 + o) * 16 + ij];
    } else if (idx < 524288 + 32768) {        // Ci=128 Co=64 kk=4
        int i2 = idx - 524288;
        int c = i2 & 127; int m = i2 >> 7;
        int o = m & 63;   int ij = m >> 6;
        wt1[i2] = w1[((size_t)c * 64 + o) * 4 + ij];
    } else if (idx < 524288 + 32768 + 8192) { // Ci=64 Co=32 kk=4
        int i3 = idx - 524288 - 32768;
        int c = i3 & 63; int m = i3 >> 6;
        int o = m & 31;  int ij = m >> 5;
        wt2[i3] = w2[((size_t)c * 32 + o) * 4 + ij];
    }
}

// ================= Final 1x1 conv (32->3) + tanh =================
__global__ void final_conv_tanh(const float* __restrict__ hbuf, const float* __restrict__ w3,
                                const float* __restrict__ b3, float* __restrict__ out) {
    int idx = blockIdx.x * 256 + threadIdx.x;
    if (idx >= 16 * 16384) return;
    int hw = idx % 16384;
    int b  = idx / 16384;
    const float* hp = hbuf + ((size_t)b * 32) * 16384 + hw;
    float a0 = b3[0], a1 = b3[1], a2 = b3[2];
#pragma unroll
    for (int c = 0; c < 32; ++c) {
        float v = hp[(size_t)c * 16384];
        a0 += v * w3[c];
        a1 += v * w3[32 + c];
        a2 += v * w3[64 + c];
    }
    size_t ob = ((size_t)b * 3) * 16384 + hw;
    out[ob]             = tanhf(a0);
    out[ob + 16384]     = tanhf(a1);
    out[ob + 2 * 16384] = tanhf(a2);
}

extern "C" void kernel_launch(void* const* d_in, const int* in_sizes, int n_in,
                              void* d_out, int out_size, void* d_ws, size_t ws_size,
                              hipStream_t stream) {
    const float* x      = (const float*)d_in[0];
    const float* enc_w0 = (const float*)d_in[1];
    const float* enc_b0 = (const float*)d_in[2];
    const float* enc_w1 = (const float*)d_in[3];
    const float* enc_b1 = (const float*)d_in[4];
    const float* enc_w2 = (const float*)d_in[5];
    const float* enc_b2 = (const float*)d_in[6];
    const float* enc_w3 = (const float*)d_in[7];
    const float* enc_b3 = (const float*)d_in[8];
    const float* ebn_g0 = (const float*)d_in[9];
    const float* ebn_b0 = (const float*)d_in[10];
    const float* ebn_g1 = (const float*)d_in[11];
    const float* ebn_b1 = (const float*)d_in[12];
    const float* ebn_g2 = (const float*)d_in[13];
    const float* ebn_b2 = (const float*)d_in[14];
    const float* cb     = (const float*)d_in[15];
    const float* dec_w0 = (const float*)d_in[16];
    const float* dec_b0 = (const float*)d_in[17];
    const float* dbn_g0 = (const float*)d_in[18];
    const float* dbn_b0 = (const float*)d_in[19];
    const float* dec_w1 = (const float*)d_in[20];
    const float* dec_b1 = (const float*)d_in[21];
    const float* dbn_g1 = (const float*)d_in[22];
    const float* dbn_b1 = (const float*)d_in[23];
    const float* dec_w2 = (const float*)d_in[24];
    const float* dec_b2 = (const float*)d_in[25];
    const float* dbn_g2 = (const float*)d_in[26];
    const float* dbn_b2 = (const float*)d_in[27];
    const float* dec_w3 = (const float*)d_in[28];
    const float* dec_b3 = (const float*)d_in[29];

    float* out = (float*)d_out;
    float* ws  = (float*)d_ws;

    // ---- workspace layout (floats); same as round 4 (verified) ----
    float* Y0   = ws;               // [0, 4194304)
    float* Y1   = ws + 4194304;     // [4194304, 6291456)
    float* Y2   = ws + 6291456;     // [6291456, 7340032)
    float* Z    = ws + 7340032;     // [7340032, 7602176)
    float* Q    = ws + 7602176;     // [7602176, 7864320)
    float* WT0  = ws + 7864320;     // 524288
    float* WT1  = ws + 8388608;     // 32768
    float* CBT  = ws + 8429568;     // 131072
    float* PART = ws + 8566784;     // 8388608 shared split-K partials
    float* BNT  = ws + 16955392;    // 6144
    float* WT2  = ws + 16961536;    // 8192
    float* D0   = ws;               // [0, 2097152)
    float* D1   = ws + 2097152;     // [2097152, 6291456)
    float* D2   = ws + 6291456;     // [6291456, 14680064)

    dim3 blk(256);

    // ---- prologue ----
    zero_buf<<<24, blk, 0, stream>>>(BNT);
    transpose_all<<<2208, blk, 0, stream>>>(dec_w0, dec_w1, dec_w2, WT0, WT1, WT2);
    vq_prep<<<512, blk, 0, stream>>>(cb, CBT);

    // ---- encoder ----
    // enc0: direct conv, Ci=3, 128->64, Co=64 : 2048 blocks
    conv4x4<8><<<2048, blk, 0, stream>>>(x, enc_w0, enc_b0, Y0, 16, 3, 128, 64, 64);
    bn_part_atomic<<<1024, blk, 0, stream>>>(Y0, BNT, 16, 64, 4096);
    bn_apply4<<<4096, blk, 0, stream>>>((float4*)Y0, BNT, ebn_g0, ebn_b0, 64, 1024, 1.f / 65536.f);

    // enc1: GEMM M=128 N=16384 K=1024, KS=4 : 1x256x4 = 1024 blocks
    gemm128<0><<<1024, blk, 0, stream>>>(enc_w1, Y0, enc_b1, PART,
        1, 256, 1024, 256, 4, 2097152, 64, 64, 128, 32, 5, 0, 0, 0, 0);
    reduce_bias_stats4<<<2048, blk, 0, stream>>>((const float4*)PART, enc_b1, (float4*)Y1,
                                                 BNT + 1024, 524288, 4, 128, 256, 1);
    bn_apply4<<<2048, blk, 0, stream>>>((float4*)Y1, BNT + 1024, ebn_g1, ebn_b1, 128, 256, 1.f / 16384.f);

    // enc2: GEMM M=256 N=4096 K=2048, KS=8 : 2x64x8 = 1024 blocks
    gemm128<0><<<1024, blk, 0, stream>>>(enc_w2, Y1, enc_b2, PART,
        2, 64, 2048, 256, 8, 1048576, 128, 32, 256, 16, 4, 0, 0, 0, 0);
    reduce_bias_stats4<<<1024, blk, 0, stream>>>((const float4*)PART, enc_b2, (float4*)Y2,
                                                 BNT + 2048, 262144, 8, 256, 64, 4);
    bn_apply4<<<1024, blk, 0, stream>>>((float4*)Y2, BNT + 2048, ebn_g2, ebn_b2, 256, 64, 1.f / 4096.f);

    // enc3: GEMM M=256 N=1024 K=4096, KS=32 : 2x16x32 = 1024 blocks (no BN)
    gemm128<0><<<1024, blk, 0, stream>>>(enc_w3, Y2, enc_b3, PART,
        2, 16, 4096, 128, 32, 262144, 256, 16, 256, 8, 3, 0, 0, 0, 0);
    reduce_bias4<<<256, blk, 0, stream>>>((const float4*)PART, enc_b3, (float4*)Z, 65536, 32, 256, 16);

    // ---- vector quantizer ----
    vq_main<<<128, blk, 0, stream>>>(Z, CBT, cb, Q, out);
    vq_loss<<<1, blk, 0, stream>>>(out);

    // ---- decoder ----
    // dec0: convT GEMM M=2048 N=1024 K=256, KS=4 : 16x16x4 = 1024 blocks
    gemm128<1><<<1024, blk, 0, stream>>>(WT0, Q, dec_b0, PART,
        16, 16, 256, 64, 4, 2097152, 256, 8, 128, 0, 0, 6, 3, 7, 2);
    reduce_bias_stats4<<<2048, blk, 0, stream>>>((const float4*)PART, dec_b0, (float4*)D0,
                                                 BNT + 3072, 524288, 4, 128, 256, 1);
    bn_apply4<<<2048, blk, 0, stream>>>((float4*)D0, BNT + 3072, dbn_g0, dbn_b0, 128, 256, 1.f / 16384.f);

    // dec1: convT GEMM M=256 N=16384 K=128, KS=2 : 2x256x2 = 1024 blocks
    gemm128<1><<<1024, blk, 0, stream>>>(WT1, D0, dec_b1, PART,
        2, 256, 128, 64, 2, 4194304, 128, 32, 64, 0, 0, 10, 5, 6, 1);
    reduce_bias_stats4<<<4096, blk, 0, stream>>>((const float4*)PART, dec_b1, (float4*)D1,
                                                 BNT + 4096, 1048576, 2, 64, 1024, 1);
    bn_apply4<<<4096, blk, 0, stream>>>((float4*)D1, BNT + 4096, dbn_g1, dbn_b1, 64, 1024, 1.f / 65536.f);

    // dec2: convT GEMM M=128 N=65536 K=64, KS=1 (direct write + bias) : 1024 blocks
    gemm128<1><<<1024, blk, 0, stream>>>(WT2, D1, dec_b2, D2,
        1, 1024, 64, 64, 1, 0, 64, 64, 32, 0, 0, 12, 6, 5, 1);
    bn_part_atomic<<<512, blk, 0, stream>>>(D2, BNT + 5120, 16, 32, 16384);
    bn_apply4<<<8192, blk, 0, stream>>>((float4*)D2, BNT + 5120, dbn_g2, dbn_b2, 32, 4096, 1.f / 262144.f);

    final_conv_tanh<<<1024, blk, 0, stream>>>(D2, dec_w3, dec_b3, out);
}

// Round 7
// 594.845 us; speedup vs baseline: 4.4518x; 1.0611x over previous
//
#include <hip/hip_runtime.h>
#include <math.h>

#define LEAK 0.01f

typedef __bf16 bf16x8 __attribute__((ext_vector_type(8)));
typedef float f32x4 __attribute__((ext_vector_type(4)));
typedef unsigned short ushort;
typedef ushort us4 __attribute__((ext_vector_type(4)));

struct HL { ushort h, l; };

// split fp32 into bf16 hi + bf16 lo (both RNE): x ~= hi + lo, err ~2^-17 rel
__device__ inline HL split_bf16(float x) {
    unsigned u = __float_as_uint(x);
    unsigned hr = (u + 0x7FFFu + ((u >> 16) & 1u)) >> 16;
    float fh = __uint_as_float(hr << 16);
    float r = x - fh;
    unsigned v = __float_as_uint(r);
    unsigned lr = (v + 0x7FFFu + ((v >> 16) & 1u)) >> 16;
    HL out; out.h = (ushort)hr; out.l = (ushort)lr;
    return out;
}

// ================= bf16-split MFMA GEMM =================
// C[M x N] = A[M x K] * B[K x N].  Block tile 128x128, 4 waves of 64x64,
// K-step 32 via v_mfma_f32_16x16x32_bf16 (3 MFMAs/tile: hh, hl, lh).
// A (weights): global bf16 hi/lo, row-major [m][K] -> fragments loaded direct.
// B (activations): staged to LDS rows Bs[n][k] (stride 40 bf16 for bank spread).
// MODE 0: conv k4s2p1 im2col (4 consecutive k = 4 contiguous iw).
// MODE 1: convT stride==k (k=c, strided gather + transpose into LDS).
template<int MODE>
__global__ __launch_bounds__(256, 2) void gemm_mfma(
    const ushort* __restrict__ Ah, const ushort* __restrict__ Al,
    const ushort* __restrict__ Bh, const ushort* __restrict__ Bl,
    const float* __restrict__ bias, float* __restrict__ P,
    int Mtiles, int Ntiles, int K, int Kslice, int KS, int outSize,
    int Ci, int Hin, int Co, int Ho, int lgHo,
    int lgHW, int lgHin, int lgCo, int lgk)
{
    __shared__ __align__(16) ushort BsH[128 * 40];
    __shared__ __align__(16) ushort BsL[128 * 40];

    int bid = blockIdx.x;
    int ntile = bid % Ntiles; bid /= Ntiles;
    int mtile = bid % Mtiles;
    int ks = bid / Mtiles;
    int tid = threadIdx.x;
    int lane = tid & 63, w = tid >> 6;
    int wm = w & 1, wn = w >> 1;
    int quad = lane >> 4, tl = lane & 15;
    int n0 = ntile << 7, m0 = mtile << 7, k0 = ks * Kslice;

    f32x4 zero4 = {0.f, 0.f, 0.f, 0.f};
    f32x4 acc[4][4];
#pragma unroll
    for (int mt = 0; mt < 4; ++mt)
#pragma unroll
        for (int nt = 0; nt < 4; ++nt) acc[mt][nt] = zero4;

    for (int kc = 0; kc < Kslice; kc += 32) {
        int kbase = k0 + kc;
        // ---- stage B tile 32k x 128n (hi+lo) ----
#pragma unroll
        for (int rep = 0; rep < 4; ++rep) {
            int g = rep * 256 + tid;       // 0..1023
            int nl = g >> 3, kg = g & 7;
            int n = n0 + nl;
            ushort hv[4], lv[4];
            if (MODE == 0) {
                int k4 = kbase + (kg << 2);
                int ic = k4 >> 4, kh = (k4 >> 2) & 3;
                int ow = n & (Ho - 1), oh = (n >> lgHo) & (Ho - 1), b = n >> (lgHo + lgHo);
                int ih = oh * 2 - 1 + kh;
                bool rowok = (unsigned)ih < (unsigned)Hin;
                int ihc = ih < 0 ? 0 : (ih >= Hin ? Hin - 1 : ih);
                int iwb = ow * 2 - 1;
                size_t base = ((size_t)(b * Ci + ic) * Hin + ihc) * Hin;
#pragma unroll
                for (int e = 0; e < 4; ++e) {
                    int iw = iwb + e;
                    bool ok = rowok && ((unsigned)iw < (unsigned)Hin);
                    int iwc = iw < 0 ? 0 : (iw >= Hin ? Hin - 1 : iw);
                    ushort hh = Bh[base + iwc], ll = Bl[base + iwc];
                    hv[e] = ok ? hh : (ushort)0;
                    lv[e] = ok ? ll : (ushort)0;
                }
            } else {
                int c = kbase + (kg << 2);
                int b = n >> lgHW, hw = n & ((1 << lgHW) - 1);
                size_t base = (((size_t)(b * Ci + c)) << lgHW) + hw;
                size_t str = (size_t)1 << lgHW;
#pragma unroll
                for (int e = 0; e < 4; ++e) {
                    hv[e] = Bh[base + e * str];
                    lv[e] = Bl[base + e * str];
                }
            }
            int off = nl * 40 + (kg << 2);
            us4 th = {hv[0], hv[1], hv[2], hv[3]};
            us4 tll = {lv[0], lv[1], lv[2], lv[3]};
            *(us4*)&BsH[off] = th;
            *(us4*)&BsL[off] = tll;
        }
        __syncthreads();

        // ---- fragments ----
        bf16x8 afh[4], afl[4], bfh[4], bfl[4];
#pragma unroll
        for (int mt = 0; mt < 4; ++mt) {
            size_t row = (size_t)(m0 + (wm << 6) + (mt << 4) + tl) * K + kbase + (quad << 3);
            afh[mt] = *(const bf16x8*)(Ah + row);
            afl[mt] = *(const bf16x8*)(Al + row);
        }
#pragma unroll
        for (int nt = 0; nt < 4; ++nt) {
            int off = ((wn << 6) + (nt << 4) + tl) * 40 + (quad << 3);
            bfh[nt] = *(const bf16x8*)&BsH[off];
            bfl[nt] = *(const bf16x8*)&BsL[off];
        }
        // ---- 48 MFMAs ----
#pragma unroll
        for (int mt = 0; mt < 4; ++mt)
#pragma unroll
            for (int nt = 0; nt < 4; ++nt) {
                acc[mt][nt] = __builtin_amdgcn_mfma_f32_16x16x32_bf16(afh[mt], bfh[nt], acc[mt][nt], 0, 0, 0);
                acc[mt][nt] = __builtin_amdgcn_mfma_f32_16x16x32_bf16(afh[mt], bfl[nt], acc[mt][nt], 0, 0, 0);
                acc[mt][nt] = __builtin_amdgcn_mfma_f32_16x16x32_bf16(afl[mt], bfh[nt], acc[mt][nt], 0, 0, 0);
            }
        __syncthreads();
    }

    // ---- epilogue: D[m = quad*4+reg][n = tl] ----
    float* dst = P + (size_t)ks * outSize;
    if (MODE == 0) {
#pragma unroll
        for (int nt = 0; nt < 4; ++nt) {
            int n = n0 + (wn << 6) + (nt << 4) + tl;
            int ow = n & (Ho - 1), oh = (n >> lgHo) & (Ho - 1), b = n >> (lgHo + lgHo);
#pragma unroll
            for (int mt = 0; mt < 4; ++mt) {
                int mb = m0 + (wm << 6) + (mt << 4) + (quad << 2);
#pragma unroll
                for (int r = 0; r < 4; ++r) {
                    int oc = mb + r;
                    float v = acc[mt][nt][r];
                    if (KS == 1) v += bias[oc];
                    dst[((size_t)(b * Co + oc) * Ho + oh) * Ho + ow] = v;
                }
            }
        }
    } else {
        int kf = 1 << lgk;
        int Ho2 = Hin << lgk;
#pragma unroll
        for (int nt = 0; nt < 4; ++nt) {
            int n = n0 + (wn << 6) + (nt << 4) + tl;
            int b = n >> lgHW, hw = n & ((1 << lgHW) - 1);
            int h = hw >> lgHin, wp = hw & (Hin - 1);
#pragma unroll
            for (int mt = 0; mt < 4; ++mt) {
                int mb = m0 + (wm << 6) + (mt << 4) + (quad << 2);
#pragma unroll
                for (int r = 0; r < 4; ++r) {
                    int m = mb + r;
                    int o = m & (Co - 1), ij = m >> lgCo;
                    int ii = ij >> lgk, jj = ij & (kf - 1);
                    float v = acc[mt][nt][r];
                    if (KS == 1) v += bias[o];
                    dst[((size_t)(b * Co + o) * Ho2 + (h << lgk) + ii) * Ho2 + (wp << lgk) + jj] = v;
                }
            }
        }
    }
}

// ================= weight prep: split into fragment-ready bf16 hi/lo rows =================
// enc layers: A[m][k] = w OIHW (already row-major).  dec: A[m=ij*Co+o][c] transposed.
__global__ void prep_weights(const float* __restrict__ w1, const float* __restrict__ w2,
                             const float* __restrict__ w3, const float* __restrict__ d0,
                             const float* __restrict__ d1, const float* __restrict__ d2,
                             ushort* __restrict__ WH, ushort* __restrict__ WL) {
    int idx = blockIdx.x * 256 + threadIdx.x;
    if (idx >= 2269184) return;
    float v;
    if (idx < 131072) {
        v = w1[idx];
    } else if (idx < 655360) {
        v = w2[idx - 131072];
    } else if (idx < 1703936) {
        v = w3[idx - 655360];
    } else if (idx < 2228224) {
        int i = idx - 1703936;             // Ci=256 Co=128 kk=16
        int c = i & 255, m = i >> 8;
        int o = m & 127, ij = m >> 7;
        v = d0[((size_t)c * 128 + o) * 16 + ij];
    } else if (idx < 2260992) {
        int i = idx - 2228224;             // Ci=128 Co=64 kk=4
        int c = i & 127, m = i >> 7;
        int o = m & 63, ij = m >> 6;
        v = d1[((size_t)c * 64 + o) * 4 + ij];
    } else {
        int i = idx - 2260992;             // Ci=64 Co=32 kk=4
        int c = i & 63, m = i >> 6;
        int o = m & 31, ij = m >> 5;
        v = d2[((size_t)c * 32 + o) * 4 + ij];
    }
    HL s = split_bf16(v);
    WH[idx] = s.h; WL[idx] = s.l;
}

// ================= enc0 direct conv (Ci=3) =================
template<int OCT>
__global__ __launch_bounds__(256) void conv4x4(
    const float* __restrict__ x, const float* __restrict__ w,
    const float* __restrict__ bias, float* __restrict__ P,
    int B, int Ci, int Hin, int Co, int Ho)
{
    int ogn = Co / OCT;
    int ntile = (B * Ho * Ho) >> 8;
    int bid = blockIdx.x;
    int tile = bid % ntile; bid /= ntile;
    int og = bid % ogn;
    int oc0 = og * OCT;

    int px = (tile << 8) + threadIdx.x;
    int ow = px % Ho; int t = px / Ho;
    int oh = t % Ho;  int b = t / Ho;

    int off[16]; float fm[16];
    int ih0 = oh * 2 - 1, iw0 = ow * 2 - 1;
#pragma unroll
    for (int kh = 0; kh < 4; ++kh)
#pragma unroll
        for (int kw = 0; kw < 4; ++kw) {
            int ih = ih0 + kh, iw = iw0 + kw;
            bool ok = (ih >= 0) && (ih < Hin) && (iw >= 0) && (iw < Hin);
            int ihc = ih < 0 ? 0 : (ih >= Hin ? Hin - 1 : ih);
            int iwc = iw < 0 ? 0 : (iw >= Hin ? Hin - 1 : iw);
            off[kh * 4 + kw] = ihc * Hin + iwc;
            fm[kh * 4 + kw] = ok ? 1.f : 0.f;
        }

    float acc[OCT];
#pragma unroll
    for (int u = 0; u < OCT; ++u) acc[u] = bias[oc0 + u];

    const float* xc = x + (size_t)b * Ci * Hin * Hin;
    const float* wi = w + (size_t)oc0 * Ci * 16;
    int HinHin = Hin * Hin;
    for (int ic = 0; ic < Ci; ++ic) {
        float xv[16];
#pragma unroll
        for (int q = 0; q < 16; ++q) xv[q] = xc[off[q]] * fm[q];
#pragma unroll
        for (int u = 0; u < OCT; ++u) {
            const float* wo = wi + (size_t)u * Ci * 16;
            float a = acc[u];
#pragma unroll
            for (int q = 0; q < 16; ++q) a += xv[q] * wo[q];
            acc[u] = a;
        }
        xc += HinHin;
        wi += 16;
    }
    size_t obase = (((size_t)b * Co + oc0) * Ho + oh) * Ho + ow;
    size_t opl = (size_t)Ho * Ho;
#pragma unroll
    for (int u = 0; u < OCT; ++u) P[obase + u * opl] = acc[u];
}

// ================= reduce partials / BN (verified round 4-5 machinery) =================
__global__ void reduce_bias4(const float4* __restrict__ P, const float* __restrict__ bias,
                             float4* __restrict__ y, int outSize4, int KS, int Co, int HW4) {
    int i = blockIdx.x * 256 + threadIdx.x;
    if (i >= outSize4) return;
    float bv = bias[(i / HW4) % Co];
    float4 s = make_float4(bv, bv, bv, bv);
    for (int ks = 0; ks < KS; ++ks) {
        float4 p = P[(size_t)ks * outSize4 + i];
        s.x += p.x; s.y += p.y; s.z += p.z; s.w += p.w;
    }
    y[i] = s;
}

__global__ void reduce_bias_stats4(const float4* __restrict__ P, const float* __restrict__ bias,
                                   float4* __restrict__ y, float* __restrict__ bnt,
                                   int outSize4, int KS, int Co, int HW4, int nch) {
    int tid = threadIdx.x;
    int i = blockIdx.x * 256 + tid;
    int c = (i / HW4) % Co;
    float bv = bias[c];
    float4 s = make_float4(bv, bv, bv, bv);
    for (int ks = 0; ks < KS; ++ks) {
        float4 p = P[(size_t)ks * outSize4 + i];
        s.x += p.x; s.y += p.y; s.z += p.z; s.w += p.w;
    }
    y[i] = s;
    float ls  = s.x + s.y + s.z + s.w;
    float ls2 = s.x * s.x + s.y * s.y + s.z * s.z + s.w * s.w;
    __shared__ float as[16], aq[16];
    if (tid < 16) { as[tid] = 0.f; aq[tid] = 0.f; }
    __syncthreads();
    int c0 = ((blockIdx.x * 256) / HW4) % Co;
    atomicAdd(&as[c - c0], ls);
    atomicAdd(&aq[c - c0], ls2);
    __syncthreads();
    if (tid < nch) {
        atomicAdd(&bnt[(c0 + tid) * 2],     as[tid]);
        atomicAdd(&bnt[(c0 + tid) * 2 + 1], aq[tid]);
    }
}

__global__ void bn_part_atomic(const float* __restrict__ y, float* __restrict__ bnt,
                               int B, int C, int HW) {
    int blk = blockIdx.x;
    int c = blk / B, b = blk % B;
    int tid = threadIdx.x;
    const float* p = y + ((size_t)b * C + c) * HW;
    float s = 0.f, s2 = 0.f;
    for (int i = tid; i < HW; i += 256) {
        float v = p[i];
        s += v; s2 += v * v;
    }
    __shared__ float ls[256], ls2[256];
    ls[tid] = s; ls2[tid] = s2;
    __syncthreads();
    for (int off = 128; off > 0; off >>= 1) {
        if (tid < off) { ls[tid] += ls[tid + off]; ls2[tid] += ls2[tid + off]; }
        __syncthreads();
    }
    if (tid == 0) {
        atomicAdd(&bnt[c * 2],     ls[0]);
        atomicAdd(&bnt[c * 2 + 1], ls2[0]);
    }
}

// BN apply + LeakyReLU; optionally emits bf16 hi/lo copies for the next GEMM
__global__ void bn_apply4(float4* __restrict__ y, ushort* __restrict__ yh, ushort* __restrict__ yl,
                          const float* __restrict__ bnt,
                          const float* __restrict__ g, const float* __restrict__ bt,
                          int C, int HW4, float invN) {
    int i = blockIdx.x * 256 + threadIdx.x;
    int c = (i / HW4) % C;
    float m = bnt[c * 2] * invN;
    float var = bnt[c * 2 + 1] * invN - m * m;
    float scale = g[c] * rsqrtf(var + 1e-5f);
    float shift = bt[c] - m * scale;
    float4 v = y[i];
    v.x = v.x * scale + shift; v.x = v.x >= 0.f ? v.x : LEAK * v.x;
    v.y = v.y * scale + shift; v.y = v.y >= 0.f ? v.y : LEAK * v.y;
    v.z = v.z * scale + shift; v.z = v.z >= 0.f ? v.z : LEAK * v.z;
    v.w = v.w * scale + shift; v.w = v.w >= 0.f ? v.w : LEAK * v.w;
    y[i] = v;
    if (yh) {
        HL sx = split_bf16(v.x), sy = split_bf16(v.y), sz = split_bf16(v.z), sw = split_bf16(v.w);
        us4 h = {sx.h, sy.h, sz.h, sw.h};
        us4 l = {sx.l, sy.l, sz.l, sw.l};
        ((us4*)yh)[i] = h;
        ((us4*)yl)[i] = l;
    }
}

__global__ void zero_buf(float* __restrict__ p) {
    p[blockIdx.x * 256 + threadIdx.x] = 0.f;
}

// ================= Vector quantizer =================
#define OUT_CL   786432
#define OUT_CB   786433
#define OUT_IDX  786434
#define OUT_MIND 787458

__global__ void vq_prep(const float* __restrict__ cb, float* __restrict__ cbT) {
    int idx = blockIdx.x * 256 + threadIdx.x;
    int k = idx & 511, c = idx >> 9;
    cbT[idx] = cb[k * 256 + c];
}

__global__ void vq_main(const float* __restrict__ z, const float* __restrict__ cbT,
                        const float* __restrict__ cb,
                        ushort* __restrict__ qh, ushort* __restrict__ ql,
                        float* __restrict__ dout) {
    int r0 = blockIdx.x * 8;
    int tid = threadIdx.x;

    __shared__ float zT[256][8];
    __shared__ float red[256][9];
    __shared__ float zn2[8];
    __shared__ float rd[256];
    __shared__ int   ri[256];
    __shared__ int   bestsh[8];

#pragma unroll
    for (int rr = 0; rr < 8; ++rr) {
        int r = r0 + rr, b = r >> 6, s = r & 63;
        zT[tid][rr] = z[((size_t)(b * 256 + tid)) * 64 + s];
    }
    __syncthreads();
#pragma unroll
    for (int rr = 0; rr < 8; ++rr) { float v = zT[tid][rr]; red[tid][rr] = v * v; }
    __syncthreads();
    for (int off = 128; off > 0; off >>= 1) {
        if (tid < off) {
#pragma unroll
            for (int rr = 0; rr < 8; ++rr) red[tid][rr] += red[tid + off][rr];
        }
        __syncthreads();
    }
    if (tid < 8) zn2[tid] = red[0][tid];
    __syncthreads();

    float d0[8], d1[8];
#pragma unroll
    for (int rr = 0; rr < 8; ++rr) { d0[rr] = 0.f; d1[rr] = 0.f; }
    float cn0 = 0.f, cn1 = 0.f;

    for (int c = 0; c < 256; ++c) {
        float cv0 = cbT[c * 512 + tid];
        float cv1 = cbT[c * 512 + 256 + tid];
        cn0 += cv0 * cv0;
        cn1 += cv1 * cv1;
        float4 za = *(const float4*)&zT[c][0];
        float4 zb = *(const float4*)&zT[c][4];
        const float* zv = (const float*)&za;
        const float* zw = (const float*)&zb;
#pragma unroll
        for (int rr = 0; rr < 4; ++rr) {
            d0[rr]     += zv[rr] * cv0;  d1[rr]     += zv[rr] * cv1;
            d0[rr + 4] += zw[rr] * cv0;  d1[rr + 4] += zw[rr] * cv1;
        }
    }

#pragma unroll
    for (int rr = 0; rr < 8; ++rr) {
        float dist0 = zn2[rr] - 2.f * d0[rr] + cn0;
        float dist1 = zn2[rr] - 2.f * d1[rr] + cn1;
        float bd = dist0; int bi = tid;
        if (dist1 < bd) { bd = dist1; bi = tid + 256; }
        rd[tid] = bd; ri[tid] = bi;
        __syncthreads();
        for (int off = 128; off > 0; off >>= 1) {
            if (tid < off) {
                float od = rd[tid + off]; int oi = ri[tid + off];
                if (od < rd[tid] || (od == rd[tid] && oi < ri[tid])) { rd[tid] = od; ri[tid] = oi; }
            }
            __syncthreads();
        }
        if (tid == 0) {
            int r = r0 + rr;
            bestsh[rr] = ri[0];
            dout[OUT_IDX + r]  = (float)ri[0];
            dout[OUT_MIND + r] = rd[0];
        }
        __syncthreads();
    }

#pragma unroll
    for (int rr = 0; rr < 8; ++rr) {
        int r = r0 + rr, b = r >> 6, s = r & 63;
        float qv = cb[(size_t)bestsh[rr] * 256 + tid];
        HL sp = split_bf16(qv);
        size_t idx = ((size_t)(b * 256 + tid)) * 64 + s;
        qh[idx] = sp.h; ql[idx] = sp.l;
    }
}

__global__ void vq_loss(float* __restrict__ dout) {
    int tid = threadIdx.x;
    __shared__ float red[256];
    float s = 0.f;
    for (int i = tid; i < 1024; i += 256) s += dout[OUT_MIND + i];
    red[tid] = s;
    __syncthreads();
    for (int off = 128; off > 0; off >>= 1) {
        if (tid < off) red[tid] += red[tid + off];
        __syncthreads();
    }
    if (tid == 0) {
        float loss = red[0] / 262144.f;
        dout[OUT_CL] = loss;
        dout[OUT_CB] = loss;
    }
}

// ================= Final 1x1 conv (32->3) + tanh =================
__global__ void final_conv_tanh(const float* __restrict__ hbuf, const float* __restrict__ w3,
                                const float* __restrict__ b3, float* __restrict__ out) {
    int idx = blockIdx.x * 256 + threadIdx.x;
    if (idx >= 16 * 16384) return;
    int hw = idx % 16384;
    int b  = idx / 16384;
    const float* hp = hbuf + ((size_t)b * 32) * 16384 + hw;
    float a0 = b3[0], a1 = b3[1], a2 = b3[2];
#pragma unroll
    for (int c = 0; c < 32; ++c) {
        float v = hp[(size_t)c * 16384];
        a0 += v * w3[c];
        a1 += v * w3[32 + c];
        a2 += v * w3[64 + c];
    }
    size_t ob = ((size_t)b * 3) * 16384 + hw;
    out[ob]             = tanhf(a0);
    out[ob + 16384]     = tanhf(a1);
    out[ob + 2 * 16384] = tanhf(a2);
}

extern "C" void kernel_launch(void* const* d_in, const int* in_sizes, int n_in,
                              void* d_out, int out_size, void* d_ws, size_t ws_size,
                              hipStream_t stream) {
    const float* x      = (const float*)d_in[0];
    const float* enc_w0 = (const float*)d_in[1];
    const float* enc_b0 = (const float*)d_in[2];
    const float* enc_w1 = (const float*)d_in[3];
    const float* enc_b1 = (const float*)d_in[4];
    const float* enc_w2 = (const float*)d_in[5];
    const float* enc_b2 = (const float*)d_in[6];
    const float* enc_w3 = (const float*)d_in[7];
    const float* enc_b3 = (const float*)d_in[8];
    const float* ebn_g0 = (const float*)d_in[9];
    const float* ebn_b0 = (const float*)d_in[10];
    const float* ebn_g1 = (const float*)d_in[11];
    const float* ebn_b1 = (const float*)d_in[12];
    const float* ebn_g2 = (const float*)d_in[13];
    const float* ebn_b2 = (const float*)d_in[14];
    const float* cb     = (const float*)d_in[15];
    const float* dec_w0 = (const float*)d_in[16];
    const float* dec_b0 = (const float*)d_in[17];
    const float* dbn_g0 = (const float*)d_in[18];
    const float* dbn_b0 = (const float*)d_in[19];
    const float* dec_w1 = (const float*)d_in[20];
    const float* dec_b1 = (const float*)d_in[21];
    const float* dbn_g1 = (const float*)d_in[22];
    const float* dbn_b1 = (const float*)d_in[23];
    const float* dec_w2 = (const float*)d_in[24];
    const float* dec_b2 = (const float*)d_in[25];
    const float* dbn_g2 = (const float*)d_in[26];
    const float* dbn_b2 = (const float*)d_in[27];
    const float* dec_w3 = (const float*)d_in[28];
    const float* dec_b3 = (const float*)d_in[29];

    float* out = (float*)d_out;
    float* ws  = (float*)d_ws;

    // ---- workspace (float units); no aliasing, total 55,359,488 fl = 221 MB ----
    float*  Y0   = ws;                               // 4194304
    float*  Y1   = ws + 4194304;                     // 2097152
    float*  Y2   = ws + 6291456;                     // 1048576
    float*  Z    = ws + 7340032;                     // 262144
    ushort* Qh   = (ushort*)(ws + 7602176);          // 262144 us
    ushort* Ql   = (ushort*)(ws + 7733248);          // 262144 us
    ushort* Y0h  = (ushort*)(ws + 7864320);          // 4194304 us
    ushort* Y0l  = (ushort*)(ws + 9961472);
    ushort* Y1h  = (ushort*)(ws + 12058624);         // 2097152 us
    ushort* Y1l  = (ushort*)(ws + 13107200);
    ushort* Y2h  = (ushort*)(ws + 14155776);         // 1048576 us
    ushort* Y2l  = (ushort*)(ws + 14680064);
    ushort* WH   = (ushort*)(ws + 15204352);         // 2269184 us
    ushort* WL   = (ushort*)(ws + 16338944);         // 2269184 us
    float*  CBT  = ws + 17473536;                    // 131072
    float*  BNT  = ws + 17604608;                    // 6144
    float*  PART = ws + 17610752;                    // 16777216
    float*  D0   = ws + 34387968;                    // 2097152
    ushort* D0h  = (ushort*)(ws + 36485120);         // 2097152 us
    ushort* D0l  = (ushort*)(ws + 37533696);
    float*  D1   = ws + 38582272;                    // 4194304
    ushort* D1h  = (ushort*)(ws + 42776576);         // 4194304 us
    ushort* D1l  = (ushort*)(ws + 44873728);
    float*  D2   = ws + 46970880;                    // 8388608 -> ends 55359488

    dim3 blk(256);

    // ---- prologue ----
    zero_buf<<<24, blk, 0, stream>>>(BNT);
    prep_weights<<<8864, blk, 0, stream>>>(enc_w1, enc_w2, enc_w3, dec_w0, dec_w1, dec_w2, WH, WL);
    vq_prep<<<512, blk, 0, stream>>>(cb, CBT);

    // ---- encoder ----
    conv4x4<8><<<2048, blk, 0, stream>>>(x, enc_w0, enc_b0, Y0, 16, 3, 128, 64, 64);
    bn_part_atomic<<<1024, blk, 0, stream>>>(Y0, BNT, 16, 64, 4096);
    bn_apply4<<<4096, blk, 0, stream>>>((float4*)Y0, Y0h, Y0l, BNT, ebn_g0, ebn_b0, 64, 1024, 1.f / 65536.f);

    // enc1: M=128 N=16384 K=1024, KS=8 -> 1024 blocks
    gemm_mfma<0><<<1024, blk, 0, stream>>>(WH, WL, Y0h, Y0l, enc_b1, PART,
        1, 128, 1024, 128, 8, 2097152, 64, 64, 128, 32, 5, 0, 0, 0, 0);
    reduce_bias_stats4<<<2048, blk, 0, stream>>>((const float4*)PART, enc_b1, (float4*)Y1,
                                                 BNT + 1024, 524288, 8, 128, 256, 1);
    bn_apply4<<<2048, blk, 0, stream>>>((float4*)Y1, Y1h, Y1l, BNT + 1024, ebn_g1, ebn_b1, 128, 256, 1.f / 16384.f);

    // enc2: M=256 N=4096 K=2048, KS=16 -> 2x32x16 = 1024 blocks
    gemm_mfma<0><<<1024, blk, 0, stream>>>(WH + 131072, WL + 131072, Y1h, Y1l, enc_b2, PART,
        2, 32, 2048, 128, 16, 1048576, 128, 32, 256, 16, 4, 0, 0, 0, 0);
    reduce_bias_stats4<<<1024, blk, 0, stream>>>((const float4*)PART, enc_b2, (float4*)Y2,
                                                 BNT + 2048, 262144, 16, 256, 64, 4);
    bn_apply4<<<1024, blk, 0, stream>>>((float4*)Y2, Y2h, Y2l, BNT + 2048, ebn_g2, ebn_b2, 256, 64, 1.f / 4096.f);

    // enc3: M=256 N=1024 K=4096, KS=32 -> 2x8x32 = 512 blocks
    gemm_mfma<0><<<512, blk, 0, stream>>>(WH + 655360, WL + 655360, Y2h, Y2l, enc_b3, PART,
        2, 8, 4096, 128, 32, 262144, 256, 16, 256, 8, 3, 0, 0, 0, 0);
    reduce_bias4<<<256, blk, 0, stream>>>((const float4*)PART, enc_b3, (float4*)Z, 65536, 32, 256, 16);

    // ---- vector quantizer ----
    vq_main<<<128, blk, 0, stream>>>(Z, CBT, cb, Qh, Ql, out);
    vq_loss<<<1, blk, 0, stream>>>(out);

    // ---- decoder ----
    // dec0: M=2048 N=1024 K=256, KS=2 -> 16x8x2 = 256 blocks
    gemm_mfma<1><<<256, blk, 0, stream>>>(WH + 1703936, WL + 1703936, Qh, Ql, dec_b0, PART,
        16, 8, 256, 128, 2, 2097152, 256, 8, 128, 0, 0, 6, 3, 7, 2);
    reduce_bias_stats4<<<2048, blk, 0, stream>>>((const float4*)PART, dec_b0, (float4*)D0,
                                                 BNT + 3072, 524288, 2, 128, 256, 1);
    bn_apply4<<<2048, blk, 0, stream>>>((float4*)D0, D0h, D0l, BNT + 3072, dbn_g0, dbn_b0, 128, 256, 1.f / 16384.f);

    // dec1: M=256 N=16384 K=128, KS=2 -> 2x128x2 = 512 blocks
    gemm_mfma<1><<<512, blk, 0, stream>>>(WH + 2228224, WL + 2228224, D0h, D0l, dec_b1, PART,
        2, 128, 128, 64, 2, 4194304, 128, 32, 64, 0, 0, 10, 5, 6, 1);
    reduce_bias_stats4<<<4096, blk, 0, stream>>>((const float4*)PART, dec_b1, (float4*)D1,
                                                 BNT + 4096, 1048576, 2, 64, 1024, 1);
    bn_apply4<<<4096, blk, 0, stream>>>((float4*)D1, D1h, D1l, BNT + 4096, dbn_g1, dbn_b1, 64, 1024, 1.f / 65536.f);

    // dec2: M=128 N=65536 K=64, KS=1 -> 512 blocks, direct write + bias
    gemm_mfma<1><<<512, blk, 0, stream>>>(WH + 2260992, WL + 2260992, D1h, D1l, dec_b2, D2,
        1, 512, 64, 64, 1, 0, 64, 64, 32, 0, 0, 12, 6, 5, 1);
    bn_part_atomic<<<512, blk, 0, stream>>>(D2, BNT + 5120, 16, 32, 16384);
    bn_apply4<<<8192, blk, 0, stream>>>((float4*)D2, nullptr, nullptr, BNT + 5120, dbn_g2, dbn_b2, 32, 4096, 1.f / 262144.f);

    final_conv_tanh<<<1024, blk, 0, stream>>>(D2, dec_w3, dec_b3, out);
}

// Round 8
// 534.033 us; speedup vs baseline: 4.9588x; 1.1139x over previous
//
#include <hip/hip_runtime.h>
#include <math.h>

#define LEAK 0.01f

typedef __bf16 bf16x8 __attribute__((ext_vector_type(8)));
typedef float f32x4 __attribute__((ext_vector_type(4)));
typedef unsigned short ushort;
typedef unsigned int uint32;

struct HL { ushort h, l; };

// split fp32 into bf16 hi + bf16 lo (both RNE): x ~= hi + lo, err ~2^-17 rel
__device__ inline HL split_bf16(float x) {
    unsigned u = __float_as_uint(x);
    unsigned hr = (u + 0x7FFFu + ((u >> 16) & 1u)) >> 16;
    float fh = __uint_as_float(hr << 16);
    float r = x - fh;
    unsigned v = __float_as_uint(r);
    unsigned lr = (v + 0x7FFFu + ((v >> 16) & 1u)) >> 16;
    HL out; out.h = (ushort)hr; out.l = (ushort)lr;
    return out;
}

// ================= staged-B load: 4 packed dwords per thread-slot per rep =================
template<int MODE>
__device__ inline void stage_load(uint32 (&pv)[4][4], const uint32* __restrict__ Bp,
                                  int kbase, int n0, int tid,
                                  int Ci, int Hin, int Ho, int lgHo, int lgHW) {
#pragma unroll
    for (int r = 0; r < 4; ++r) {
        int g = r * 256 + tid;
        int nl = g >> 3, kg = g & 7;
        int n = n0 + nl;
        if (MODE == 0) {
            int k4 = kbase + (kg << 2);
            int ic = k4 >> 4, kh = (k4 >> 2) & 3;
            int ow = n & (Ho - 1), oh = (n >> lgHo) & (Ho - 1), b = n >> (lgHo + lgHo);
            int ih = oh * 2 - 1 + kh;
            bool rowok = (unsigned)ih < (unsigned)Hin;
            int ihc = ih < 0 ? 0 : (ih >= Hin ? Hin - 1 : ih);
            int iwb = ow * 2 - 1;
            size_t base = ((size_t)(b * Ci + ic) * Hin + ihc) * Hin;
#pragma unroll
            for (int e = 0; e < 4; ++e) {
                int iw = iwb + e;
                bool ok = rowok && ((unsigned)iw < (unsigned)Hin);
                int iwc = iw < 0 ? 0 : (iw >= Hin ? Hin - 1 : iw);
                uint32 v = Bp[base + iwc];
                pv[r][e] = ok ? v : 0u;
            }
        } else {
            int c = kbase + (kg << 2);
            int b = n >> lgHW, hw = n & ((1 << lgHW) - 1);
            size_t base = (((size_t)(b * Ci + c)) << lgHW) + hw;
            size_t str = (size_t)1 << lgHW;
#pragma unroll
            for (int e = 0; e < 4; ++e) pv[r][e] = Bp[base + e * str];
        }
    }
}

// ================= bf16-split MFMA GEMM (packed-uint B, reg-prefetch) =================
// Same math as round 7 (verified): C = Ah*Bh + Ah*Bl + Al*Bh per 16x16x32 tile.
template<int MODE>
__global__ __launch_bounds__(256, 2) void gemm_mfma(
    const ushort* __restrict__ Ah, const ushort* __restrict__ Al,
    const uint32* __restrict__ Bp,
    const float* __restrict__ bias, float* __restrict__ P,
    int Mtiles, int Ntiles, int K, int Kslice, int KS, int outSize,
    int Ci, int Hin, int Co, int Ho, int lgHo,
    int lgHW, int lgHin, int lgCo, int lgk)
{
    __shared__ __align__(16) uint32 Bsp[128 * 36];   // [n][k] packed, stride 36 uints

    int bid = blockIdx.x;
    int ntile = bid % Ntiles; bid /= Ntiles;
    int mtile = bid % Mtiles;
    int ks = bid / Mtiles;
    int tid = threadIdx.x;
    int lane = tid & 63, w = tid >> 6;
    int wm = w & 1, wn = w >> 1;
    int quad = lane >> 4, tl = lane & 15;
    int n0 = ntile << 7, m0 = mtile << 7, k0 = ks * Kslice;

    f32x4 zero4 = {0.f, 0.f, 0.f, 0.f};
    f32x4 acc[4][4];
#pragma unroll
    for (int mt = 0; mt < 4; ++mt)
#pragma unroll
        for (int nt = 0; nt < 4; ++nt) acc[mt][nt] = zero4;

    uint32 pv[4][4];
    stage_load<MODE>(pv, Bp, k0, n0, tid, Ci, Hin, Ho, lgHo, lgHW);

    for (int kc = 0; kc < Kslice; kc += 32) {
        int kbase = k0 + kc;
        // ---- regs -> LDS ----
#pragma unroll
        for (int r = 0; r < 4; ++r) {
            int g = r * 256 + tid;
            int nl = g >> 3, kg = g & 7;
            uint4 t = make_uint4(pv[r][0], pv[r][1], pv[r][2], pv[r][3]);
            *(uint4*)&Bsp[nl * 36 + (kg << 2)] = t;
        }
        __syncthreads();

        // ---- prefetch next tile (loads stay in flight through the MFMAs) ----
        bool more = (kc + 32) < Kslice;
        uint32 pvn[4][4];
        if (more) stage_load<MODE>(pvn, Bp, kbase + 32, n0, tid, Ci, Hin, Ho, lgHo, lgHW);

        // ---- A fragments (global, hi/lo ushort rows) ----
        bf16x8 afh[4], afl[4];
#pragma unroll
        for (int mt = 0; mt < 4; ++mt) {
            size_t row = (size_t)(m0 + (wm << 6) + (mt << 4) + tl) * K + kbase + (quad << 3);
            afh[mt] = *(const bf16x8*)(Ah + row);
            afl[mt] = *(const bf16x8*)(Al + row);
        }
        // ---- B fragments: LDS packed -> unpack via v_perm ----
        bf16x8 bfh[4], bfl[4];
#pragma unroll
        for (int nt = 0; nt < 4; ++nt) {
            int base = ((wn << 6) + (nt << 4) + tl) * 36 + (quad << 3);
            uint4 ua = *(const uint4*)&Bsp[base];
            uint4 ub = *(const uint4*)&Bsp[base + 4];
            union { uint32 u[4]; bf16x8 v; } H, L;
            H.u[0] = __builtin_amdgcn_perm(ua.y, ua.x, 0x07060302u);
            H.u[1] = __builtin_amdgcn_perm(ua.w, ua.z, 0x07060302u);
            H.u[2] = __builtin_amdgcn_perm(ub.y, ub.x, 0x07060302u);
            H.u[3] = __builtin_amdgcn_perm(ub.w, ub.z, 0x07060302u);
            L.u[0] = __builtin_amdgcn_perm(ua.y, ua.x, 0x05040100u);
            L.u[1] = __builtin_amdgcn_perm(ua.w, ua.z, 0x05040100u);
            L.u[2] = __builtin_amdgcn_perm(ub.y, ub.x, 0x05040100u);
            L.u[3] = __builtin_amdgcn_perm(ub.w, ub.z, 0x05040100u);
            bfh[nt] = H.v; bfl[nt] = L.v;
        }
        // ---- 48 MFMAs ----
#pragma unroll
        for (int mt = 0; mt < 4; ++mt)
#pragma unroll
            for (int nt = 0; nt < 4; ++nt) {
                acc[mt][nt] = __builtin_amdgcn_mfma_f32_16x16x32_bf16(afh[mt], bfh[nt], acc[mt][nt], 0, 0, 0);
                acc[mt][nt] = __builtin_amdgcn_mfma_f32_16x16x32_bf16(afh[mt], bfl[nt], acc[mt][nt], 0, 0, 0);
                acc[mt][nt] = __builtin_amdgcn_mfma_f32_16x16x32_bf16(afl[mt], bfh[nt], acc[mt][nt], 0, 0, 0);
            }
        __syncthreads();
        if (more) {
#pragma unroll
            for (int r = 0; r < 4; ++r)
#pragma unroll
                for (int e = 0; e < 4; ++e) pv[r][e] = pvn[r][e];
        }
    }

    // ---- epilogue: D[m = quad*4+reg][n = tl] (verified round 7) ----
    float* dst = P + (size_t)ks * outSize;
    if (MODE == 0) {
#pragma unroll
        for (int nt = 0; nt < 4; ++nt) {
            int n = n0 + (wn << 6) + (nt << 4) + tl;
            int ow = n & (Ho - 1), oh = (n >> lgHo) & (Ho - 1), b = n >> (lgHo + lgHo);
#pragma unroll
            for (int mt = 0; mt < 4; ++mt) {
                int mb = m0 + (wm << 6) + (mt << 4) + (quad << 2);
#pragma unroll
                for (int r = 0; r < 4; ++r) {
                    int oc = mb + r;
                    float v = acc[mt][nt][r];
                    if (KS == 1) v += bias[oc];
                    dst[((size_t)(b * Co + oc) * Ho + oh) * Ho + ow] = v;
                }
            }
        }
    } else {
        int kf = 1 << lgk;
        int Ho2 = Hin << lgk;
#pragma unroll
        for (int nt = 0; nt < 4; ++nt) {
            int n = n0 + (wn << 6) + (nt << 4) + tl;
            int b = n >> lgHW, hw = n & ((1 << lgHW) - 1);
            int h = hw >> lgHin, wp = hw & (Hin - 1);
#pragma unroll
            for (int mt = 0; mt < 4; ++mt) {
                int mb = m0 + (wm << 6) + (mt << 4) + (quad << 2);
#pragma unroll
                for (int r = 0; r < 4; ++r) {
                    int m = mb + r;
                    int o = m & (Co - 1), ij = m >> lgCo;
                    int ii = ij >> lgk, jj = ij & (kf - 1);
                    float v = acc[mt][nt][r];
                    if (KS == 1) v += bias[o];
                    dst[((size_t)(b * Co + o) * Ho2 + (h << lgk) + ii) * Ho2 + (wp << lgk) + jj] = v;
                }
            }
        }
    }
}

// ================= weight prep (unchanged, verified) =================
__global__ void prep_weights(const float* __restrict__ w1, const float* __restrict__ w2,
                             const float* __restrict__ w3, const float* __restrict__ d0,
                             const float* __restrict__ d1, const float* __restrict__ d2,
                             ushort* __restrict__ WH, ushort* __restrict__ WL) {
    int idx = blockIdx.x * 256 + threadIdx.x;
    if (idx >= 2269184) return;
    float v;
    if (idx < 131072) {
        v = w1[idx];
    } else if (idx < 655360) {
        v = w2[idx - 131072];
    } else if (idx < 1703936) {
        v = w3[idx - 655360];
    } else if (idx < 2228224) {
        int i = idx - 1703936;             // Ci=256 Co=128 kk=16
        int c = i & 255, m = i >> 8;
        int o = m & 127, ij = m >> 7;
        v = d0[((size_t)c * 128 + o) * 16 + ij];
    } else if (idx < 2260992) {
        int i = idx - 2228224;             // Ci=128 Co=64 kk=4
        int c = i & 127, m = i >> 7;
        int o = m & 63, ij = m >> 6;
        v = d1[((size_t)c * 64 + o) * 4 + ij];
    } else {
        int i = idx - 2260992;             // Ci=64 Co=32 kk=4
        int c = i & 63, m = i >> 6;
        int o = m & 31, ij = m >> 5;
        v = d2[((size_t)c * 32 + o) * 4 + ij];
    }
    HL s = split_bf16(v);
    WH[idx] = s.h; WL[idx] = s.l;
}

// ================= enc0 direct conv (Ci=3) =================
template<int OCT>
__global__ __launch_bounds__(256) void conv4x4(
    const float* __restrict__ x, const float* __restrict__ w,
    const float* __restrict__ bias, float* __restrict__ P,
    int B, int Ci, int Hin, int Co, int Ho)
{
    int ogn = Co / OCT;
    int ntile = (B * Ho * Ho) >> 8;
    int bid = blockIdx.x;
    int tile = bid % ntile; bid /= ntile;
    int og = bid % ogn;
    int oc0 = og * OCT;

    int px = (tile << 8) + threadIdx.x;
    int ow = px % Ho; int t = px / Ho;
    int oh = t % Ho;  int b = t / Ho;

    int off[16]; float fm[16];
    int ih0 = oh * 2 - 1, iw0 = ow * 2 - 1;
#pragma unroll
    for (int kh = 0; kh < 4; ++kh)
#pragma unroll
        for (int kw = 0; kw < 4; ++kw) {
            int ih = ih0 + kh, iw = iw0 + kw;
            bool ok = (ih >= 0) && (ih < Hin) && (iw >= 0) && (iw < Hin);
            int ihc = ih < 0 ? 0 : (ih >= Hin ? Hin - 1 : ih);
            int iwc = iw < 0 ? 0 : (iw >= Hin ? Hin - 1 : iw);
            off[kh * 4 + kw] = ihc * Hin + iwc;
            fm[kh * 4 + kw] = ok ? 1.f : 0.f;
        }

    float acc[OCT];
#pragma unroll
    for (int u = 0; u < OCT; ++u) acc[u] = bias[oc0 + u];

    const float* xc = x + (size_t)b * Ci * Hin * Hin;
    const float* wi = w + (size_t)oc0 * Ci * 16;
    int HinHin = Hin * Hin;
    for (int ic = 0; ic < Ci; ++ic) {
        float xv[16];
#pragma unroll
        for (int q = 0; q < 16; ++q) xv[q] = xc[off[q]] * fm[q];
#pragma unroll
        for (int u = 0; u < OCT; ++u) {
            const float* wo = wi + (size_t)u * Ci * 16;
            float a = acc[u];
#pragma unroll
            for (int q = 0; q < 16; ++q) a += xv[q] * wo[q];
            acc[u] = a;
        }
        xc += HinHin;
        wi += 16;
    }
    size_t obase = (((size_t)b * Co + oc0) * Ho + oh) * Ho + ow;
    size_t opl = (size_t)Ho * Ho;
#pragma unroll
    for (int u = 0; u < OCT; ++u) P[obase + u * opl] = acc[u];
}

// ================= reduce partials / BN (verified) =================
__global__ void reduce_bias4(const float4* __restrict__ P, const float* __restrict__ bias,
                             float4* __restrict__ y, int outSize4, int KS, int Co, int HW4) {
    int i = blockIdx.x * 256 + threadIdx.x;
    if (i >= outSize4) return;
    float bv = bias[(i / HW4) % Co];
    float4 s = make_float4(bv, bv, bv, bv);
    for (int ks = 0; ks < KS; ++ks) {
        float4 p = P[(size_t)ks * outSize4 + i];
        s.x += p.x; s.y += p.y; s.z += p.z; s.w += p.w;
    }
    y[i] = s;
}

__global__ void reduce_bias_stats4(const float4* __restrict__ P, const float* __restrict__ bias,
                                   float4* __restrict__ y, float* __restrict__ bnt,
                                   int outSize4, int KS, int Co, int HW4, int nch) {
    int tid = threadIdx.x;
    int i = blockIdx.x * 256 + tid;
    int c = (i / HW4) % Co;
    float bv = bias[c];
    float4 s = make_float4(bv, bv, bv, bv);
    for (int ks = 0; ks < KS; ++ks) {
        float4 p = P[(size_t)ks * outSize4 + i];
        s.x += p.x; s.y += p.y; s.z += p.z; s.w += p.w;
    }
    y[i] = s;
    float ls  = s.x + s.y + s.z + s.w;
    float ls2 = s.x * s.x + s.y * s.y + s.z * s.z + s.w * s.w;
    __shared__ float as[16], aq[16];
    if (tid < 16) { as[tid] = 0.f; aq[tid] = 0.f; }
    __syncthreads();
    int c0 = ((blockIdx.x * 256) / HW4) % Co;
    atomicAdd(&as[c - c0], ls);
    atomicAdd(&aq[c - c0], ls2);
    __syncthreads();
    if (tid < nch) {
        atomicAdd(&bnt[(c0 + tid) * 2],     as[tid]);
        atomicAdd(&bnt[(c0 + tid) * 2 + 1], aq[tid]);
    }
}

__global__ void bn_part_atomic(const float* __restrict__ y, float* __restrict__ bnt,
                               int B, int C, int HW) {
    int blk = blockIdx.x;
    int c = blk / B, b = blk % B;
    int tid = threadIdx.x;
    const float* p = y + ((size_t)b * C + c) * HW;
    float s = 0.f, s2 = 0.f;
    for (int i = tid; i < HW; i += 256) {
        float v = p[i];
        s += v; s2 += v * v;
    }
    __shared__ float ls[256], ls2[256];
    ls[tid] = s; ls2[tid] = s2;
    __syncthreads();
    for (int off = 128; off > 0; off >>= 1) {
        if (tid < off) { ls[tid] += ls[tid + off]; ls2[tid] += ls2[tid + off]; }
        __syncthreads();
    }
    if (tid == 0) {
        atomicAdd(&bnt[c * 2],     ls[0]);
        atomicAdd(&bnt[c * 2 + 1], ls2[0]);
    }
}

// BN apply + LeakyReLU; optionally emits packed bf16 hi|lo copies
__global__ void bn_apply4(float4* __restrict__ y, uint32* __restrict__ yp,
                          const float* __restrict__ bnt,
                          const float* __restrict__ g, const float* __restrict__ bt,
                          int C, int HW4, float invN) {
    int i = blockIdx.x * 256 + threadIdx.x;
    int c = (i / HW4) % C;
    float m = bnt[c * 2] * invN;
    float var = bnt[c * 2 + 1] * invN - m * m;
    float scale = g[c] * rsqrtf(var + 1e-5f);
    float shift = bt[c] - m * scale;
    float4 v = y[i];
    v.x = v.x * scale + shift; v.x = v.x >= 0.f ? v.x : LEAK * v.x;
    v.y = v.y * scale + shift; v.y = v.y >= 0.f ? v.y : LEAK * v.y;
    v.z = v.z * scale + shift; v.z = v.z >= 0.f ? v.z : LEAK * v.z;
    v.w = v.w * scale + shift; v.w = v.w >= 0.f ? v.w : LEAK * v.w;
    y[i] = v;
    if (yp) {
        HL sx = split_bf16(v.x), sy = split_bf16(v.y), sz = split_bf16(v.z), sw = split_bf16(v.w);
        uint4 o = make_uint4(((uint32)sx.h << 16) | sx.l, ((uint32)sy.h << 16) | sy.l,
                             ((uint32)sz.h << 16) | sz.l, ((uint32)sw.h << 16) | sw.l);
        ((uint4*)yp)[i] = o;
    }
}

__global__ void zero_buf(float* __restrict__ p) {
    p[blockIdx.x * 256 + threadIdx.x] = 0.f;
}

// ================= Vector quantizer =================
#define OUT_CL   786432
#define OUT_CB   786433
#define OUT_IDX  786434
#define OUT_MIND 787458

__global__ void vq_prep(const float* __restrict__ cb, float* __restrict__ cbT) {
    int idx = blockIdx.x * 256 + threadIdx.x;
    int k = idx & 511, c = idx >> 9;
    cbT[idx] = cb[k * 256 + c];
}

__global__ void vq_main(const float* __restrict__ z, const float* __restrict__ cbT,
                        const float* __restrict__ cb,
                        uint32* __restrict__ qp, float* __restrict__ dout) {
    int r0 = blockIdx.x * 8;
    int tid = threadIdx.x;

    __shared__ float zT[256][8];
    __shared__ float red[256][9];
    __shared__ float zn2[8];
    __shared__ float rd[256];
    __shared__ int   ri[256];
    __shared__ int   bestsh[8];

#pragma unroll
    for (int rr = 0; rr < 8; ++rr) {
        int r = r0 + rr, b = r >> 6, s = r & 63;
        zT[tid][rr] = z[((size_t)(b * 256 + tid)) * 64 + s];
    }
    __syncthreads();
#pragma unroll
    for (int rr = 0; rr < 8; ++rr) { float v = zT[tid][rr]; red[tid][rr] = v * v; }
    __syncthreads();
    for (int off = 128; off > 0; off >>= 1) {
        if (tid < off) {
#pragma unroll
            for (int rr = 0; rr < 8; ++rr) red[tid][rr] += red[tid + off][rr];
        }
        __syncthreads();
    }
    if (tid < 8) zn2[tid] = red[0][tid];
    __syncthreads();

    float d0[8], d1[8];
#pragma unroll
    for (int rr = 0; rr < 8; ++rr) { d0[rr] = 0.f; d1[rr] = 0.f; }
    float cn0 = 0.f, cn1 = 0.f;

    for (int c = 0; c < 256; ++c) {
        float cv0 = cbT[c * 512 + tid];
        float cv1 = cbT[c * 512 + 256 + tid];
        cn0 += cv0 * cv0;
        cn1 += cv1 * cv1;
        float4 za = *(const float4*)&zT[c][0];
        float4 zb = *(const float4*)&zT[c][4];
        const float* zv = (const float*)&za;
        const float* zw = (const float*)&zb;
#pragma unroll
        for (int rr = 0; rr < 4; ++rr) {
            d0[rr]     += zv[rr] * cv0;  d1[rr]     += zv[rr] * cv1;
            d0[rr + 4] += zw[rr] * cv0;  d1[rr + 4] += zw[rr] * cv1;
        }
    }

#pragma unroll
    for (int rr = 0; rr < 8; ++rr) {
        float dist0 = zn2[rr] - 2.f * d0[rr] + cn0;
        float dist1 = zn2[rr] - 2.f * d1[rr] + cn1;
        float bd = dist0; int bi = tid;
        if (dist1 < bd) { bd = dist1; bi = tid + 256; }
        rd[tid] = bd; ri[tid] = bi;
        __syncthreads();
        for (int off = 128; off > 0; off >>= 1) {
            if (tid < off) {
                float od = rd[tid + off]; int oi = ri[tid + off];
                if (od < rd[tid] || (od == rd[tid] && oi < ri[tid])) { rd[tid] = od; ri[tid] = oi; }
            }
            __syncthreads();
        }
        if (tid == 0) {
            int r = r0 + rr;
            bestsh[rr] = ri[0];
            dout[OUT_IDX + r]  = (float)ri[0];
            dout[OUT_MIND + r] = rd[0];
        }
        __syncthreads();
    }

#pragma unroll
    for (int rr = 0; rr < 8; ++rr) {
        int r = r0 + rr, b = r >> 6, s = r & 63;
        float qv = cb[(size_t)bestsh[rr] * 256 + tid];
        HL sp = split_bf16(qv);
        qp[((size_t)(b * 256 + tid)) * 64 + s] = ((uint32)sp.h << 16) | sp.l;
    }
}

__global__ void vq_loss(float* __restrict__ dout) {
    int tid = threadIdx.x;
    __shared__ float red[256];
    float s = 0.f;
    for (int i = tid; i < 1024; i += 256) s += dout[OUT_MIND + i];
    red[tid] = s;
    __syncthreads();
    for (int off = 128; off > 0; off >>= 1) {
        if (tid < off) red[tid] += red[tid + off];
        __syncthreads();
    }
    if (tid == 0) {
        float loss = red[0] / 262144.f;
        dout[OUT_CL] = loss;
        dout[OUT_CB] = loss;
    }
}

// ================= Final 1x1 conv (32->3) + tanh =================
__global__ void final_conv_tanh(const float* __restrict__ hbuf, const float* __restrict__ w3,
                                const float* __restrict__ b3, float* __restrict__ out) {
    int idx = blockIdx.x * 256 + threadIdx.x;
    if (idx >= 16 * 16384) return;
    int hw = idx % 16384;
    int b  = idx / 16384;
    const float* hp = hbuf + ((size_t)b * 32) * 16384 + hw;
    float a0 = b3[0], a1 = b3[1], a2 = b3[2];
#pragma unroll
    for (int c = 0; c < 32; ++c) {
        float v = hp[(size_t)c * 16384];
        a0 += v * w3[c];
        a1 += v * w3[32 + c];
        a2 += v * w3[64 + c];
    }
    size_t ob = ((size_t)b * 3) * 16384 + hw;
    out[ob]             = tanhf(a0);
    out[ob + 16384]     = tanhf(a1);
    out[ob + 2 * 16384] = tanhf(a2);
}

extern "C" void kernel_launch(void* const* d_in, const int* in_sizes, int n_in,
                              void* d_out, int out_size, void* d_ws, size_t ws_size,
                              hipStream_t stream) {
    const float* x      = (const float*)d_in[0];
    const float* enc_w0 = (const float*)d_in[1];
    const float* enc_b0 = (const float*)d_in[2];
    const float* enc_w1 = (const float*)d_in[3];
    const float* enc_b1 = (const float*)d_in[4];
    const float* enc_w2 = (const float*)d_in[5];
    const float* enc_b2 = (const float*)d_in[6];
    const float* enc_w3 = (const float*)d_in[7];
    const float* enc_b3 = (const float*)d_in[8];
    const float* ebn_g0 = (const float*)d_in[9];
    const float* ebn_b0 = (const float*)d_in[10];
    const float* ebn_g1 = (const float*)d_in[11];
    const float* ebn_b1 = (const float*)d_in[12];
    const float* ebn_g2 = (const float*)d_in[13];
    const float* ebn_b2 = (const float*)d_in[14];
    const float* cb     = (const float*)d_in[15];
    const float* dec_w0 = (const float*)d_in[16];
    const float* dec_b0 = (const float*)d_in[17];
    const float* dbn_g0 = (const float*)d_in[18];
    const float* dbn_b0 = (const float*)d_in[19];
    const float* dec_w1 = (const float*)d_in[20];
    const float* dec_b1 = (const float*)d_in[21];
    const float* dbn_g1 = (const float*)d_in[22];
    const float* dbn_b1 = (const float*)d_in[23];
    const float* dec_w2 = (const float*)d_in[24];
    const float* dec_b2 = (const float*)d_in[25];
    const float* dbn_g2 = (const float*)d_in[26];
    const float* dbn_b2 = (const float*)d_in[27];
    const float* dec_w3 = (const float*)d_in[28];
    const float* dec_b3 = (const float*)d_in[29];

    float* out = (float*)d_out;
    float* ws  = (float*)d_ws;

    // ---- workspace (float units); packed-uint activation copies ----
    float*  Y0   = ws;                               // 4194304
    float*  Y1   = ws + 4194304;                     // 2097152
    float*  Y2   = ws + 6291456;                     // 1048576
    float*  Z    = ws + 7340032;                     // 262144
    uint32* Qp   = (uint32*)(ws + 7602176);          // 262144 u32
    uint32* Y0p  = (uint32*)(ws + 7864320);          // 4194304 u32
    uint32* Y1p  = (uint32*)(ws + 12058624);         // 2097152 u32
    uint32* Y2p  = (uint32*)(ws + 14155776);         // 1048576 u32
    ushort* WH   = (ushort*)(ws + 15204352);         // 2269184 us
    ushort* WL   = (ushort*)(ws + 16338944);         // 2269184 us
    float*  CBT  = ws + 17473536;                    // 131072
    float*  BNT  = ws + 17604608;                    // 6144
    float*  PART = ws + 17610752;                    // up to 8388608 used
    float*  D0   = ws + 34387968;                    // 2097152
    uint32* D0p  = (uint32*)(ws + 36485120);         // 2097152 u32
    float*  D1   = ws + 38582272;                    // 4194304
    uint32* D1p  = (uint32*)(ws + 42776576);         // 4194304 u32
    float*  D2   = ws + 46970880;                    // 8388608 -> ends 55359488

    dim3 blk(256);

    // ---- prologue ----
    zero_buf<<<24, blk, 0, stream>>>(BNT);
    prep_weights<<<8864, blk, 0, stream>>>(enc_w1, enc_w2, enc_w3, dec_w0, dec_w1, dec_w2, WH, WL);
    vq_prep<<<512, blk, 0, stream>>>(cb, CBT);

    // ---- encoder ----
    conv4x4<8><<<2048, blk, 0, stream>>>(x, enc_w0, enc_b0, Y0, 16, 3, 128, 64, 64);
    bn_part_atomic<<<1024, blk, 0, stream>>>(Y0, BNT, 16, 64, 4096);
    bn_apply4<<<4096, blk, 0, stream>>>((float4*)Y0, Y0p, BNT, ebn_g0, ebn_b0, 64, 1024, 1.f / 65536.f);

    // enc1: M=128 N=16384 K=1024, KS=4 -> 512 blocks
    gemm_mfma<0><<<512, blk, 0, stream>>>(WH, WL, Y0p, enc_b1, PART,
        1, 128, 1024, 256, 4, 2097152, 64, 64, 128, 32, 5, 0, 0, 0, 0);
    reduce_bias_stats4<<<2048, blk, 0, stream>>>((const float4*)PART, enc_b1, (float4*)Y1,
                                                 BNT + 1024, 524288, 4, 128, 256, 1);
    bn_apply4<<<2048, blk, 0, stream>>>((float4*)Y1, Y1p, BNT + 1024, ebn_g1, ebn_b1, 128, 256, 1.f / 16384.f);

    // enc2: M=256 N=4096 K=2048, KS=8 -> 2x32x8 = 512 blocks
    gemm_mfma<0><<<512, blk, 0, stream>>>(WH + 131072, WL + 131072, Y1p, enc_b2, PART,
        2, 32, 2048, 256, 8, 1048576, 128, 32, 256, 16, 4, 0, 0, 0, 0);
    reduce_bias_stats4<<<1024, blk, 0, stream>>>((const float4*)PART, enc_b2, (float4*)Y2,
                                                 BNT + 2048, 262144, 8, 256, 64, 4);
    bn_apply4<<<1024, blk, 0, stream>>>((float4*)Y2, Y2p, BNT + 2048, ebn_g2, ebn_b2, 256, 64, 1.f / 4096.f);

    // enc3: M=256 N=1024 K=4096, KS=32 -> 2x8x32 = 512 blocks
    gemm_mfma<0><<<512, blk, 0, stream>>>(WH + 655360, WL + 655360, Y2p, enc_b3, PART,
        2, 8, 4096, 128, 32, 262144, 256, 16, 256, 8, 3, 0, 0, 0, 0);
    reduce_bias4<<<256, blk, 0, stream>>>((const float4*)PART, enc_b3, (float4*)Z, 65536, 32, 256, 16);

    // ---- vector quantizer ----
    vq_main<<<128, blk, 0, stream>>>(Z, CBT, cb, Qp, out);
    vq_loss<<<1, blk, 0, stream>>>(out);

    // ---- decoder ----
    // dec0: M=2048 N=1024 K=256, KS=4 -> 16x8x4 = 512 blocks
    gemm_mfma<1><<<512, blk, 0, stream>>>(WH + 1703936, WL + 1703936, Qp, dec_b0, PART,
        16, 8, 256, 64, 4, 2097152, 256, 8, 128, 0, 0, 6, 3, 7, 2);
    reduce_bias_stats4<<<2048, blk, 0, stream>>>((const float4*)PART, dec_b0, (float4*)D0,
                                                 BNT + 3072, 524288, 4, 128, 256, 1);
    bn_apply4<<<2048, blk, 0, stream>>>((float4*)D0, D0p, BNT + 3072, dbn_g0, dbn_b0, 128, 256, 1.f / 16384.f);

    // dec1: M=256 N=16384 K=128, KS=2 -> 2x128x2 = 512 blocks
    gemm_mfma<1><<<512, blk, 0, stream>>>(WH + 2228224, WL + 2228224, D0p, dec_b1, PART,
        2, 128, 128, 64, 2, 4194304, 128, 32, 64, 0, 0, 10, 5, 6, 1);
    reduce_bias_stats4<<<4096, blk, 0, stream>>>((const float4*)PART, dec_b1, (float4*)D1,
                                                 BNT + 4096, 1048576, 2, 64, 1024, 1);
    bn_apply4<<<4096, blk, 0, stream>>>((float4*)D1, D1p, BNT + 4096, dbn_g1, dbn_b1, 64, 1024, 1.f / 65536.f);

    // dec2: M=128 N=65536 K=64, KS=1 -> 512 blocks, direct write + bias
    gemm_mfma<1><<<512, blk, 0, stream>>>(WH + 2260992, WL + 2260992, D1p, dec_b2, D2,
        1, 512, 64, 64, 1, 0, 64, 64, 32, 0, 0, 12, 6, 5, 1);
    bn_part_atomic<<<512, blk, 0, stream>>>(D2, BNT + 5120, 16, 32, 16384);
    bn_apply4<<<8192, blk, 0, stream>>>((float4*)D2, nullptr, BNT + 5120, dbn_g2, dbn_b2, 32, 4096, 1.f / 262144.f);

    final_conv_tanh<<<1024, blk, 0, stream>>>(D2, dec_w3, dec_b3, out);
}

// Round 9
// 493.813 us; speedup vs baseline: 5.3627x; 1.0814x over previous
//
#include <hip/hip_runtime.h>
#include <math.h>

#define LEAK 0.01f

typedef __bf16 bf16x8 __attribute__((ext_vector_type(8)));
typedef float f32x4 __attribute__((ext_vector_type(4)));
typedef unsigned short ushort;
typedef unsigned int uint32;

struct HL { ushort h, l; };

// split fp32 into bf16 hi + bf16 lo (both RNE): x ~= hi + lo, err ~2^-17 rel
__device__ inline HL split_bf16(float x) {
    unsigned u = __float_as_uint(x);
    unsigned hr = (u + 0x7FFFu + ((u >> 16) & 1u)) >> 16;
    float fh = __uint_as_float(hr << 16);
    float r = x - fh;
    unsigned v = __float_as_uint(r);
    unsigned lr = (v + 0x7FFFu + ((v >> 16) & 1u)) >> 16;
    HL out; out.h = (ushort)hr; out.l = (ushort)lr;
    return out;
}

// ================= staged-B load: 64n x 32k packed tile, 8 dwords/thread =================
template<int MODE>
__device__ inline void stage_load(uint32 (&pv)[2][4], const uint32* __restrict__ Bp,
                                  int kbase, int n0, int tid,
                                  int Ci, int Hin, int Ho, int lgHo, int lgHW) {
#pragma unroll
    for (int r = 0; r < 2; ++r) {
        int g = r * 256 + tid;          // 0..511
        int nl = g >> 3, kg = g & 7;
        int n = n0 + nl;
        if (MODE == 0) {
            int k4 = kbase + (kg << 2);
            int ic = k4 >> 4, kh = (k4 >> 2) & 3;
            int ow = n & (Ho - 1), oh = (n >> lgHo) & (Ho - 1), b = n >> (lgHo + lgHo);
            int ih = oh * 2 - 1 + kh;
            bool rowok = (unsigned)ih < (unsigned)Hin;
            int ihc = ih < 0 ? 0 : (ih >= Hin ? Hin - 1 : ih);
            int iwb = ow * 2 - 1;
            size_t base = ((size_t)(b * Ci + ic) * Hin + ihc) * Hin;
#pragma unroll
            for (int e = 0; e < 4; ++e) {
                int iw = iwb + e;
                bool ok = rowok && ((unsigned)iw < (unsigned)Hin);
                int iwc = iw < 0 ? 0 : (iw >= Hin ? Hin - 1 : iw);
                uint32 v = Bp[base + iwc];
                pv[r][e] = ok ? v : 0u;
            }
        } else {
            int c = kbase + (kg << 2);
            int b = n >> lgHW, hw = n & ((1 << lgHW) - 1);
            size_t base = (((size_t)(b * Ci + c)) << lgHW) + hw;
            size_t str = (size_t)1 << lgHW;
#pragma unroll
            for (int e = 0; e < 4; ++e) pv[r][e] = Bp[base + e * str];
        }
    }
}

// ================= bf16-split MFMA GEMM =================
// Block tile 128M x 64N, 4 waves of 32M x 64N. K-step 32.
// A: fragment-ordered bf16 hi/lo -> fully coalesced 16B/lane wave loads.
// B: packed (hi<<16|lo) uint32, staged via regs -> LDS, unpacked with v_perm.
// Math (verified r7/r8): C = Ah*Bh + Ah*Bl + Al*Bh per 16x16x32 tile.
template<int MODE>
__global__ __launch_bounds__(256, 3) void gemm_mfma(
    const ushort* __restrict__ Ah, const ushort* __restrict__ Al,
    const uint32* __restrict__ Bp,
    const float* __restrict__ bias, float* __restrict__ P,
    int Mtiles, int Ntiles, int K, int Kslice, int KS, int outSize,
    int Ci, int Hin, int Co, int Ho, int lgHo,
    int lgHW, int lgHin, int lgCo, int lgk)
{
    __shared__ __align__(16) uint32 Bsp[64 * 36];   // [n][k] packed, stride 36

    int bid = blockIdx.x;
    int ntile = bid % Ntiles; bid /= Ntiles;
    int mtile = bid % Mtiles;
    int ks = bid / Mtiles;
    int tid = threadIdx.x;
    int lane = tid & 63, w = tid >> 6;              // w = wave 0..3 (32 rows each)
    int quad = lane >> 4, tl = lane & 15;
    int n0 = ntile << 6, m0 = mtile << 7, k0 = ks * Kslice;
    int Kt = K >> 5;

    f32x4 zero4 = {0.f, 0.f, 0.f, 0.f};
    f32x4 acc[2][4];
#pragma unroll
    for (int mt = 0; mt < 2; ++mt)
#pragma unroll
        for (int nt = 0; nt < 4; ++nt) acc[mt][nt] = zero4;

    uint32 pv[2][4];
    stage_load<MODE>(pv, Bp, k0, n0, tid, Ci, Hin, Ho, lgHo, lgHW);

    for (int kc = 0; kc < Kslice; kc += 32) {
        int kbase = k0 + kc;
        int kt = kbase >> 5;
        // ---- regs -> LDS ----
#pragma unroll
        for (int r = 0; r < 2; ++r) {
            int g = r * 256 + tid;
            int nl = g >> 3, kg = g & 7;
            uint4 t = make_uint4(pv[r][0], pv[r][1], pv[r][2], pv[r][3]);
            *(uint4*)&Bsp[nl * 36 + (kg << 2)] = t;
        }
        __syncthreads();

        // ---- prefetch next B tile ----
        bool more = (kc + 32) < Kslice;
        uint32 pvn[2][4];
        if (more) stage_load<MODE>(pvn, Bp, kbase + 32, n0, tid, Ci, Hin, Ho, lgHo, lgHW);

        // ---- A fragments: fragment-ordered global, coalesced 16B/lane ----
        bf16x8 afh[2], afl[2];
#pragma unroll
        for (int mt = 0; mt < 2; ++mt) {
            int mtAbs = (m0 >> 4) + (w << 1) + mt;
            size_t abase = (((size_t)mtAbs * Kt + kt) << 6) + lane;
            afh[mt] = *(const bf16x8*)(Ah + abase * 8);
            afl[mt] = *(const bf16x8*)(Al + abase * 8);
        }
        // ---- B fragments: LDS packed -> unpack via v_perm ----
        bf16x8 bfh[4], bfl[4];
#pragma unroll
        for (int nt = 0; nt < 4; ++nt) {
            int base = ((nt << 4) + tl) * 36 + (quad << 3);
            uint4 ua = *(const uint4*)&Bsp[base];
            uint4 ub = *(const uint4*)&Bsp[base + 4];
            union { uint32 u[4]; bf16x8 v; } H, L;
            H.u[0] = __builtin_amdgcn_perm(ua.y, ua.x, 0x07060302u);
            H.u[1] = __builtin_amdgcn_perm(ua.w, ua.z, 0x07060302u);
            H.u[2] = __builtin_amdgcn_perm(ub.y, ub.x, 0x07060302u);
            H.u[3] = __builtin_amdgcn_perm(ub.w, ub.z, 0x07060302u);
            L.u[0] = __builtin_amdgcn_perm(ua.y, ua.x, 0x05040100u);
            L.u[1] = __builtin_amdgcn_perm(ua.w, ua.z, 0x05040100u);
            L.u[2] = __builtin_amdgcn_perm(ub.y, ub.x, 0x05040100u);
            L.u[3] = __builtin_amdgcn_perm(ub.w, ub.z, 0x05040100u);
            bfh[nt] = H.v; bfl[nt] = L.v;
        }
        // ---- 24 MFMAs / wave ----
#pragma unroll
        for (int mt = 0; mt < 2; ++mt)
#pragma unroll
            for (int nt = 0; nt < 4; ++nt) {
                acc[mt][nt] = __builtin_amdgcn_mfma_f32_16x16x32_bf16(afh[mt], bfh[nt], acc[mt][nt], 0, 0, 0);
                acc[mt][nt] = __builtin_amdgcn_mfma_f32_16x16x32_bf16(afh[mt], bfl[nt], acc[mt][nt], 0, 0, 0);
                acc[mt][nt] = __builtin_amdgcn_mfma_f32_16x16x32_bf16(afl[mt], bfh[nt], acc[mt][nt], 0, 0, 0);
            }
        __syncthreads();
        if (more) {
#pragma unroll
            for (int r = 0; r < 2; ++r)
#pragma unroll
                for (int e = 0; e < 4; ++e) pv[r][e] = pvn[r][e];
        }
    }

    // ---- epilogue: D[m = quad*4+reg][n = tl] (verified r7/r8) ----
    float* dst = P + (size_t)ks * outSize;
    if (MODE == 0) {
#pragma unroll
        for (int nt = 0; nt < 4; ++nt) {
            int n = n0 + (nt << 4) + tl;
            int ow = n & (Ho - 1), oh = (n >> lgHo) & (Ho - 1), b = n >> (lgHo + lgHo);
#pragma unroll
            for (int mt = 0; mt < 2; ++mt) {
                int mb = m0 + (w << 5) + (mt << 4) + (quad << 2);
#pragma unroll
                for (int r = 0; r < 4; ++r) {
                    int oc = mb + r;
                    float v = acc[mt][nt][r];
                    if (KS == 1) v += bias[oc];
                    dst[((size_t)(b * Co + oc) * Ho + oh) * Ho + ow] = v;
                }
            }
        }
    } else {
        int kf = 1 << lgk;
        int Ho2 = Hin << lgk;
#pragma unroll
        for (int nt = 0; nt < 4; ++nt) {
            int n = n0 + (nt << 4) + tl;
            int b = n >> lgHW, hw = n & ((1 << lgHW) - 1);
            int h = hw >> lgHin, wp = hw & (Hin - 1);
#pragma unroll
            for (int mt = 0; mt < 2; ++mt) {
                int mb = m0 + (w << 5) + (mt << 4) + (quad << 2);
#pragma unroll
                for (int r = 0; r < 4; ++r) {
                    int m = mb + r;
                    int o = m & (Co - 1), ij = m >> lgCo;
                    int ii = ij >> lgk, jj = ij & (kf - 1);
                    float v = acc[mt][nt][r];
                    if (KS == 1) v += bias[o];
                    dst[((size_t)(b * Co + o) * Ho2 + (h << lgk) + ii) * Ho2 + (wp << lgk) + jj] = v;
                }
            }
        }
    }
}

// ================= weight prep: split + write in MFMA fragment order =================
// fragaddr(m,k; K) = ((m/16)*(K/32) + k/32)*512 + ((k>>3)&3)*128 + (m&15)*8 + (k&7)
__device__ inline int fragaddr(int m, int k, int K) {
    return ((((m >> 4) * (K >> 5) + (k >> 5)) << 9) | (((k >> 3) & 3) << 7) | ((m & 15) << 3) | (k & 7));
}

__global__ void prep_weights(const float* __restrict__ w1, const float* __restrict__ w2,
                             const float* __restrict__ w3, const float* __restrict__ d0,
                             const float* __restrict__ d1, const float* __restrict__ d2,
                             ushort* __restrict__ WH, ushort* __restrict__ WL) {
    int idx = blockIdx.x * 256 + threadIdx.x;
    if (idx >= 2269184) return;
    float v; int dst;
    if (idx < 131072) {                      // enc1: M=128 K=1024
        int m = idx >> 10, k = idx & 1023;
        v = w1[idx];
        dst = fragaddr(m, k, 1024);
    } else if (idx < 655360) {               // enc2: M=256 K=2048
        int i = idx - 131072;
        int m = i >> 11, k = i & 2047;
        v = w2[i];
        dst = 131072 + fragaddr(m, k, 2048);
    } else if (idx < 1703936) {              // enc3: M=256 K=4096
        int i = idx - 655360;
        int m = i >> 12, k = i & 4095;
        v = w3[i];
        dst = 655360 + fragaddr(m, k, 4096);
    } else if (idx < 2228224) {              // dec0: M=2048(ij*128+o) K=256, Ci=256 Co=128 kk=16
        int i = idx - 1703936;
        int m = i >> 8, c = i & 255;
        int o = m & 127, ij = m >> 7;
        v = d0[((size_t)c * 128 + o) * 16 + ij];
        dst = 1703936 + fragaddr(m, c, 256);
    } else if (idx < 2260992) {              // dec1: M=256 K=128, Ci=128 Co=64 kk=4
        int i = idx - 2228224;
        int m = i >> 7, c = i & 127;
        int o = m & 63, ij = m >> 6;
        v = d1[((size_t)c * 64 + o) * 4 + ij];
        dst = 2228224 + fragaddr(m, c, 128);
    } else {                                 // dec2: M=128 K=64, Ci=64 Co=32 kk=4
        int i = idx - 2260992;
        int m = i >> 6, c = i & 63;
        int o = m & 31, ij = m >> 5;
        v = d2[((size_t)c * 32 + o) * 4 + ij];
        dst = 2260992 + fragaddr(m, c, 64);
    }
    HL s = split_bf16(v);
    WH[dst] = s.h; WL[dst] = s.l;
}

// ================= enc0 direct conv (Ci=3) =================
template<int OCT>
__global__ __launch_bounds__(256) void conv4x4(
    const float* __restrict__ x, const float* __restrict__ w,
    const float* __restrict__ bias, float* __restrict__ P,
    int B, int Ci, int Hin, int Co, int Ho)
{
    int ogn = Co / OCT;
    int ntile = (B * Ho * Ho) >> 8;
    int bid = blockIdx.x;
    int tile = bid % ntile; bid /= ntile;
    int og = bid % ogn;
    int oc0 = og * OCT;

    int px = (tile << 8) + threadIdx.x;
    int ow = px % Ho; int t = px / Ho;
    int oh = t % Ho;  int b = t / Ho;

    int off[16]; float fm[16];
    int ih0 = oh * 2 - 1, iw0 = ow * 2 - 1;
#pragma unroll
    for (int kh = 0; kh < 4; ++kh)
#pragma unroll
        for (int kw = 0; kw < 4; ++kw) {
            int ih = ih0 + kh, iw = iw0 + kw;
            bool ok = (ih >= 0) && (ih < Hin) && (iw >= 0) && (iw < Hin);
            int ihc = ih < 0 ? 0 : (ih >= Hin ? Hin - 1 : ih);
            int iwc = iw < 0 ? 0 : (iw >= Hin ? Hin - 1 : iw);
            off[kh * 4 + kw] = ihc * Hin + iwc;
            fm[kh * 4 + kw] = ok ? 1.f : 0.f;
        }

    float acc[OCT];
#pragma unroll
    for (int u = 0; u < OCT; ++u) acc[u] = bias[oc0 + u];

    const float* xc = x + (size_t)b * Ci * Hin * Hin;
    const float* wi = w + (size_t)oc0 * Ci * 16;
    int HinHin = Hin * Hin;
    for (int ic = 0; ic < Ci; ++ic) {
        float xv[16];
#pragma unroll
        for (int q = 0; q < 16; ++q) xv[q] = xc[off[q]] * fm[q];
#pragma unroll
        for (int u = 0; u < OCT; ++u) {
            const float* wo = wi + (size_t)u * Ci * 16;
            float a = acc[u];
#pragma unroll
            for (int q = 0; q < 16; ++q) a += xv[q] * wo[q];
            acc[u] = a;
        }
        xc += HinHin;
        wi += 16;
    }
    size_t obase = (((size_t)b * Co + oc0) * Ho + oh) * Ho + ow;
    size_t opl = (size_t)Ho * Ho;
#pragma unroll
    for (int u = 0; u < OCT; ++u) P[obase + u * opl] = acc[u];
}

// ================= reduce partials / BN (verified) =================
__global__ void reduce_bias4(const float4* __restrict__ P, const float* __restrict__ bias,
                             float4* __restrict__ y, int outSize4, int KS, int Co, int HW4) {
    int i = blockIdx.x * 256 + threadIdx.x;
    if (i >= outSize4) return;
    float bv = bias[(i / HW4) % Co];
    float4 s = make_float4(bv, bv, bv, bv);
    for (int ks = 0; ks < KS; ++ks) {
        float4 p = P[(size_t)ks * outSize4 + i];
        s.x += p.x; s.y += p.y; s.z += p.z; s.w += p.w;
    }
    y[i] = s;
}

__global__ void reduce_bias_stats4(const float4* __restrict__ P, const float* __restrict__ bias,
                                   float4* __restrict__ y, float* __restrict__ bnt,
                                   int outSize4, int KS, int Co, int HW4, int nch) {
    int tid = threadIdx.x;
    int i = blockIdx.x * 256 + tid;
    int c = (i / HW4) % Co;
    float bv = bias[c];
    float4 s = make_float4(bv, bv, bv, bv);
    for (int ks = 0; ks < KS; ++ks) {
        float4 p = P[(size_t)ks * outSize4 + i];
        s.x += p.x; s.y += p.y; s.z += p.z; s.w += p.w;
    }
    y[i] = s;
    float ls  = s.x + s.y + s.z + s.w;
    float ls2 = s.x * s.x + s.y * s.y + s.z * s.z + s.w * s.w;
    __shared__ float as[16], aq[16];
    if (tid < 16) { as[tid] = 0.f; aq[tid] = 0.f; }
    __syncthreads();
    int c0 = ((blockIdx.x * 256) / HW4) % Co;
    atomicAdd(&as[c - c0], ls);
    atomicAdd(&aq[c - c0], ls2);
    __syncthreads();
    if (tid < nch) {
        atomicAdd(&bnt[(c0 + tid) * 2],     as[tid]);
        atomicAdd(&bnt[(c0 + tid) * 2 + 1], aq[tid]);
    }
}

__global__ void bn_part_atomic(const float* __restrict__ y, float* __restrict__ bnt,
                               int B, int C, int HW) {
    int blk = blockIdx.x;
    int c = blk / B, b = blk % B;
    int tid = threadIdx.x;
    const float* p = y + ((size_t)b * C + c) * HW;
    float s = 0.f, s2 = 0.f;
    for (int i = tid; i < HW; i += 256) {
        float v = p[i];
        s += v; s2 += v * v;
    }
    __shared__ float ls[256], ls2[256];
    ls[tid] = s; ls2[tid] = s2;
    __syncthreads();
    for (int off = 128; off > 0; off >>= 1) {
        if (tid < off) { ls[tid] += ls[tid + off]; ls2[tid] += ls2[tid + off]; }
        __syncthreads();
    }
    if (tid == 0) {
        atomicAdd(&bnt[c * 2],     ls[0]);
        atomicAdd(&bnt[c * 2 + 1], ls2[0]);
    }
}

// BN apply + LeakyReLU; optionally emits packed bf16 hi|lo copies
__global__ void bn_apply4(float4* __restrict__ y, uint32* __restrict__ yp,
                          const float* __restrict__ bnt,
                          const float* __restrict__ g, const float* __restrict__ bt,
                          int C, int HW4, float invN) {
    int i = blockIdx.x * 256 + threadIdx.x;
    int c = (i / HW4) % C;
    float m = bnt[c * 2] * invN;
    float var = bnt[c * 2 + 1] * invN - m * m;
    float scale = g[c] * rsqrtf(var + 1e-5f);
    float shift = bt[c] - m * scale;
    float4 v = y[i];
    v.x = v.x * scale + shift; v.x = v.x >= 0.f ? v.x : LEAK * v.x;
    v.y = v.y * scale + shift; v.y = v.y >= 0.f ? v.y : LEAK * v.y;
    v.z = v.z * scale + shift; v.z = v.z >= 0.f ? v.z : LEAK * v.z;
    v.w = v.w * scale + shift; v.w = v.w >= 0.f ? v.w : LEAK * v.w;
    y[i] = v;
    if (yp) {
        HL sx = split_bf16(v.x), sy = split_bf16(v.y), sz = split_bf16(v.z), sw = split_bf16(v.w);
        uint4 o = make_uint4(((uint32)sx.h << 16) | sx.l, ((uint32)sy.h << 16) | sy.l,
                             ((uint32)sz.h << 16) | sz.l, ((uint32)sw.h << 16) | sw.l);
        ((uint4*)yp)[i] = o;
    }
}

__global__ void zero_buf(float* __restrict__ p) {
    p[blockIdx.x * 256 + threadIdx.x] = 0.f;
}

// ================= Vector quantizer =================
#define OUT_CL   786432
#define OUT_CB   786433
#define OUT_IDX  786434
#define OUT_MIND 787458

__global__ void vq_prep(const float* __restrict__ cb, float* __restrict__ cbT) {
    int idx = blockIdx.x * 256 + threadIdx.x;
    int k = idx & 511, c = idx >> 9;
    cbT[idx] = cb[k * 256 + c];
}

__global__ void vq_main(const float* __restrict__ z, const float* __restrict__ cbT,
                        const float* __restrict__ cb,
                        uint32* __restrict__ qp, float* __restrict__ dout) {
    int r0 = blockIdx.x * 8;
    int tid = threadIdx.x;

    __shared__ float zT[256][8];
    __shared__ float red[256][9];
    __shared__ float zn2[8];
    __shared__ float rd[256];
    __shared__ int   ri[256];
    __shared__ int   bestsh[8];

#pragma unroll
    for (int rr = 0; rr < 8; ++rr) {
        int r = r0 + rr, b = r >> 6, s = r & 63;
        zT[tid][rr] = z[((size_t)(b * 256 + tid)) * 64 + s];
    }
    __syncthreads();
#pragma unroll
    for (int rr = 0; rr < 8; ++rr) { float v = zT[tid][rr]; red[tid][rr] = v * v; }
    __syncthreads();
    for (int off = 128; off > 0; off >>= 1) {
        if (tid < off) {
#pragma unroll
            for (int rr = 0; rr < 8; ++rr) red[tid][rr] += red[tid + off][rr];
        }
        __syncthreads();
    }
    if (tid < 8) zn2[tid] = red[0][tid];
    __syncthreads();

    float d0[8], d1[8];
#pragma unroll
    for (int rr = 0; rr < 8; ++rr) { d0[rr] = 0.f; d1[rr] = 0.f; }
    float cn0 = 0.f, cn1 = 0.f;

    for (int c = 0; c < 256; ++c) {
        float cv0 = cbT[c * 512 + tid];
        float cv1 = cbT[c * 512 + 256 + tid];
        cn0 += cv0 * cv0;
        cn1 += cv1 * cv1;
        float4 za = *(const float4*)&zT[c][0];
        float4 zb = *(const float4*)&zT[c][4];
        const float* zv = (const float*)&za;
        const float* zw = (const float*)&zb;
#pragma unroll
        for (int rr = 0; rr < 4; ++rr) {
            d0[rr]     += zv[rr] * cv0;  d1[rr]     += zv[rr] * cv1;
            d0[rr + 4] += zw[rr] * cv0;  d1[rr + 4] += zw[rr] * cv1;
        }
    }

#pragma unroll
    for (int rr = 0; rr < 8; ++rr) {
        float dist0 = zn2[rr] - 2.f * d0[rr] + cn0;
        float dist1 = zn2[rr] - 2.f * d1[rr] + cn1;
        float bd = dist0; int bi = tid;
        if (dist1 < bd) { bd = dist1; bi = tid + 256; }
        rd[tid] = bd; ri[tid] = bi;
        __syncthreads();
        for (int off = 128; off > 0; off >>= 1) {
            if (tid < off) {
                float od = rd[tid + off]; int oi = ri[tid + off];
                if (od < rd[tid] || (od == rd[tid] && oi < ri[tid])) { rd[tid] = od; ri[tid] = oi; }
            }
            __syncthreads();
        }
        if (tid == 0) {
            int r = r0 + rr;
            bestsh[rr] = ri[0];
            dout[OUT_IDX + r]  = (float)ri[0];
            dout[OUT_MIND + r] = rd[0];
        }
        __syncthreads();
    }

#pragma unroll
    for (int rr = 0; rr < 8; ++rr) {
        int r = r0 + rr, b = r >> 6, s = r & 63;
        float qv = cb[(size_t)bestsh[rr] * 256 + tid];
        HL sp = split_bf16(qv);
        qp[((size_t)(b * 256 + tid)) * 64 + s] = ((uint32)sp.h << 16) | sp.l;
    }
}

__global__ void vq_loss(float* __restrict__ dout) {
    int tid = threadIdx.x;
    __shared__ float red[256];
    float s = 0.f;
    for (int i = tid; i < 1024; i += 256) s += dout[OUT_MIND + i];
    red[tid] = s;
    __syncthreads();
    for (int off = 128; off > 0; off >>= 1) {
        if (tid < off) red[tid] += red[tid + off];
        __syncthreads();
    }
    if (tid == 0) {
        float loss = red[0] / 262144.f;
        dout[OUT_CL] = loss;
        dout[OUT_CB] = loss;
    }
}

// ================= Final 1x1 conv (32->3) + tanh =================
__global__ void final_conv_tanh(const float* __restrict__ hbuf, const float* __restrict__ w3,
                                const float* __restrict__ b3, float* __restrict__ out) {
    int idx = blockIdx.x * 256 + threadIdx.x;
    if (idx >= 16 * 16384) return;
    int hw = idx % 16384;
    int b  = idx / 16384;
    const float* hp = hbuf + ((size_t)b * 32) * 16384 + hw;
    float a0 = b3[0], a1 = b3[1], a2 = b3[2];
#pragma unroll
    for (int c = 0; c < 32; ++c) {
        float v = hp[(size_t)c * 16384];
        a0 += v * w3[c];
        a1 += v * w3[32 + c];
        a2 += v * w3[64 + c];
    }
    size_t ob = ((size_t)b * 3) * 16384 + hw;
    out[ob]             = tanhf(a0);
    out[ob + 16384]     = tanhf(a1);
    out[ob + 2 * 16384] = tanhf(a2);
}

extern "C" void kernel_launch(void* const* d_in, const int* in_sizes, int n_in,
                              void* d_out, int out_size, void* d_ws, size_t ws_size,
                              hipStream_t stream) {
    const float* x      = (const float*)d_in[0];
    const float* enc_w0 = (const float*)d_in[1];
    const float* enc_b0 = (const float*)d_in[2];
    const float* enc_w1 = (const float*)d_in[3];
    const float* enc_b1 = (const float*)d_in[4];
    const float* enc_w2 = (const float*)d_in[5];
    const float* enc_b2 = (const float*)d_in[6];
    const float* enc_w3 = (const float*)d_in[7];
    const float* enc_b3 = (const float*)d_in[8];
    const float* ebn_g0 = (const float*)d_in[9];
    const float* ebn_b0 = (const float*)d_in[10];
    const float* ebn_g1 = (const float*)d_in[11];
    const float* ebn_b1 = (const float*)d_in[12];
    const float* ebn_g2 = (const float*)d_in[13];
    const float* ebn_b2 = (const float*)d_in[14];
    const float* cb     = (const float*)d_in[15];
    const float* dec_w0 = (const float*)d_in[16];
    const float* dec_b0 = (const float*)d_in[17];
    const float* dbn_g0 = (const float*)d_in[18];
    const float* dbn_b0 = (const float*)d_in[19];
    const float* dec_w1 = (const float*)d_in[20];
    const float* dec_b1 = (const float*)d_in[21];
    const float* dbn_g1 = (const float*)d_in[22];
    const float* dbn_b1 = (const float*)d_in[23];
    const float* dec_w2 = (const float*)d_in[24];
    const float* dec_b2 = (const float*)d_in[25];
    const float* dbn_g2 = (const float*)d_in[26];
    const float* dbn_b2 = (const float*)d_in[27];
    const float* dec_w3 = (const float*)d_in[28];
    const float* dec_b3 = (const float*)d_in[29];

    float* out = (float*)d_out;
    float* ws  = (float*)d_ws;

    // ---- workspace (float units); same layout as round 8 (verified) ----
    float*  Y0   = ws;                               // 4194304
    float*  Y1   = ws + 4194304;                     // 2097152
    float*  Y2   = ws + 6291456;                     // 1048576
    float*  Z    = ws + 7340032;                     // 262144
    uint32* Qp   = (uint32*)(ws + 7602176);          // 262144 u32
    uint32* Y0p  = (uint32*)(ws + 7864320);          // 4194304 u32
    uint32* Y1p  = (uint32*)(ws + 12058624);         // 2097152 u32
    uint32* Y2p  = (uint32*)(ws + 14155776);         // 1048576 u32
    ushort* WH   = (ushort*)(ws + 15204352);         // 2269184 us
    ushort* WL   = (ushort*)(ws + 16338944);         // 2269184 us
    float*  CBT  = ws + 17473536;                    // 131072
    float*  BNT  = ws + 17604608;                    // 6144
    float*  PART = ws + 17610752;                    // up to 8388608 used
    float*  D0   = ws + 34387968;                    // 2097152
    uint32* D0p  = (uint32*)(ws + 36485120);         // 2097152 u32
    float*  D1   = ws + 38582272;                    // 4194304
    uint32* D1p  = (uint32*)(ws + 42776576);         // 4194304 u32
    float*  D2   = ws + 46970880;                    // 8388608 -> ends 55359488

    dim3 blk(256);

    // ---- prologue ----
    zero_buf<<<24, blk, 0, stream>>>(BNT);
    prep_weights<<<8864, blk, 0, stream>>>(enc_w1, enc_w2, enc_w3, dec_w0, dec_w1, dec_w2, WH, WL);
    vq_prep<<<512, blk, 0, stream>>>(cb, CBT);

    // ---- encoder ----
    conv4x4<8><<<2048, blk, 0, stream>>>(x, enc_w0, enc_b0, Y0, 16, 3, 128, 64, 64);
    bn_part_atomic<<<1024, blk, 0, stream>>>(Y0, BNT, 16, 64, 4096);
    bn_apply4<<<4096, blk, 0, stream>>>((float4*)Y0, Y0p, BNT, ebn_g0, ebn_b0, 64, 1024, 1.f / 65536.f);

    // enc1: M=128 N=16384 K=1024, KS=4 -> 1x256x4 = 1024 blocks
    gemm_mfma<0><<<1024, blk, 0, stream>>>(WH, WL, Y0p, enc_b1, PART,
        1, 256, 1024, 256, 4, 2097152, 64, 64, 128, 32, 5, 0, 0, 0, 0);
    reduce_bias_stats4<<<2048, blk, 0, stream>>>((const float4*)PART, enc_b1, (float4*)Y1,
                                                 BNT + 1024, 524288, 4, 128, 256, 1);
    bn_apply4<<<2048, blk, 0, stream>>>((float4*)Y1, Y1p, BNT + 1024, ebn_g1, ebn_b1, 128, 256, 1.f / 16384.f);

    // enc2: M=256 N=4096 K=2048, KS=8 -> 2x64x8 = 1024 blocks
    gemm_mfma<0><<<1024, blk, 0, stream>>>(WH + 131072, WL + 131072, Y1p, enc_b2, PART,
        2, 64, 2048, 256, 8, 1048576, 128, 32, 256, 16, 4, 0, 0, 0, 0);
    reduce_bias_stats4<<<1024, blk, 0, stream>>>((const float4*)PART, enc_b2, (float4*)Y2,
                                                 BNT + 2048, 262144, 8, 256, 64, 4);
    bn_apply4<<<1024, blk, 0, stream>>>((float4*)Y2, Y2p, BNT + 2048, ebn_g2, ebn_b2, 256, 64, 1.f / 4096.f);

    // enc3: M=256 N=1024 K=4096, KS=32 -> 2x16x32 = 1024 blocks
    gemm_mfma<0><<<1024, blk, 0, stream>>>(WH + 655360, WL + 655360, Y2p, enc_b3, PART,
        2, 16, 4096, 128, 32, 262144, 256, 16, 256, 8, 3, 0, 0, 0, 0);
    reduce_bias4<<<256, blk, 0, stream>>>((const float4*)PART, enc_b3, (float4*)Z, 65536, 32, 256, 16);

    // ---- vector quantizer ----
    vq_main<<<128, blk, 0, stream>>>(Z, CBT, cb, Qp, out);
    vq_loss<<<1, blk, 0, stream>>>(out);

    // ---- decoder ----
    // dec0: M=2048 N=1024 K=256, KS=4 -> 16x16x4 = 1024 blocks
    gemm_mfma<1><<<1024, blk, 0, stream>>>(WH + 1703936, WL + 1703936, Qp, dec_b0, PART,
        16, 16, 256, 64, 4, 2097152, 256, 8, 128, 0, 0, 6, 3, 7, 2);
    reduce_bias_stats4<<<2048, blk, 0, stream>>>((const float4*)PART, dec_b0, (float4*)D0,
                                                 BNT + 3072, 524288, 4, 128, 256, 1);
    bn_apply4<<<2048, blk, 0, stream>>>((float4*)D0, D0p, BNT + 3072, dbn_g0, dbn_b0, 128, 256, 1.f / 16384.f);

    // dec1: M=256 N=16384 K=128, KS=2 -> 2x256x2 = 1024 blocks
    gemm_mfma<1><<<1024, blk, 0, stream>>>(WH + 2228224, WL + 2228224, D0p, dec_b1, PART,
        2, 256, 128, 64, 2, 4194304, 128, 32, 64, 0, 0, 10, 5, 6, 1);
    reduce_bias_stats4<<<4096, blk, 0, stream>>>((const float4*)PART, dec_b1, (float4*)D1,
                                                 BNT + 4096, 1048576, 2, 64, 1024, 1);
    bn_apply4<<<4096, blk, 0, stream>>>((float4*)D1, D1p, BNT + 4096, dbn_g1, dbn_b1, 64, 1024, 1.f / 65536.f);

    // dec2: M=128 N=65536 K=64, KS=1 -> 1x1024x1 = 1024 blocks, direct write + bias
    gemm_mfma<1><<<1024, blk, 0, stream>>>(WH + 2260992, WL + 2260992, D1p, dec_b2, D2,
        1, 1024, 64, 64, 1, 0, 64, 64, 32, 0, 0, 12, 6, 5, 1);
    bn_part_atomic<<<512, blk, 0, stream>>>(D2, BNT + 5120, 16, 32, 16384);
    bn_apply4<<<8192, blk, 0, stream>>>((float4*)D2, nullptr, BNT + 5120, dbn_g2, dbn_b2, 32, 4096, 1.f / 262144.f);

    final_conv_tanh<<<1024, blk, 0, stream>>>(D2, dec_w3, dec_b3, out);
}

// Round 10
// 460.615 us; speedup vs baseline: 5.7492x; 1.0721x over previous
//
#include <hip/hip_runtime.h>
#include <math.h>

#define LEAK 0.01f

typedef __bf16 bf16x8 __attribute__((ext_vector_type(8)));
typedef float f32x4 __attribute__((ext_vector_type(4)));
typedef unsigned short ushort;
typedef unsigned int uint32;

struct HL { ushort h, l; };

// split fp32 into bf16 hi + bf16 lo (both RNE): x ~= hi + lo, err ~2^-17 rel
__device__ inline HL split_bf16(float x) {
    unsigned u = __float_as_uint(x);
    unsigned hr = (u + 0x7FFFu + ((u >> 16) & 1u)) >> 16;
    float fh = __uint_as_float(hr << 16);
    float r = x - fh;
    unsigned v = __float_as_uint(r);
    unsigned lr = (v + 0x7FFFu + ((v >> 16) & 1u)) >> 16;
    HL out; out.h = (ushort)hr; out.l = (ushort)lr;
    return out;
}

// ================= staged-B raw load: 64n x 32k fp32 tile, 8 floats/thread =================
template<int MODE>
__device__ inline void stage_load(float (&pv)[2][4], const float* __restrict__ Bf,
                                  int kbase, int n0, int tid,
                                  int Ci, int Hin, int Ho, int lgHo, int lgHW) {
#pragma unroll
    for (int r = 0; r < 2; ++r) {
        int g = r * 256 + tid;          // 0..511
        int nl = g >> 3, kg = g & 7;
        int n = n0 + nl;
        if (MODE == 0) {
            int k4 = kbase + (kg << 2);
            int ic = k4 >> 4, kh = (k4 >> 2) & 3;
            int ow = n & (Ho - 1), oh = (n >> lgHo) & (Ho - 1), b = n >> (lgHo + lgHo);
            int ih = oh * 2 - 1 + kh;
            int ihc = ih < 0 ? 0 : (ih >= Hin ? Hin - 1 : ih);
            int iwb = ow * 2 - 1;
            size_t base = ((size_t)(b * Ci + ic) * Hin + ihc) * Hin;
#pragma unroll
            for (int e = 0; e < 4; ++e) {
                int iw = iwb + e;
                int iwc = iw < 0 ? 0 : (iw >= Hin ? Hin - 1 : iw);
                pv[r][e] = Bf[base + iwc];
            }
        } else {
            int c = kbase + (kg << 2);
            int b = n >> lgHW, hw = n & ((1 << lgHW) - 1);
            size_t base = (((size_t)(b * Ci + c)) << lgHW) + hw;
            size_t str = (size_t)1 << lgHW;
#pragma unroll
            for (int e = 0; e < 4; ++e) pv[r][e] = Bf[base + e * str];
        }
    }
}

// ================= bf16-split MFMA GEMM with fused BN+LeakyReLU on B-load =================
// Block tile 128M x 64N, 4 waves of 32M x 64N. K-step 32.
// A: fragment-ordered bf16 hi/lo (verified r9).  B: raw fp32 activations; per-channel
// scale/shift computed from stats totals (bnt) in the block prologue; transform
// (BN -> leaky -> mask -> split -> pack) applied at LDS-write time.
// Math (verified r7-r9): C = Ah*Bh + Ah*Bl + Al*Bh per 16x16x32 tile.
template<int MODE>
__global__ __launch_bounds__(256, 3) void gemm_mfma(
    const ushort* __restrict__ Ah, const ushort* __restrict__ Al,
    const float* __restrict__ Bf,
    const float* __restrict__ bnt, const float* __restrict__ gamma,
    const float* __restrict__ beta, float invN, int chanShift,
    const float* __restrict__ bias, float* __restrict__ P,
    int Mtiles, int Ntiles, int K, int Kslice, int KS, int outSize,
    int Ci, int Hin, int Co, int Ho, int lgHo,
    int lgHW, int lgHin, int lgCo, int lgk)
{
    __shared__ __align__(16) uint32 Bsp[64 * 36];   // [n][k] packed, stride 36
    __shared__ float scs[256], shs[256];

    int bid = blockIdx.x;
    int ntile = bid % Ntiles; bid /= Ntiles;
    int mtile = bid % Mtiles;
    int ks = bid / Mtiles;
    int tid = threadIdx.x;
    int lane = tid & 63, w = tid >> 6;
    int quad = lane >> 4, tl = lane & 15;
    int n0 = ntile << 6, m0 = mtile << 7, k0 = ks * Kslice;
    int Kt = K >> 5;

    bool useBN = (bnt != nullptr);
    int c0 = k0 >> chanShift;
    if (useBN) {
        int nch = Kslice >> chanShift;
        for (int c = tid; c < nch; c += 256) {
            float m = bnt[(c0 + c) * 2] * invN;
            float var = bnt[(c0 + c) * 2 + 1] * invN - m * m;
            float scale = gamma[c0 + c] * rsqrtf(var + 1e-5f);
            scs[c] = scale;
            shs[c] = beta[c0 + c] - m * scale;
        }
    }
    __syncthreads();

    f32x4 zero4 = {0.f, 0.f, 0.f, 0.f};
    f32x4 acc[2][4];
#pragma unroll
    for (int mt = 0; mt < 2; ++mt)
#pragma unroll
        for (int nt = 0; nt < 4; ++nt) acc[mt][nt] = zero4;

    float pv[2][4];
    stage_load<MODE>(pv, Bf, k0, n0, tid, Ci, Hin, Ho, lgHo, lgHW);

    for (int kc = 0; kc < Kslice; kc += 32) {
        int kbase = k0 + kc;
        int kt = kbase >> 5;
        // ---- transform + regs -> LDS ----
#pragma unroll
        for (int r = 0; r < 2; ++r) {
            int g = r * 256 + tid;
            int nl = g >> 3, kg = g & 7;
            int k4 = kbase + (kg << 2);
            uint32 pk[4];
            if (MODE == 0) {
                int ic = k4 >> 4, kh = (k4 >> 2) & 3;
                int n = n0 + nl;
                int ow = n & (Ho - 1), oh = (n >> lgHo) & (Ho - 1);
                int ih = oh * 2 - 1 + kh;
                bool rowok = (unsigned)ih < (unsigned)Hin;
                int iwb = ow * 2 - 1;
                float sc_ = useBN ? scs[ic - c0] : 0.f;
                float sh_ = useBN ? shs[ic - c0] : 0.f;
#pragma unroll
                for (int e = 0; e < 4; ++e) {
                    int iw = iwb + e;
                    bool ok = rowok && ((unsigned)iw < (unsigned)Hin);
                    float f = pv[r][e];
                    if (useBN) { f = f * sc_ + sh_; f = f >= 0.f ? f : LEAK * f; }
                    if (!ok) f = 0.f;
                    HL s = split_bf16(f);
                    pk[e] = ((uint32)s.h << 16) | s.l;
                }
            } else {
#pragma unroll
                for (int e = 0; e < 4; ++e) {
                    float f = pv[r][e];
                    if (useBN) {
                        int lc = k4 + e - k0;
                        f = f * scs[lc] + shs[lc];
                        f = f >= 0.f ? f : LEAK * f;
                    }
                    HL s = split_bf16(f);
                    pk[e] = ((uint32)s.h << 16) | s.l;
                }
            }
            *(uint4*)&Bsp[nl * 36 + (kg << 2)] = make_uint4(pk[0], pk[1], pk[2], pk[3]);
        }
        __syncthreads();

        // ---- prefetch next B tile (raw, no transform -> loads stay in flight) ----
        bool more = (kc + 32) < Kslice;
        float pvn[2][4];
        if (more) stage_load<MODE>(pvn, Bf, kbase + 32, n0, tid, Ci, Hin, Ho, lgHo, lgHW);

        // ---- A fragments: fragment-ordered global, coalesced 16B/lane ----
        bf16x8 afh[2], afl[2];
#pragma unroll
        for (int mt = 0; mt < 2; ++mt) {
            int mtAbs = (m0 >> 4) + (w << 1) + mt;
            size_t abase = (((size_t)mtAbs * Kt + kt) << 6) + lane;
            afh[mt] = *(const bf16x8*)(Ah + abase * 8);
            afl[mt] = *(const bf16x8*)(Al + abase * 8);
        }
        // ---- B fragments: LDS packed -> unpack via v_perm ----
        bf16x8 bfh[4], bfl[4];
#pragma unroll
        for (int nt = 0; nt < 4; ++nt) {
            int base = ((nt << 4) + tl) * 36 + (quad << 3);
            uint4 ua = *(const uint4*)&Bsp[base];
            uint4 ub = *(const uint4*)&Bsp[base + 4];
            union { uint32 u[4]; bf16x8 v; } H, L;
            H.u[0] = __builtin_amdgcn_perm(ua.y, ua.x, 0x07060302u);
            H.u[1] = __builtin_amdgcn_perm(ua.w, ua.z, 0x07060302u);
            H.u[2] = __builtin_amdgcn_perm(ub.y, ub.x, 0x07060302u);
            H.u[3] = __builtin_amdgcn_perm(ub.w, ub.z, 0x07060302u);
            L.u[0] = __builtin_amdgcn_perm(ua.y, ua.x, 0x05040100u);
            L.u[1] = __builtin_amdgcn_perm(ua.w, ua.z, 0x05040100u);
            L.u[2] = __builtin_amdgcn_perm(ub.y, ub.x, 0x05040100u);
            L.u[3] = __builtin_amdgcn_perm(ub.w, ub.z, 0x05040100u);
            bfh[nt] = H.v; bfl[nt] = L.v;
        }
        // ---- 24 MFMAs / wave ----
#pragma unroll
        for (int mt = 0; mt < 2; ++mt)
#pragma unroll
            for (int nt = 0; nt < 4; ++nt) {
                acc[mt][nt] = __builtin_amdgcn_mfma_f32_16x16x32_bf16(afh[mt], bfh[nt], acc[mt][nt], 0, 0, 0);
                acc[mt][nt] = __builtin_amdgcn_mfma_f32_16x16x32_bf16(afh[mt], bfl[nt], acc[mt][nt], 0, 0, 0);
                acc[mt][nt] = __builtin_amdgcn_mfma_f32_16x16x32_bf16(afl[mt], bfh[nt], acc[mt][nt], 0, 0, 0);
            }
        __syncthreads();
        if (more) {
#pragma unroll
            for (int r = 0; r < 2; ++r)
#pragma unroll
                for (int e = 0; e < 4; ++e) pv[r][e] = pvn[r][e];
        }
    }

    // ---- epilogue: D[m = quad*4+reg][n = tl] (verified r7-r9) ----
    float* dst = P + (size_t)ks * outSize;
    if (MODE == 0) {
#pragma unroll
        for (int nt = 0; nt < 4; ++nt) {
            int n = n0 + (nt << 4) + tl;
            int ow = n & (Ho - 1), oh = (n >> lgHo) & (Ho - 1), b = n >> (lgHo + lgHo);
#pragma unroll
            for (int mt = 0; mt < 2; ++mt) {
                int mb = m0 + (w << 5) + (mt << 4) + (quad << 2);
#pragma unroll
                for (int r = 0; r < 4; ++r) {
                    int oc = mb + r;
                    float v = acc[mt][nt][r];
                    if (KS == 1) v += bias[oc];
                    dst[((size_t)(b * Co + oc) * Ho + oh) * Ho + ow] = v;
                }
            }
        }
    } else {
        int kf = 1 << lgk;
        int Ho2 = Hin << lgk;
#pragma unroll
        for (int nt = 0; nt < 4; ++nt) {
            int n = n0 + (nt << 4) + tl;
            int b = n >> lgHW, hw = n & ((1 << lgHW) - 1);
            int h = hw >> lgHin, wp = hw & (Hin - 1);
#pragma unroll
            for (int mt = 0; mt < 2; ++mt) {
                int mb = m0 + (w << 5) + (mt << 4) + (quad << 2);
#pragma unroll
                for (int r = 0; r < 4; ++r) {
                    int m = mb + r;
                    int o = m & (Co - 1), ij = m >> lgCo;
                    int ii = ij >> lgk, jj = ij & (kf - 1);
                    float v = acc[mt][nt][r];
                    if (KS == 1) v += bias[o];
                    dst[((size_t)(b * Co + o) * Ho2 + (h << lgk) + ii) * Ho2 + (wp << lgk) + jj] = v;
                }
            }
        }
    }
}

// ================= weight prep: split + write in MFMA fragment order (verified r9) =================
__device__ inline int fragaddr(int m, int k, int K) {
    return ((((m >> 4) * (K >> 5) + (k >> 5)) << 9) | (((k >> 3) & 3) << 7) | ((m & 15) << 3) | (k & 7));
}

__global__ void prep_weights(const float* __restrict__ w1, const float* __restrict__ w2,
                             const float* __restrict__ w3, const float* __restrict__ d0,
                             const float* __restrict__ d1, const float* __restrict__ d2,
                             ushort* __restrict__ WH, ushort* __restrict__ WL) {
    int idx = blockIdx.x * 256 + threadIdx.x;
    if (idx >= 2269184) return;
    float v; int dst;
    if (idx < 131072) {                      // enc1: M=128 K=1024
        int m = idx >> 10, k = idx & 1023;
        v = w1[idx];
        dst = fragaddr(m, k, 1024);
    } else if (idx < 655360) {               // enc2: M=256 K=2048
        int i = idx - 131072;
        int m = i >> 11, k = i & 2047;
        v = w2[i];
        dst = 131072 + fragaddr(m, k, 2048);
    } else if (idx < 1703936) {              // enc3: M=256 K=4096
        int i = idx - 655360;
        int m = i >> 12, k = i & 4095;
        v = w3[i];
        dst = 655360 + fragaddr(m, k, 4096);
    } else if (idx < 2228224) {              // dec0: M=2048 K=256
        int i = idx - 1703936;
        int m = i >> 8, c = i & 255;
        int o = m & 127, ij = m >> 7;
        v = d0[((size_t)c * 128 + o) * 16 + ij];
        dst = 1703936 + fragaddr(m, c, 256);
    } else if (idx < 2260992) {              // dec1: M=256 K=128
        int i = idx - 2228224;
        int m = i >> 7, c = i & 127;
        int o = m & 63, ij = m >> 6;
        v = d1[((size_t)c * 64 + o) * 4 + ij];
        dst = 2228224 + fragaddr(m, c, 128);
    } else {                                 // dec2: M=128 K=64
        int i = idx - 2260992;
        int m = i >> 6, c = i & 63;
        int o = m & 31, ij = m >> 5;
        v = d2[((size_t)c * 32 + o) * 4 + ij];
        dst = 2260992 + fragaddr(m, c, 64);
    }
    HL s = split_bf16(v);
    WH[dst] = s.h; WL[dst] = s.l;
}

// ================= enc0 direct conv (Ci=3) =================
template<int OCT>
__global__ __launch_bounds__(256) void conv4x4(
    const float* __restrict__ x, const float* __restrict__ w,
    const float* __restrict__ bias, float* __restrict__ P,
    int B, int Ci, int Hin, int Co, int Ho)
{
    int ogn = Co / OCT;
    int ntile = (B * Ho * Ho) >> 8;
    int bid = blockIdx.x;
    int tile = bid % ntile; bid /= ntile;
    int og = bid % ogn;
    int oc0 = og * OCT;

    int px = (tile << 8) + threadIdx.x;
    int ow = px % Ho; int t = px / Ho;
    int oh = t % Ho;  int b = t / Ho;

    int off[16]; float fm[16];
    int ih0 = oh * 2 - 1, iw0 = ow * 2 - 1;
#pragma unroll
    for (int kh = 0; kh < 4; ++kh)
#pragma unroll
        for (int kw = 0; kw < 4; ++kw) {
            int ih = ih0 + kh, iw = iw0 + kw;
            bool ok = (ih >= 0) && (ih < Hin) && (iw >= 0) && (iw < Hin);
            int ihc = ih < 0 ? 0 : (ih >= Hin ? Hin - 1 : ih);
            int iwc = iw < 0 ? 0 : (iw >= Hin ? Hin - 1 : iw);
            off[kh * 4 + kw] = ihc * Hin + iwc;
            fm[kh * 4 + kw] = ok ? 1.f : 0.f;
        }

    float acc[OCT];
#pragma unroll
    for (int u = 0; u < OCT; ++u) acc[u] = bias[oc0 + u];

    const float* xc = x + (size_t)b * Ci * Hin * Hin;
    const float* wi = w + (size_t)oc0 * Ci * 16;
    int HinHin = Hin * Hin;
    for (int ic = 0; ic < Ci; ++ic) {
        float xv[16];
#pragma unroll
        for (int q = 0; q < 16; ++q) xv[q] = xc[off[q]] * fm[q];
#pragma unroll
        for (int u = 0; u < OCT; ++u) {
            const float* wo = wi + (size_t)u * Ci * 16;
            float a = acc[u];
#pragma unroll
            for (int q = 0; q < 16; ++q) a += xv[q] * wo[q];
            acc[u] = a;
        }
        xc += HinHin;
        wi += 16;
    }
    size_t obase = (((size_t)b * Co + oc0) * Ho + oh) * Ho + ow;
    size_t opl = (size_t)Ho * Ho;
#pragma unroll
    for (int u = 0; u < OCT; ++u) P[obase + u * opl] = acc[u];
}

// ================= reduce partials / BN stats (verified) =================
__global__ void reduce_bias4(const float4* __restrict__ P, const float* __restrict__ bias,
                             float4* __restrict__ y, int outSize4, int KS, int Co, int HW4) {
    int i = blockIdx.x * 256 + threadIdx.x;
    if (i >= outSize4) return;
    float bv = bias[(i / HW4) % Co];
    float4 s = make_float4(bv, bv, bv, bv);
    for (int ks = 0; ks < KS; ++ks) {
        float4 p = P[(size_t)ks * outSize4 + i];
        s.x += p.x; s.y += p.y; s.z += p.z; s.w += p.w;
    }
    y[i] = s;
}

__global__ void reduce_bias_stats4(const float4* __restrict__ P, const float* __restrict__ bias,
                                   float4* __restrict__ y, float* __restrict__ bnt,
                                   int outSize4, int KS, int Co, int HW4, int nch) {
    int tid = threadIdx.x;
    int i = blockIdx.x * 256 + tid;
    int c = (i / HW4) % Co;
    float bv = bias[c];
    float4 s = make_float4(bv, bv, bv, bv);
    for (int ks = 0; ks < KS; ++ks) {
        float4 p = P[(size_t)ks * outSize4 + i];
        s.x += p.x; s.y += p.y; s.z += p.z; s.w += p.w;
    }
    y[i] = s;
    float ls  = s.x + s.y + s.z + s.w;
    float ls2 = s.x * s.x + s.y * s.y + s.z * s.z + s.w * s.w;
    __shared__ float as[16], aq[16];
    if (tid < 16) { as[tid] = 0.f; aq[tid] = 0.f; }
    __syncthreads();
    int c0 = ((blockIdx.x * 256) / HW4) % Co;
    atomicAdd(&as[c - c0], ls);
    atomicAdd(&aq[c - c0], ls2);
    __syncthreads();
    if (tid < nch) {
        atomicAdd(&bnt[(c0 + tid) * 2],     as[tid]);
        atomicAdd(&bnt[(c0 + tid) * 2 + 1], aq[tid]);
    }
}

__global__ void bn_part_atomic(const float* __restrict__ y, float* __restrict__ bnt,
                               int B, int C, int HW) {
    int blk = blockIdx.x;
    int c = blk / B, b = blk % B;
    int tid = threadIdx.x;
    const float* p = y + ((size_t)b * C + c) * HW;
    float s = 0.f, s2 = 0.f;
    for (int i = tid; i < HW; i += 256) {
        float v = p[i];
        s += v; s2 += v * v;
    }
    __shared__ float ls[256], ls2[256];
    ls[tid] = s; ls2[tid] = s2;
    __syncthreads();
    for (int off = 128; off > 0; off >>= 1) {
        if (tid < off) { ls[tid] += ls[tid + off]; ls2[tid] += ls2[tid + off]; }
        __syncthreads();
    }
    if (tid == 0) {
        atomicAdd(&bnt[c * 2],     ls[0]);
        atomicAdd(&bnt[c * 2 + 1], ls2[0]);
    }
}

__global__ void zero_buf(float* __restrict__ p) {
    p[blockIdx.x * 256 + threadIdx.x] = 0.f;
}

// ================= Vector quantizer (fp32 Q output) =================
#define OUT_CL   786432
#define OUT_CB   786433
#define OUT_IDX  786434
#define OUT_MIND 787458

__global__ void vq_prep(const float* __restrict__ cb, float* __restrict__ cbT) {
    int idx = blockIdx.x * 256 + threadIdx.x;
    int k = idx & 511, c = idx >> 9;
    cbT[idx] = cb[k * 256 + c];
}

__global__ void vq_main(const float* __restrict__ z, const float* __restrict__ cbT,
                        const float* __restrict__ cb,
                        float* __restrict__ q, float* __restrict__ dout) {
    int r0 = blockIdx.x * 8;
    int tid = threadIdx.x;

    __shared__ float zT[256][8];
    __shared__ float red[256][9];
    __shared__ float zn2[8];
    __shared__ float rd[256];
    __shared__ int   ri[256];
    __shared__ int   bestsh[8];

#pragma unroll
    for (int rr = 0; rr < 8; ++rr) {
        int r = r0 + rr, b = r >> 6, s = r & 63;
        zT[tid][rr] = z[((size_t)(b * 256 + tid)) * 64 + s];
    }
    __syncthreads();
#pragma unroll
    for (int rr = 0; rr < 8; ++rr) { float v = zT[tid][rr]; red[tid][rr] = v * v; }
    __syncthreads();
    for (int off = 128; off > 0; off >>= 1) {
        if (tid < off) {
#pragma unroll
            for (int rr = 0; rr < 8; ++rr) red[tid][rr] += red[tid + off][rr];
        }
        __syncthreads();
    }
    if (tid < 8) zn2[tid] = red[0][tid];
    __syncthreads();

    float d0[8], d1[8];
#pragma unroll
    for (int rr = 0; rr < 8; ++rr) { d0[rr] = 0.f; d1[rr] = 0.f; }
    float cn0 = 0.f, cn1 = 0.f;

    for (int c = 0; c < 256; ++c) {
        float cv0 = cbT[c * 512 + tid];
        float cv1 = cbT[c * 512 + 256 + tid];
        cn0 += cv0 * cv0;
        cn1 += cv1 * cv1;
        float4 za = *(const float4*)&zT[c][0];
        float4 zb = *(const float4*)&zT[c][4];
        const float* zv = (const float*)&za;
        const float* zw = (const float*)&zb;
#pragma unroll
        for (int rr = 0; rr < 4; ++rr) {
            d0[rr]     += zv[rr] * cv0;  d1[rr]     += zv[rr] * cv1;
            d0[rr + 4] += zw[rr] * cv0;  d1[rr + 4] += zw[rr] * cv1;
        }
    }

#pragma unroll
    for (int rr = 0; rr < 8; ++rr) {
        float dist0 = zn2[rr] - 2.f * d0[rr] + cn0;
        float dist1 = zn2[rr] - 2.f * d1[rr] + cn1;
        float bd = dist0; int bi = tid;
        if (dist1 < bd) { bd = dist1; bi = tid + 256; }
        rd[tid] = bd; ri[tid] = bi;
        __syncthreads();
        for (int off = 128; off > 0; off >>= 1) {
            if (tid < off) {
                float od = rd[tid + off]; int oi = ri[tid + off];
                if (od < rd[tid] || (od == rd[tid] && oi < ri[tid])) { rd[tid] = od; ri[tid] = oi; }
            }
            __syncthreads();
        }
        if (tid == 0) {
            int r = r0 + rr;
            bestsh[rr] = ri[0];
            dout[OUT_IDX + r]  = (float)ri[0];
            dout[OUT_MIND + r] = rd[0];
        }
        __syncthreads();
    }

#pragma unroll
    for (int rr = 0; rr < 8; ++rr) {
        int r = r0 + rr, b = r >> 6, s = r & 63;
        q[((size_t)(b * 256 + tid)) * 64 + s] = cb[(size_t)bestsh[rr] * 256 + tid];
    }
}

__global__ void vq_loss(float* __restrict__ dout) {
    int tid = threadIdx.x;
    __shared__ float red[256];
    float s = 0.f;
    for (int i = tid; i < 1024; i += 256) s += dout[OUT_MIND + i];
    red[tid] = s;
    __syncthreads();
    for (int off = 128; off > 0; off >>= 1) {
        if (tid < off) red[tid] += red[tid + off];
        __syncthreads();
    }
    if (tid == 0) {
        float loss = red[0] / 262144.f;
        dout[OUT_CL] = loss;
        dout[OUT_CB] = loss;
    }
}

// ================= Final: BN(D2) + LeakyReLU + 1x1 conv (32->3) + tanh =================
__global__ void final_conv_tanh(const float* __restrict__ hbuf, const float* __restrict__ bnt,
                                const float* __restrict__ g, const float* __restrict__ bt,
                                const float* __restrict__ w3, const float* __restrict__ b3,
                                float* __restrict__ out) {
    __shared__ float sc[32], sh[32];
    int tid = threadIdx.x;
    if (tid < 32) {
        float m = bnt[tid * 2] * (1.f / 262144.f);
        float var = bnt[tid * 2 + 1] * (1.f / 262144.f) - m * m;
        float scale = g[tid] * rsqrtf(var + 1e-5f);
        sc[tid] = scale;
        sh[tid] = bt[tid] - m * scale;
    }
    __syncthreads();
    int idx = blockIdx.x * 256 + tid;
    if (idx >= 16 * 16384) return;
    int hw = idx % 16384;
    int b  = idx / 16384;
    const float* hp = hbuf + ((size_t)b * 32) * 16384 + hw;
    float a0 = b3[0], a1 = b3[1], a2 = b3[2];
#pragma unroll
    for (int c = 0; c < 32; ++c) {
        float v = hp[(size_t)c * 16384];
        v = v * sc[c] + sh[c];
        v = v >= 0.f ? v : LEAK * v;
        a0 += v * w3[c];
        a1 += v * w3[32 + c];
        a2 += v * w3[64 + c];
    }
    size_t ob = ((size_t)b * 3) * 16384 + hw;
    out[ob]             = tanhf(a0);
    out[ob + 16384]     = tanhf(a1);
    out[ob + 2 * 16384] = tanhf(a2);
}

extern "C" void kernel_launch(void* const* d_in, const int* in_sizes, int n_in,
                              void* d_out, int out_size, void* d_ws, size_t ws_size,
                              hipStream_t stream) {
    const float* x      = (const float*)d_in[0];
    const float* enc_w0 = (const float*)d_in[1];
    const float* enc_b0 = (const float*)d_in[2];
    const float* enc_w1 = (const float*)d_in[3];
    const float* enc_b1 = (const float*)d_in[4];
    const float* enc_w2 = (const float*)d_in[5];
    const float* enc_b2 = (const float*)d_in[6];
    const float* enc_w3 = (const float*)d_in[7];
    const float* enc_b3 = (const float*)d_in[8];
    const float* ebn_g0 = (const float*)d_in[9];
    const float* ebn_b0 = (const float*)d_in[10];
    const float* ebn_g1 = (const float*)d_in[11];
    const float* ebn_b1 = (const float*)d_in[12];
    const float* ebn_g2 = (const float*)d_in[13];
    const float* ebn_b2 = (const float*)d_in[14];
    const float* cb     = (const float*)d_in[15];
    const float* dec_w0 = (const float*)d_in[16];
    const float* dec_b0 = (const float*)d_in[17];
    const float* dbn_g0 = (const float*)d_in[18];
    const float* dbn_b0 = (const float*)d_in[19];
    const float* dec_w1 = (const float*)d_in[20];
    const float* dec_b1 = (const float*)d_in[21];
    const float* dbn_g1 = (const float*)d_in[22];
    const float* dbn_b1 = (const float*)d_in[23];
    const float* dec_w2 = (const float*)d_in[24];
    const float* dec_b2 = (const float*)d_in[25];
    const float* dbn_g2 = (const float*)d_in[26];
    const float* dbn_b2 = (const float*)d_in[27];
    const float* dec_w3 = (const float*)d_in[28];
    const float* dec_b3 = (const float*)d_in[29];

    float* out = (float*)d_out;
    float* ws  = (float*)d_ws;

    // ---- workspace (float units); compacted, no aliasing; ends 33,339,392 fl (133 MB) ----
    float*  Y0   = ws;                               // 4194304
    float*  Y1   = ws + 4194304;                     // 2097152
    float*  Y2   = ws + 6291456;                     // 1048576
    float*  Z    = ws + 7340032;                     // 262144
    float*  Q    = ws + 7602176;                     // 262144
    ushort* WH   = (ushort*)(ws + 7864320);          // 2269184 us
    ushort* WL   = (ushort*)(ws + 8998912);          // 2269184 us
    float*  CBT  = ws + 10133504;                    // 131072
    float*  BNT  = ws + 10264576;                    // 6144
    float*  PART = ws + 10270720;                    // 8388608
    float*  D0   = ws + 18659328;                    // 2097152
    float*  D1   = ws + 20756480;                    // 4194304
    float*  D2   = ws + 24950784;                    // 8388608

    dim3 blk(256);

    // ---- prologue ----
    zero_buf<<<24, blk, 0, stream>>>(BNT);
    prep_weights<<<8864, blk, 0, stream>>>(enc_w1, enc_w2, enc_w3, dec_w0, dec_w1, dec_w2, WH, WL);
    vq_prep<<<512, blk, 0, stream>>>(cb, CBT);

    // ---- encoder ----
    conv4x4<8><<<2048, blk, 0, stream>>>(x, enc_w0, enc_b0, Y0, 16, 3, 128, 64, 64);
    bn_part_atomic<<<1024, blk, 0, stream>>>(Y0, BNT, 16, 64, 4096);

    // enc1: M=128 N=16384 K=1024, KS=4 -> 1024 blocks; B=Y0 raw + BN0
    gemm_mfma<0><<<1024, blk, 0, stream>>>(WH, WL, Y0,
        BNT, ebn_g0, ebn_b0, 1.f / 65536.f, 4, enc_b1, PART,
        1, 256, 1024, 256, 4, 2097152, 64, 64, 128, 32, 5, 0, 0, 0, 0);
    reduce_bias_stats4<<<2048, blk, 0, stream>>>((const float4*)PART, enc_b1, (float4*)Y1,
                                                 BNT + 1024, 524288, 4, 128, 256, 1);

    // enc2: M=256 N=4096 K=2048, KS=8 -> 1024 blocks; B=Y1 raw + BN1
    gemm_mfma<0><<<1024, blk, 0, stream>>>(WH + 131072, WL + 131072, Y1,
        BNT + 1024, ebn_g1, ebn_b1, 1.f / 16384.f, 4, enc_b2, PART,
        2, 64, 2048, 256, 8, 1048576, 128, 32, 256, 16, 4, 0, 0, 0, 0);
    reduce_bias_stats4<<<1024, blk, 0, stream>>>((const float4*)PART, enc_b2, (float4*)Y2,
                                                 BNT + 2048, 262144, 8, 256, 64, 4);

    // enc3: M=256 N=1024 K=4096, KS=32 -> 1024 blocks; B=Y2 raw + BN2
    gemm_mfma<0><<<1024, blk, 0, stream>>>(WH + 655360, WL + 655360, Y2,
        BNT + 2048, ebn_g2, ebn_b2, 1.f / 4096.f, 4, enc_b3, PART,
        2, 16, 4096, 128, 32, 262144, 256, 16, 256, 8, 3, 0, 0, 0, 0);
    reduce_bias4<<<256, blk, 0, stream>>>((const float4*)PART, enc_b3, (float4*)Z, 65536, 32, 256, 16);

    // ---- vector quantizer ----
    vq_main<<<128, blk, 0, stream>>>(Z, CBT, cb, Q, out);
    vq_loss<<<1, blk, 0, stream>>>(out);

    // ---- decoder ----
    // dec0: M=2048 N=1024 K=256, KS=4 -> 1024 blocks; B=Q (no BN)
    gemm_mfma<1><<<1024, blk, 0, stream>>>(WH + 1703936, WL + 1703936, Q,
        nullptr, nullptr, nullptr, 0.f, 0, dec_b0, PART,
        16, 16, 256, 64, 4, 2097152, 256, 8, 128, 0, 0, 6, 3, 7, 2);
    reduce_bias_stats4<<<2048, blk, 0, stream>>>((const float4*)PART, dec_b0, (float4*)D0,
                                                 BNT + 3072, 524288, 4, 128, 256, 1);

    // dec1: M=256 N=16384 K=128, KS=2 -> 1024 blocks; B=D0 raw + BN3
    gemm_mfma<1><<<1024, blk, 0, stream>>>(WH + 2228224, WL + 2228224, D0,
        BNT + 3072, dbn_g0, dbn_b0, 1.f / 16384.f, 0, dec_b1, PART,
        2, 256, 128, 64, 2, 4194304, 128, 32, 64, 0, 0, 10, 5, 6, 1);
    reduce_bias_stats4<<<4096, blk, 0, stream>>>((const float4*)PART, dec_b1, (float4*)D1,
                                                 BNT + 4096, 1048576, 2, 64, 1024, 1);

    // dec2: M=128 N=65536 K=64, KS=1 -> 1024 blocks; B=D1 raw + BN4; direct write + bias
    gemm_mfma<1><<<1024, blk, 0, stream>>>(WH + 2260992, WL + 2260992, D1,
        BNT + 4096, dbn_g1, dbn_b1, 1.f / 65536.f, 0, dec_b2, D2,
        1, 1024, 64, 64, 1, 0, 64, 64, 32, 0, 0, 12, 6, 5, 1);
    bn_part_atomic<<<512, blk, 0, stream>>>(D2, BNT + 5120, 16, 32, 16384);

    // final: BN5 + leaky + 1x1 conv + tanh
    final_conv_tanh<<<1024, blk, 0, stream>>>(D2, BNT + 5120, dbn_g2, dbn_b2, dec_w3, dec_b3, out);
}